// Round 8
// baseline (198.540 us; speedup 1.0000x reference)
//
#include <hip/hip_runtime.h>
#include <math.h>

#define NTOT 32768
#define NPG  2048
#define INDIM 32
#define HID  128
#define OUTD 64
#define NPAIR 100000
#define NEG_SLOPE 0.2f

typedef short bf16x8 __attribute__((ext_vector_type(8)));
typedef float f32x4 __attribute__((ext_vector_type(4)));

static __device__ __forceinline__ float b2f(ushort u) {
  return __uint_as_float(((unsigned)u) << 16);
}
static __device__ __forceinline__ ushort f2b(float f) {
  unsigned u = __float_as_uint(f);
  unsigned r = (u + 0x7fffu + ((u >> 16) & 1u)) >> 16;   // RNE
  return (ushort)r;
}
// chunk-swizzle: permute 8-bf16 (16B) chunks within each aligned 64-col group
// by row&7.  Involution; producers write swizzled global layout, GEMM stages
// linearly via global_load_lds, readers XOR on the LDS offset.
static __device__ __forceinline__ int swz_col(int row, int col) {
  return (col & ~63) | ((((col >> 3) ^ row) & 7) << 3) | (col & 7);
}

// ---------------------------------------------------------------------------
// prep: h = x@linW + b (LDS only) ; xl = h@gatW ; a_src = xl.attS ; a_dst
// ---------------------------------------------------------------------------
__global__ __launch_bounds__(256) void prep_kernel(
    const float* __restrict__ x, const float* __restrict__ linW,
    const float* __restrict__ linb, const float* __restrict__ gatW,
    const float* __restrict__ attS, const float* __restrict__ attD,
    float* __restrict__ xl, float* __restrict__ asrc, float* __restrict__ adst)
{
  __shared__ float xs[16][INDIM];
  __shared__ float hsm[16][HID + 1];
  __shared__ float xls[16][HID + 1];
  const int t = threadIdx.x;
  const int n0 = blockIdx.x * 16;
  for (int i = t; i < 16 * INDIM; i += 256) xs[i >> 5][i & 31] = x[(size_t)n0 * INDIM + i];
  __syncthreads();
  const int j = t & 127, half = t >> 7;
  float hacc[8];
  const float bj = linb[j];
#pragma unroll
  for (int nl = 0; nl < 8; nl++) hacc[nl] = bj;
#pragma unroll
  for (int i = 0; i < INDIM; i++) {
    const float w = linW[i * HID + j];
#pragma unroll
    for (int nl = 0; nl < 8; nl++) hacc[nl] = fmaf(xs[half * 8 + nl][i], w, hacc[nl]);
  }
#pragma unroll
  for (int nl = 0; nl < 8; nl++) hsm[half * 8 + nl][j] = hacc[nl];
  __syncthreads();
  float xacc[8];
#pragma unroll
  for (int nl = 0; nl < 8; nl++) xacc[nl] = 0.f;
  for (int k = 0; k < HID; k++) {
    const float w = gatW[k * HID + j];
#pragma unroll
    for (int nl = 0; nl < 8; nl++) xacc[nl] = fmaf(hsm[half * 8 + nl][k], w, xacc[nl]);
  }
#pragma unroll
  for (int nl = 0; nl < 8; nl++) {
    xls[half * 8 + nl][j] = xacc[nl];
    xl[(size_t)(n0 + half * 8 + nl) * HID + j] = xacc[nl];
  }
  __syncthreads();
  if (t < 16) {
    float as_ = 0.f, ad = 0.f;
    for (int k = 0; k < HID; k++) {
      const float xv = xls[t][k];
      as_ = fmaf(xv, attS[k], as_);
      ad  = fmaf(xv, attD[k], ad);
    }
    asrc[n0 + t] = as_; adst[n0 + t] = ad;
  }
}

// ---------------------------------------------------------------------------
// GAT attention (reference's degenerate neighbor pattern); emits hi/lo bf16
// in chunk-swizzled global layout for the MFMA GEMM consumer.
// ---------------------------------------------------------------------------
__global__ __launch_bounds__(256) void attn_kernel(
    const float* __restrict__ xl, const float* __restrict__ asrc,
    const float* __restrict__ adst, const float* __restrict__ gatb,
    ushort* __restrict__ ghi, ushort* __restrict__ glo)
{
  __shared__ int cs[2][17];
  __shared__ float al[2][17];
  const int t = threadIdx.x;
  const int nl = t >> 7, j = t & 127;
  const int n = blockIdx.x * 2 + nl;
  const int loc = n & (NPG - 1);
  const int gb = n & ~(NPG - 1);
  if (j < 17) {
    int c;
    if (j < 16) {
      const int nb = (loc < 16) ? ((j < loc) ? j : j + 1) : j;
      c = gb + nb;
    } else {
      c = n;  // self loop
    }
    cs[nl][j] = c;
    al[nl][j] = asrc[c];
  }
  __syncthreads();
  const float ad = adst[n];
  float m = -__builtin_inff();
#pragma unroll
  for (int k = 0; k < 17; k++) {
    float l = al[nl][k] + ad;
    l = (l > 0.f) ? l : NEG_SLOPE * l;
    m = fmaxf(m, l);
  }
  float w[17]; float den = 0.f;
#pragma unroll
  for (int k = 0; k < 17; k++) {
    float l = al[nl][k] + ad;
    l = (l > 0.f) ? l : NEG_SLOPE * l;
    w[k] = expf(l - m);
    den += w[k];
  }
  const float inv = 1.f / den;
  float accv = 0.f;
#pragma unroll
  for (int k = 0; k < 17; k++)
    accv = fmaf(w[k], xl[(size_t)cs[nl][k] * HID + j], accv);
  const float v = accv * inv + gatb[j];
  const ushort hi = f2b(v);
  const int jc = swz_col(n, j);
  ghi[(size_t)n * HID + jc] = hi;
  glo[(size_t)n * HID + jc] = f2b(v - b2f(hi));
}

// ---------------------------------------------------------------------------
// weight convert: W[K][N] fp32 -> Wt_hi/lo [N][K] bf16, transposed + swizzled
// ---------------------------------------------------------------------------
__global__ __launch_bounds__(256) void convw_kernel(
    const float* __restrict__ W, int Kd, int Nd,
    ushort* __restrict__ Whi, ushort* __restrict__ Wlo)
{
  const int i = blockIdx.x * 256 + threadIdx.x;
  if (i < Kd * Nd) {
    const int k = i / Nd, n = i - k * Nd;
    const float v = W[i];
    const ushort hi = f2b(v);
    const int kc = swz_col(n, k);
    Whi[(size_t)n * Kd + kc] = hi;
    Wlo[(size_t)n * Kd + kc] = f2b(v - b2f(hi));
  }
}

// ---------------------------------------------------------------------------
// MFMA split-bf16 GEMM, 2-phase double-buffered pipeline (T3 minimum recipe):
//   prologue: STAGE(buf0) ; barrier
//   loop:     STAGE(buf^1, next kt) ; ds_read+MFMA(buf) ; barrier ; flip
// 512 threads = 8 waves (2M x 4N), BM=128, BK=64, wave tile 64 x BN/4.
// Staging via global_load_lds dwordx4 into linear LDS; ds_read chunk-XOR.
// ---------------------------------------------------------------------------
template <int K, int N, int BN, bool RELU, bool SPLIT_OUT>
__global__ __launch_bounds__(512) void mgemm_kernel(
    const ushort* __restrict__ Ahi, const ushort* __restrict__ Alo,
    const ushort* __restrict__ Whi, const ushort* __restrict__ Wlo,
    const float* __restrict__ bias, float* __restrict__ C,
    ushort* __restrict__ Chi, ushort* __restrict__ Clo)
{
  constexpr int ASEG = 128 * 128;          // bytes per A half (128 rows x 64 bf16)
  constexpr int BSEG = BN * 128;
  constexpr int BUF  = 2 * ASEG + 2 * BSEG;
  constexpr int NC   = BN / 64;            // 16-col frags per wave
  extern __shared__ __align__(16) char lds[];

  const int m0 = blockIdx.x * 128;
  const int n0 = blockIdx.y * BN;
  const int t = threadIdx.x;
  const int wv = t >> 6, lane = t & 63;
  const int frow = lane & 15, kq = lane >> 4;
  const int wr = (wv >> 2) * 64;
  const int wc = (wv & 3) * (BN / 4);

  f32x4 acc[4][NC];
#pragma unroll
  for (int fr = 0; fr < 4; fr++)
#pragma unroll
    for (int fc = 0; fc < NC; fc++) acc[fr][fc] = (f32x4){0.f, 0.f, 0.f, 0.f};

  auto stage = [&](int buf, int kt) {
    char* base = lds + buf * BUF;
#pragma unroll
    for (int i = 0; i < 2; ++i) {          // A: 1024 chunks of 16B (hi & lo)
      const int c = t + i * 512;
      const int row = c >> 3, ch = c & 7;
      const size_t g = (size_t)(m0 + row) * K + kt + ch * 8;
      __builtin_amdgcn_global_load_lds(
          (const __attribute__((address_space(1))) void*)(Ahi + g),
          (__attribute__((address_space(3))) void*)(base + i * 8192 + wv * 1024), 16, 0, 0);
      __builtin_amdgcn_global_load_lds(
          (const __attribute__((address_space(1))) void*)(Alo + g),
          (__attribute__((address_space(3))) void*)(base + ASEG + i * 8192 + wv * 1024), 16, 0, 0);
    }
#pragma unroll
    for (int i = 0; i < BSEG / 8192; ++i) { // B: BN*8 chunks (hi & lo)
      const int c = t + i * 512;
      const int row = c >> 3, ch = c & 7;
      const size_t g = (size_t)(n0 + row) * K + kt + ch * 8;
      __builtin_amdgcn_global_load_lds(
          (const __attribute__((address_space(1))) void*)(Whi + g),
          (__attribute__((address_space(3))) void*)(base + 2 * ASEG + i * 8192 + wv * 1024), 16, 0, 0);
      __builtin_amdgcn_global_load_lds(
          (const __attribute__((address_space(1))) void*)(Wlo + g),
          (__attribute__((address_space(3))) void*)(base + 2 * ASEG + BSEG + i * 8192 + wv * 1024), 16, 0, 0);
    }
  };

  auto compute = [&](int buf) {
    char* Ah = lds + buf * BUF;
    char* Al = Ah + ASEG;
    char* Bh = Ah + 2 * ASEG;
    char* Bl = Bh + BSEG;
#pragma unroll
    for (int ks = 0; ks < 2; ++ks) {
      const int cc = ks * 4 + kq;
      bf16x8 afh[4], afl[4], bfh[NC], bfl[NC];
#pragma unroll
      for (int fr = 0; fr < 4; ++fr) {
        const int r = wr + fr * 16 + frow;
        const int off = r * 128 + (((cc ^ r) & 7) << 4);
        afh[fr] = *(const bf16x8*)(Ah + off);
        afl[fr] = *(const bf16x8*)(Al + off);
      }
#pragma unroll
      for (int fc = 0; fc < NC; ++fc) {
        const int r = wc + fc * 16 + frow;
        const int off = r * 128 + (((cc ^ r) & 7) << 4);
        bfh[fc] = *(const bf16x8*)(Bh + off);
        bfl[fc] = *(const bf16x8*)(Bl + off);
      }
#pragma unroll
      for (int fr = 0; fr < 4; ++fr)
#pragma unroll
        for (int fc = 0; fc < NC; ++fc) {
          acc[fr][fc] = __builtin_amdgcn_mfma_f32_16x16x32_bf16(afh[fr], bfh[fc], acc[fr][fc], 0, 0, 0);
          acc[fr][fc] = __builtin_amdgcn_mfma_f32_16x16x32_bf16(afh[fr], bfl[fc], acc[fr][fc], 0, 0, 0);
          acc[fr][fc] = __builtin_amdgcn_mfma_f32_16x16x32_bf16(afl[fr], bfh[fc], acc[fr][fc], 0, 0, 0);
        }
    }
  };

  stage(0, 0);
  __syncthreads();                 // prologue drain (compiler emits vmcnt(0))
  int cur = 0;
#pragma unroll 1
  for (int kt = 0; kt < K; kt += 64) {
    if (kt + 64 < K) stage(cur ^ 1, kt + 64);   // issue next tile first
    compute(cur);                                // overlap: MFMA hides load
    __syncthreads();                             // drain stage + join readers
    cur ^= 1;
  }

  const int rq = kq * 4;
#pragma unroll
  for (int fr = 0; fr < 4; fr++)
#pragma unroll
    for (int fc = 0; fc < NC; fc++)
#pragma unroll
      for (int j = 0; j < 4; j++) {
        const int row = m0 + wr + fr * 16 + rq + j;
        const int col = n0 + wc + fc * 16 + frow;
        float v = acc[fr][fc][j] + bias[col];
        if (RELU) v = fmaxf(v, 0.f);
        if constexpr (SPLIT_OUT) {
          const ushort hi = f2b(v);
          const int colc = swz_col(row, col);
          Chi[(size_t)row * N + colc] = hi;
          Clo[(size_t)row * N + colc] = f2b(v - b2f(hi));
        } else {
          C[(size_t)row * N + col] = v;
        }
      }
}

// ---------------------------------------------------------------------------
// pairs layout detection (parallel) + init
// ---------------------------------------------------------------------------
__global__ void init_flag_kernel(int* __restrict__ flag) { *flag = 0; }

__global__ __launch_bounds__(256) void detect_kernel(
    const unsigned long long* __restrict__ p64, int* __restrict__ flag)
{
  __shared__ int s;
  if (threadIdx.x == 0) s = 0;
  __syncthreads();
  int loc = 0;
  for (int i = blockIdx.x * 256 + threadIdx.x; i < NPAIR; i += 256 * 256)
    loc |= ((p64[i] >> 32) != 0ull) ? 1 : 0;
  if (loc) atomicOr(&s, 1);
  __syncthreads();
  if (threadIdx.x == 0 && s) atomicOr(flag, 1);
}

// ---------------------------------------------------------------------------
// final pair gather (fp32 out): [emb[pairs[:,0]], emb[pairs[:,1]]] ++ labels
// ---------------------------------------------------------------------------
__global__ __launch_bounds__(256) void gather_kernel(
    const float* __restrict__ emb, const unsigned long long* __restrict__ p64,
    const float* __restrict__ labels, const int* __restrict__ flagp,
    float* __restrict__ out)
{
  const int i = blockIdx.x * 256 + threadIdx.x;
  const int tot = 2 * NPAIR * OUTD;
  if (i < tot) {
    const int fl = *flagp;
    const int which = i / (NPAIR * OUTD);
    const int rem = i - which * (NPAIR * OUTD);
    const int p = rem >> 6, j = rem & 63;
    const int fi = p * 2 + which;
    int node;
    if (fl) {
      const unsigned long long w = p64[fi >> 1];
      node = (int)((fi & 1) ? (w >> 32) : (w & 0xffffffffull));
    } else {
      node = (int)p64[fi];
    }
    node &= (NTOT - 1);
    out[i] = emb[(size_t)node * OUTD + j];
  } else if (i < tot + NPAIR) {
    out[i] = labels[i - tot];
  }
}

extern "C" void kernel_launch(void* const* d_in, const int* in_sizes, int n_in,
                              void* d_out, int out_size, void* d_ws, size_t ws_size,
                              hipStream_t stream)
{
  const float* x      = (const float*)d_in[0];
  const unsigned long long* pairs = (const unsigned long long*)d_in[2];
  const float* labels = (const float*)d_in[3];
  const float* linW   = (const float*)d_in[4];
  const float* linb   = (const float*)d_in[5];
  const float* gatW   = (const float*)d_in[6];
  const float* attS   = (const float*)d_in[7];
  const float* attD   = (const float*)d_in[8];
  const float* gatb   = (const float*)d_in[9];
  const float* W1     = (const float*)d_in[10];
  const float* b1     = (const float*)d_in[11];
  const float* W2     = (const float*)d_in[12];
  const float* b2     = (const float*)d_in[13];
  const float* W3     = (const float*)d_in[14];
  const float* b3     = (const float*)d_in[15];

  float* ws = (float*)d_ws;
  const size_t NT = NTOT;
  // float-offset layout (overlays safe under serial stream ordering):
  float*  xl   = ws;                         // [0,128)   dead after attn
  ushort* e1hi = (ushort*)(ws);              // [0,256)   overlays xl
  ushort* e1lo = (ushort*)(ws + NT * 256);   // [256,512)
  ushort* ghi  = (ushort*)(ws + NT * 512);   // [512,576) dead after gemm1
  ushort* glo  = (ushort*)(ws + NT * 576);   // [576,640) dead after gemm1
  ushort* e2hi = (ushort*)(ws + NT * 512);   // [512,640) overlays ghi/glo
  ushort* e2lo = (ushort*)(ws + NT * 640);   // [640,768)
  float*  emb  = ws + NT * 768;              // [768,832)
  float*  asrc = ws + NT * 832;              // [832,833)
  float*  adst = ws + NT * 833;              // [833,834)
  ushort* wt1hi = (ushort*)(ws + NT * 834);
  ushort* wt1lo = wt1hi + 512 * 128;
  ushort* wt2hi = wt1lo + 512 * 128;
  ushort* wt2lo = wt2hi + 512 * 256;
  ushort* wt3hi = wt2lo + 512 * 256;
  ushort* wt3lo = wt3hi + 256 * 64;
  int*    flag  = (int*)(wt3lo + 256 * 64);

  // raise dynamic-LDS cap for the double-buffered GEMMs (idempotent host call)
  constexpr int LDS1 = 2 * (2 * 128 * 128 + 2 * 128 * 128);  // 131072 (BN=128)
  constexpr int LDS3 = 2 * (2 * 128 * 128 + 2 * 64 * 128);   //  98304 (BN=64)
  (void)hipFuncSetAttribute(
      reinterpret_cast<const void*>(mgemm_kernel<128, 512, 128, true,  true >),
      hipFuncAttributeMaxDynamicSharedMemorySize, LDS1);
  (void)hipFuncSetAttribute(
      reinterpret_cast<const void*>(mgemm_kernel<512, 256, 128, true,  true >),
      hipFuncAttributeMaxDynamicSharedMemorySize, LDS1);
  (void)hipFuncSetAttribute(
      reinterpret_cast<const void*>(mgemm_kernel<256,  64,  64, false, false>),
      hipFuncAttributeMaxDynamicSharedMemorySize, LDS3);

  init_flag_kernel<<<1, 1, 0, stream>>>(flag);
  detect_kernel<<<256, 256, 0, stream>>>(pairs, flag);
  convw_kernel<<<(128 * 512 + 255) / 256, 256, 0, stream>>>(W1, 128, 512, wt1hi, wt1lo);
  convw_kernel<<<(512 * 256 + 255) / 256, 256, 0, stream>>>(W2, 512, 256, wt2hi, wt2lo);
  convw_kernel<<<(256 * 64 + 255) / 256, 256, 0, stream>>>(W3, 256, 64, wt3hi, wt3lo);
  prep_kernel<<<NTOT / 16, 256, 0, stream>>>(x, linW, linb, gatW, attS, attD,
                                             xl, asrc, adst);
  attn_kernel<<<NTOT / 2, 256, 0, stream>>>(xl, asrc, adst, gatb, ghi, glo);

  mgemm_kernel<128, 512, 128, true,  true ><<<dim3(NTOT / 128, 4), 512, LDS1, stream>>>(
      ghi, glo, wt1hi, wt1lo, b1, nullptr, e1hi, e1lo);
  mgemm_kernel<512, 256, 128, true,  true ><<<dim3(NTOT / 128, 2), 512, LDS1, stream>>>(
      e1hi, e1lo, wt2hi, wt2lo, b2, nullptr, e2hi, e2lo);
  mgemm_kernel<256,  64,  64, false, false><<<dim3(NTOT / 128, 1), 512, LDS3, stream>>>(
      e2hi, e2lo, wt3hi, wt3lo, b3, emb, nullptr, nullptr);
  const int total = 2 * NPAIR * OUTD + NPAIR;
  gather_kernel<<<(total + 255) / 256, 256, 0, stream>>>(emb, pairs, labels, flag, (float*)d_out);
}

// Round 9
// 156.143 us; speedup vs baseline: 1.2715x; 1.2715x over previous
//
#include <hip/hip_runtime.h>
#include <math.h>

#define NTOT 32768
#define NPG  2048
#define INDIM 32
#define HID  128
#define OUTD 64
#define NPAIR 100000
#define NEG_SLOPE 0.2f

typedef short bf16x8 __attribute__((ext_vector_type(8)));
typedef float f32x4 __attribute__((ext_vector_type(4)));

static __device__ __forceinline__ float b2f(ushort u) {
  return __uint_as_float(((unsigned)u) << 16);
}
static __device__ __forceinline__ ushort f2b(float f) {
  unsigned u = __float_as_uint(f);
  unsigned r = (u + 0x7fffu + ((u >> 16) & 1u)) >> 16;   // RNE
  return (ushort)r;
}
// chunk-swizzle: permute 8-bf16 (16B) chunks within each aligned 64-col group
// by row&7.  Involution; producers write swizzled global layout, GEMM stages
// linearly via global_load_lds, readers XOR on the LDS offset.
static __device__ __forceinline__ int swz_col(int row, int col) {
  return (col & ~63) | ((((col >> 3) ^ row) & 7) << 3) | (col & 7);
}

// ---------------------------------------------------------------------------
// prep: h = x@linW + b (LDS only) ; xl = h@gatW ; a_src = xl.attS ; a_dst
// ---------------------------------------------------------------------------
__global__ __launch_bounds__(256) void prep_kernel(
    const float* __restrict__ x, const float* __restrict__ linW,
    const float* __restrict__ linb, const float* __restrict__ gatW,
    const float* __restrict__ attS, const float* __restrict__ attD,
    float* __restrict__ xl, float* __restrict__ asrc, float* __restrict__ adst)
{
  __shared__ float xs[16][INDIM];
  __shared__ float hsm[16][HID + 1];
  __shared__ float xls[16][HID + 1];
  const int t = threadIdx.x;
  const int n0 = blockIdx.x * 16;
  for (int i = t; i < 16 * INDIM; i += 256) xs[i >> 5][i & 31] = x[(size_t)n0 * INDIM + i];
  __syncthreads();
  const int j = t & 127, half = t >> 7;
  float hacc[8];
  const float bj = linb[j];
#pragma unroll
  for (int nl = 0; nl < 8; nl++) hacc[nl] = bj;
#pragma unroll
  for (int i = 0; i < INDIM; i++) {
    const float w = linW[i * HID + j];
#pragma unroll
    for (int nl = 0; nl < 8; nl++) hacc[nl] = fmaf(xs[half * 8 + nl][i], w, hacc[nl]);
  }
#pragma unroll
  for (int nl = 0; nl < 8; nl++) hsm[half * 8 + nl][j] = hacc[nl];
  __syncthreads();
  float xacc[8];
#pragma unroll
  for (int nl = 0; nl < 8; nl++) xacc[nl] = 0.f;
  for (int k = 0; k < HID; k++) {
    const float w = gatW[k * HID + j];
#pragma unroll
    for (int nl = 0; nl < 8; nl++) xacc[nl] = fmaf(hsm[half * 8 + nl][k], w, xacc[nl]);
  }
#pragma unroll
  for (int nl = 0; nl < 8; nl++) {
    xls[half * 8 + nl][j] = xacc[nl];
    xl[(size_t)(n0 + half * 8 + nl) * HID + j] = xacc[nl];
  }
  __syncthreads();
  if (t < 16) {
    float as_ = 0.f, ad = 0.f;
    for (int k = 0; k < HID; k++) {
      const float xv = xls[t][k];
      as_ = fmaf(xv, attS[k], as_);
      ad  = fmaf(xv, attD[k], ad);
    }
    asrc[n0 + t] = as_; adst[n0 + t] = ad;
  }
}

// ---------------------------------------------------------------------------
// GAT attention (reference's degenerate neighbor pattern); emits single bf16
// in chunk-swizzled global layout.  __expf: native v_exp_f32 path.
// ---------------------------------------------------------------------------
__global__ __launch_bounds__(256) void attn_kernel(
    const float* __restrict__ xl, const float* __restrict__ asrc,
    const float* __restrict__ adst, const float* __restrict__ gatb,
    ushort* __restrict__ ghi)
{
  __shared__ int cs[2][17];
  __shared__ float al[2][17];
  const int t = threadIdx.x;
  const int nl = t >> 7, j = t & 127;
  const int n = blockIdx.x * 2 + nl;
  const int loc = n & (NPG - 1);
  const int gb = n & ~(NPG - 1);
  if (j < 17) {
    int c;
    if (j < 16) {
      const int nb = (loc < 16) ? ((j < loc) ? j : j + 1) : j;
      c = gb + nb;
    } else {
      c = n;  // self loop
    }
    cs[nl][j] = c;
    al[nl][j] = asrc[c];
  }
  __syncthreads();
  const float ad = adst[n];
  float m = -__builtin_inff();
#pragma unroll
  for (int k = 0; k < 17; k++) {
    float l = al[nl][k] + ad;
    l = (l > 0.f) ? l : NEG_SLOPE * l;
    m = fmaxf(m, l);
  }
  float w[17]; float den = 0.f;
#pragma unroll
  for (int k = 0; k < 17; k++) {
    float l = al[nl][k] + ad;
    l = (l > 0.f) ? l : NEG_SLOPE * l;
    w[k] = __expf(l - m);
    den += w[k];
  }
  const float inv = 1.f / den;
  float accv = 0.f;
#pragma unroll
  for (int k = 0; k < 17; k++)
    accv = fmaf(w[k], xl[(size_t)cs[nl][k] * HID + j], accv);
  const float v = accv * inv + gatb[j];
  ghi[(size_t)n * HID + swz_col(n, j)] = f2b(v);
}

// ---------------------------------------------------------------------------
// weight convert: W[K][N] fp32 -> Wt_hi/lo [N][K] bf16, transposed + swizzled
// ---------------------------------------------------------------------------
__global__ __launch_bounds__(256) void convw_kernel(
    const float* __restrict__ W, int Kd, int Nd,
    ushort* __restrict__ Whi, ushort* __restrict__ Wlo)
{
  const int i = blockIdx.x * 256 + threadIdx.x;
  if (i < Kd * Nd) {
    const int k = i / Nd, n = i - k * Nd;
    const float v = W[i];
    const ushort hi = f2b(v);
    const int kc = swz_col(n, k);
    Whi[(size_t)n * Kd + kc] = hi;
    Wlo[(size_t)n * Kd + kc] = f2b(v - b2f(hi));
  }
}

// ---------------------------------------------------------------------------
// MFMA GEMM, A single bf16 x W split hi/lo (2-term), 2-phase dbuf pipeline.
// BM=64, BK=64, 256 threads = 4 waves (2M x 2N); wave tile 32 x BN/2.
// LDS/buf = 64*128 (A) + 2*BN*128 (B) -> BN=128: 40KB*2=80KB (2 blocks/CU).
// Staging via global_load_lds dwordx4, linear LDS; ds_read chunk-XOR swizzle.
// ---------------------------------------------------------------------------
template <int K, int N, int BN, bool RELU, bool BF_OUT>
__global__ __launch_bounds__(256) void mgemm_kernel(
    const ushort* __restrict__ A,
    const ushort* __restrict__ Whi, const ushort* __restrict__ Wlo,
    const float* __restrict__ bias, float* __restrict__ C,
    ushort* __restrict__ Cb)
{
  constexpr int ASEG = 64 * 128;           // bytes: 64 rows x 64 bf16
  constexpr int BSEG = BN * 128;           // bytes per B half
  constexpr int BUF  = ASEG + 2 * BSEG;
  constexpr int NC   = BN / 32;            // 16-col frags per wave
  extern __shared__ __align__(16) char lds[];

  const int m0 = blockIdx.x * 64;
  const int n0 = blockIdx.y * BN;
  const int t = threadIdx.x;
  const int wv = t >> 6, lane = t & 63;
  const int frow = lane & 15, kq = lane >> 4;
  const int wr = (wv >> 1) * 32;
  const int wc = (wv & 1) * (BN / 2);

  f32x4 acc[2][NC];
#pragma unroll
  for (int fr = 0; fr < 2; fr++)
#pragma unroll
    for (int fc = 0; fc < NC; fc++) acc[fr][fc] = (f32x4){0.f, 0.f, 0.f, 0.f};

  auto stage = [&](int buf, int kt) {
    char* base = lds + buf * BUF;
#pragma unroll
    for (int i = 0; i < ASEG / 4096; ++i) {   // A: 64 rows x 8 chunks
      const int c = t + i * 256;
      const int row = c >> 3, ch = c & 7;
      const size_t g = (size_t)(m0 + row) * K + kt + ch * 8;
      __builtin_amdgcn_global_load_lds(
          (const __attribute__((address_space(1))) void*)(A + g),
          (__attribute__((address_space(3))) void*)(base + i * 4096 + wv * 1024), 16, 0, 0);
    }
#pragma unroll
    for (int i = 0; i < BSEG / 4096; ++i) {   // B: BN rows x 8 chunks, hi & lo
      const int c = t + i * 256;
      const int row = c >> 3, ch = c & 7;
      const size_t g = (size_t)(n0 + row) * K + kt + ch * 8;
      __builtin_amdgcn_global_load_lds(
          (const __attribute__((address_space(1))) void*)(Whi + g),
          (__attribute__((address_space(3))) void*)(base + ASEG + i * 4096 + wv * 1024), 16, 0, 0);
      __builtin_amdgcn_global_load_lds(
          (const __attribute__((address_space(1))) void*)(Wlo + g),
          (__attribute__((address_space(3))) void*)(base + ASEG + BSEG + i * 4096 + wv * 1024), 16, 0, 0);
    }
  };

  auto compute = [&](int buf) {
    char* Ah = lds + buf * BUF;
    char* Bh = Ah + ASEG;
    char* Bl = Bh + BSEG;
#pragma unroll
    for (int ks = 0; ks < 2; ++ks) {
      const int cc = ks * 4 + kq;
      bf16x8 af[2], bfh[NC], bfl[NC];
#pragma unroll
      for (int fr = 0; fr < 2; ++fr) {
        const int r = wr + fr * 16 + frow;
        af[fr] = *(const bf16x8*)(Ah + r * 128 + (((cc ^ r) & 7) << 4));
      }
#pragma unroll
      for (int fc = 0; fc < NC; ++fc) {
        const int r = wc + fc * 16 + frow;
        const int off = r * 128 + (((cc ^ r) & 7) << 4);
        bfh[fc] = *(const bf16x8*)(Bh + off);
        bfl[fc] = *(const bf16x8*)(Bl + off);
      }
#pragma unroll
      for (int fr = 0; fr < 2; ++fr)
#pragma unroll
        for (int fc = 0; fc < NC; ++fc) {
          acc[fr][fc] = __builtin_amdgcn_mfma_f32_16x16x32_bf16(af[fr], bfh[fc], acc[fr][fc], 0, 0, 0);
          acc[fr][fc] = __builtin_amdgcn_mfma_f32_16x16x32_bf16(af[fr], bfl[fc], acc[fr][fc], 0, 0, 0);
        }
    }
  };

  stage(0, 0);
  __syncthreads();                 // prologue drain
  int cur = 0;
#pragma unroll 1
  for (int kt = 0; kt < K; kt += 64) {
    if (kt + 64 < K) stage(cur ^ 1, kt + 64);   // issue next tile first
    compute(cur);                                // MFMA hides load latency
    __syncthreads();
    cur ^= 1;
  }

  const int rq = kq * 4;
#pragma unroll
  for (int fr = 0; fr < 2; fr++)
#pragma unroll
    for (int fc = 0; fc < NC; fc++)
#pragma unroll
      for (int j = 0; j < 4; j++) {
        const int row = m0 + wr + fr * 16 + rq + j;
        const int col = n0 + wc + fc * 16 + frow;
        float v = acc[fr][fc][j] + bias[col];
        if (RELU) v = fmaxf(v, 0.f);
        if constexpr (BF_OUT) {
          Cb[(size_t)row * N + swz_col(row, col)] = f2b(v);
        } else {
          C[(size_t)row * N + col] = v;
        }
      }
}

// ---------------------------------------------------------------------------
// pairs layout detection (parallel) + init
// ---------------------------------------------------------------------------
__global__ void init_flag_kernel(int* __restrict__ flag) { *flag = 0; }

__global__ __launch_bounds__(256) void detect_kernel(
    const unsigned long long* __restrict__ p64, int* __restrict__ flag)
{
  __shared__ int s;
  if (threadIdx.x == 0) s = 0;
  __syncthreads();
  int loc = 0;
  for (int i = blockIdx.x * 256 + threadIdx.x; i < NPAIR; i += 256 * 256)
    loc |= ((p64[i] >> 32) != 0ull) ? 1 : 0;
  if (loc) atomicOr(&s, 1);
  __syncthreads();
  if (threadIdx.x == 0 && s) atomicOr(flag, 1);
}

// ---------------------------------------------------------------------------
// final pair gather (fp32 out): [emb[pairs[:,0]], emb[pairs[:,1]]] ++ labels
// ---------------------------------------------------------------------------
__global__ __launch_bounds__(256) void gather_kernel(
    const float* __restrict__ emb, const unsigned long long* __restrict__ p64,
    const float* __restrict__ labels, const int* __restrict__ flagp,
    float* __restrict__ out)
{
  const int i = blockIdx.x * 256 + threadIdx.x;
  const int tot = 2 * NPAIR * OUTD;
  if (i < tot) {
    const int fl = *flagp;
    const int which = i / (NPAIR * OUTD);
    const int rem = i - which * (NPAIR * OUTD);
    const int p = rem >> 6, j = rem & 63;
    const int fi = p * 2 + which;
    int node;
    if (fl) {
      const unsigned long long w = p64[fi >> 1];
      node = (int)((fi & 1) ? (w >> 32) : (w & 0xffffffffull));
    } else {
      node = (int)p64[fi];
    }
    node &= (NTOT - 1);
    out[i] = emb[(size_t)node * OUTD + j];
  } else if (i < tot + NPAIR) {
    out[i] = labels[i - tot];
  }
}

extern "C" void kernel_launch(void* const* d_in, const int* in_sizes, int n_in,
                              void* d_out, int out_size, void* d_ws, size_t ws_size,
                              hipStream_t stream)
{
  const float* x      = (const float*)d_in[0];
  const unsigned long long* pairs = (const unsigned long long*)d_in[2];
  const float* labels = (const float*)d_in[3];
  const float* linW   = (const float*)d_in[4];
  const float* linb   = (const float*)d_in[5];
  const float* gatW   = (const float*)d_in[6];
  const float* attS   = (const float*)d_in[7];
  const float* attD   = (const float*)d_in[8];
  const float* gatb   = (const float*)d_in[9];
  const float* W1     = (const float*)d_in[10];
  const float* b1     = (const float*)d_in[11];
  const float* W2     = (const float*)d_in[12];
  const float* b2     = (const float*)d_in[13];
  const float* W3     = (const float*)d_in[14];
  const float* b3     = (const float*)d_in[15];

  float* ws = (float*)d_ws;
  const size_t NT = NTOT;
  // sequential layout, no overlays (ample workspace):
  float*  xl   = ws;                         // [0,128)
  ushort* ghi  = (ushort*)(ws + NT * 128);   // [128,192)  N x 128 bf16
  ushort* e1b  = (ushort*)(ws + NT * 192);   // [192,448)  N x 512 bf16
  ushort* e2b  = (ushort*)(ws + NT * 448);   // [448,576)  N x 256 bf16
  float*  emb  = ws + NT * 576;              // [576,640)
  float*  asrc = ws + NT * 640;
  float*  adst = ws + NT * 641;
  ushort* wt1hi = (ushort*)(ws + NT * 642);
  ushort* wt1lo = wt1hi + 512 * 128;
  ushort* wt2hi = wt1lo + 512 * 128;
  ushort* wt2lo = wt2hi + 512 * 256;
  ushort* wt3hi = wt2lo + 512 * 256;
  ushort* wt3lo = wt3hi + 256 * 64;
  int*    flag  = (int*)(wt3lo + 256 * 64);

  constexpr int LDS1 = 2 * (64 * 128 + 2 * 128 * 128);  // 81920 (BN=128)
  constexpr int LDS3 = 2 * (64 * 128 + 2 * 64 * 128);   // 49152 (BN=64)
  (void)hipFuncSetAttribute(
      reinterpret_cast<const void*>(mgemm_kernel<128, 512, 128, true,  true >),
      hipFuncAttributeMaxDynamicSharedMemorySize, LDS1);
  (void)hipFuncSetAttribute(
      reinterpret_cast<const void*>(mgemm_kernel<512, 256, 128, true,  true >),
      hipFuncAttributeMaxDynamicSharedMemorySize, LDS1);
  (void)hipFuncSetAttribute(
      reinterpret_cast<const void*>(mgemm_kernel<256,  64,  64, false, false>),
      hipFuncAttributeMaxDynamicSharedMemorySize, LDS3);

  init_flag_kernel<<<1, 1, 0, stream>>>(flag);
  detect_kernel<<<256, 256, 0, stream>>>(pairs, flag);
  convw_kernel<<<(128 * 512 + 255) / 256, 256, 0, stream>>>(W1, 128, 512, wt1hi, wt1lo);
  convw_kernel<<<(512 * 256 + 255) / 256, 256, 0, stream>>>(W2, 512, 256, wt2hi, wt2lo);
  convw_kernel<<<(256 * 64 + 255) / 256, 256, 0, stream>>>(W3, 256, 64, wt3hi, wt3lo);
  prep_kernel<<<NTOT / 16, 256, 0, stream>>>(x, linW, linb, gatW, attS, attD,
                                             xl, asrc, adst);
  attn_kernel<<<NTOT / 2, 256, 0, stream>>>(xl, asrc, adst, gatb, ghi);

  mgemm_kernel<128, 512, 128, true,  true ><<<dim3(NTOT / 64, 4), 256, LDS1, stream>>>(
      ghi, wt1hi, wt1lo, b1, nullptr, e1b);
  mgemm_kernel<512, 256, 128, true,  true ><<<dim3(NTOT / 64, 2), 256, LDS1, stream>>>(
      e1b, wt2hi, wt2lo, b2, nullptr, e2b);
  mgemm_kernel<256,  64,  64, false, false><<<dim3(NTOT / 64, 1), 256, LDS3, stream>>>(
      e2b, wt3hi, wt3lo, b3, emb, nullptr);
  const int total = 2 * NPAIR * OUTD + NPAIR;
  gather_kernel<<<(total + 255) / 256, 256, 0, stream>>>(emb, pairs, labels, flag, (float*)d_out);
}

// Round 10
// 140.980 us; speedup vs baseline: 1.4083x; 1.1076x over previous
//
#include <hip/hip_runtime.h>
#include <math.h>

#define NTOT 32768
#define NPG  2048
#define INDIM 32
#define HID  128
#define OUTD 64
#define NPAIR 100000
#define NEG_SLOPE 0.2f

typedef short bf16x8 __attribute__((ext_vector_type(8)));
typedef float f32x4 __attribute__((ext_vector_type(4)));

static __device__ __forceinline__ float b2f(ushort u) {
  return __uint_as_float(((unsigned)u) << 16);
}
static __device__ __forceinline__ ushort f2b(float f) {
  unsigned u = __float_as_uint(f);
  unsigned r = (u + 0x7fffu + ((u >> 16) & 1u)) >> 16;   // RNE
  return (ushort)r;
}
// chunk-swizzle: permute 8-bf16 (16B) chunks within each aligned 64-col group
// by row&7.  Involution; producers write swizzled global layout, GEMM stages
// linearly via global_load_lds, readers XOR on the LDS offset.
static __device__ __forceinline__ int swz_col(int row, int col) {
  return (col & ~63) | ((((col >> 3) ^ row) & 7) << 3) | (col & 7);
}

// ---------------------------------------------------------------------------
// MFMA prep: h = x@linW + b ; xl = h@gatW   (both split-bf16 3-term)
// One block = 128 rows, 256 threads = 4 waves (2x2), full N=128 cols.
// GEMM1: K=32 (one MFMA k-step).  GEMM2: K=128 (4 k-steps), gatWt staged via
// global_load_lds from swizzled global, hs padded stride (no swizzle needed).
// ---------------------------------------------------------------------------
#define HSTR 136          // hs row stride in ushorts (272B = 17*16)
#define XSTR 40           // xs row stride in ushorts (80B = 5*16)
#define PREP_LDS (34816 * 2 + 65536)

__global__ __launch_bounds__(256) void prep_mfma_kernel(
    const float* __restrict__ x,
    const ushort* __restrict__ lwThi, const ushort* __restrict__ lwTlo,
    const float* __restrict__ linb,
    const ushort* __restrict__ gwShi, const ushort* __restrict__ gwSlo,
    float* __restrict__ xl)
{
  extern __shared__ __align__(16) char lds[];
  char* HS_HI = lds;                  // [128][136] u16 = 34816 B
  char* HS_LO = lds + 34816;
  char* GW_HI = lds + 69632;          // [128][128] u16 linear(swizzled content)
  char* GW_LO = lds + 102400;
  char* XS_HI = lds;                  // [128][40] u16 (overlays HS, dead early)
  char* XS_LO = lds + 10240;

  const int t = threadIdx.x;
  const int wv = t >> 6, lane = t & 63;
  const int frow = lane & 15, kq = lane >> 4;
  const int wr = (wv >> 1) * 64;
  const int wc = (wv & 1) * 64;
  const int m0 = blockIdx.x * 128;

  // ---- issue gatWt staging early (64 KB, drained at first barrier) ----
#pragma unroll
  for (int i = 0; i < 8; ++i) {
    const int c = t + i * 256;               // 2048 chunks per half
    const int row = c >> 4, ch = c & 15;
    const size_t g = (size_t)row * 128 + ch * 8;
    __builtin_amdgcn_global_load_lds(
        (const __attribute__((address_space(1))) void*)(gwShi + g),
        (__attribute__((address_space(3))) void*)(GW_HI + i * 4096 + wv * 1024), 16, 0, 0);
    __builtin_amdgcn_global_load_lds(
        (const __attribute__((address_space(1))) void*)(gwSlo + g),
        (__attribute__((address_space(3))) void*)(GW_LO + i * 4096 + wv * 1024), 16, 0, 0);
  }

  // ---- stage x tile: fp32 -> bf16 hi/lo in LDS ----
  {
    const int row = t >> 1, hf = t & 1;      // 16 floats per thread
#pragma unroll
    for (int q = 0; q < 4; ++q) {
      const float4 v = *(const float4*)&x[(size_t)(m0 + row) * INDIM + hf * 16 + q * 4];
      ushort4 hi, lo;
      hi.x = f2b(v.x); lo.x = f2b(v.x - b2f(hi.x));
      hi.y = f2b(v.y); lo.y = f2b(v.y - b2f(hi.y));
      hi.z = f2b(v.z); lo.z = f2b(v.z - b2f(hi.z));
      hi.w = f2b(v.w); lo.w = f2b(v.w - b2f(hi.w));
      const int off = row * (XSTR * 2) + (hf * 16 + q * 4) * 2;
      *(ushort4*)(XS_HI + off) = hi;
      *(ushort4*)(XS_LO + off) = lo;
    }
  }
  __syncthreads();

  // ---- GEMM1: h = x @ linW + b  (K=32, one k-step) ----
  f32x4 acc1[4][4];
  {
    bf16x8 ah[4], al[4], bh[4], bl[4];
#pragma unroll
    for (int fr = 0; fr < 4; ++fr) {
      const int r = wr + fr * 16 + frow;
      const int off = r * (XSTR * 2) + kq * 16;
      ah[fr] = *(const bf16x8*)(XS_HI + off);
      al[fr] = *(const bf16x8*)(XS_LO + off);
    }
#pragma unroll
    for (int fc = 0; fc < 4; ++fc) {
      const int col = wc + fc * 16 + frow;
      bh[fc] = *(const bf16x8*)(lwThi + (size_t)col * 32 + kq * 8);
      bl[fc] = *(const bf16x8*)(lwTlo + (size_t)col * 32 + kq * 8);
    }
#pragma unroll
    for (int fr = 0; fr < 4; ++fr)
#pragma unroll
      for (int fc = 0; fc < 4; ++fc) {
        f32x4 a = (f32x4){0.f, 0.f, 0.f, 0.f};
        a = __builtin_amdgcn_mfma_f32_16x16x32_bf16(ah[fr], bh[fc], a, 0, 0, 0);
        a = __builtin_amdgcn_mfma_f32_16x16x32_bf16(ah[fr], bl[fc], a, 0, 0, 0);
        a = __builtin_amdgcn_mfma_f32_16x16x32_bf16(al[fr], bh[fc], a, 0, 0, 0);
        acc1[fr][fc] = a;
      }
  }
  __syncthreads();   // xs reads done; safe to overwrite region with hs

  // ---- h += bias; split to hs hi/lo ----
#pragma unroll
  for (int fr = 0; fr < 4; ++fr)
#pragma unroll
    for (int fc = 0; fc < 4; ++fc) {
      const int col = wc + fc * 16 + frow;
      const float bj = linb[col];
#pragma unroll
      for (int j = 0; j < 4; ++j) {
        const int row = wr + fr * 16 + kq * 4 + j;
        const float v = acc1[fr][fc][j] + bj;
        const ushort hi = f2b(v);
        const int off = row * (HSTR * 2) + col * 2;
        *(ushort*)(HS_HI + off) = hi;
        *(ushort*)(HS_LO + off) = f2b(v - b2f(hi));
      }
    }
  __syncthreads();   // hs visible; gw staging long since drained

  // ---- GEMM2: xl = h @ gatW  (K=128, 4 k-steps) ----
  f32x4 acc2[4][4];
#pragma unroll
  for (int fr = 0; fr < 4; ++fr)
#pragma unroll
    for (int fc = 0; fc < 4; ++fc) acc2[fr][fc] = (f32x4){0.f, 0.f, 0.f, 0.f};
#pragma unroll
  for (int ks = 0; ks < 4; ++ks) {
    const int k = ks * 32 + kq * 8;
    bf16x8 ah[4], al[4], bh[4], bl[4];
#pragma unroll
    for (int fr = 0; fr < 4; ++fr) {
      const int r = wr + fr * 16 + frow;
      const int off = r * (HSTR * 2) + k * 2;
      ah[fr] = *(const bf16x8*)(HS_HI + off);
      al[fr] = *(const bf16x8*)(HS_LO + off);
    }
#pragma unroll
    for (int fc = 0; fc < 4; ++fc) {
      const int col = wc + fc * 16 + frow;
      const int off = col * 256 + (k & ~63) * 2 + ((((k >> 3) ^ col) & 7) << 4);
      bh[fc] = *(const bf16x8*)(GW_HI + off);
      bl[fc] = *(const bf16x8*)(GW_LO + off);
    }
#pragma unroll
    for (int fr = 0; fr < 4; ++fr)
#pragma unroll
      for (int fc = 0; fc < 4; ++fc) {
        acc2[fr][fc] = __builtin_amdgcn_mfma_f32_16x16x32_bf16(ah[fr], bh[fc], acc2[fr][fc], 0, 0, 0);
        acc2[fr][fc] = __builtin_amdgcn_mfma_f32_16x16x32_bf16(ah[fr], bl[fc], acc2[fr][fc], 0, 0, 0);
        acc2[fr][fc] = __builtin_amdgcn_mfma_f32_16x16x32_bf16(al[fr], bh[fc], acc2[fr][fc], 0, 0, 0);
      }
  }

  // ---- epilogue: xl fp32 to global ----
#pragma unroll
  for (int fr = 0; fr < 4; ++fr)
#pragma unroll
    for (int fc = 0; fc < 4; ++fc)
#pragma unroll
      for (int j = 0; j < 4; ++j) {
        const int row = m0 + wr + fr * 16 + kq * 4 + j;
        const int col = wc + fc * 16 + frow;
        xl[(size_t)row * HID + col] = acc2[fr][fc][j];
      }
}

// ---------------------------------------------------------------------------
// asrc/adst: one wave per node, shuffle reduce over 128 cols of xl (fp32)
// ---------------------------------------------------------------------------
__global__ __launch_bounds__(256) void reduce_kernel(
    const float* __restrict__ xl, const float* __restrict__ attS,
    const float* __restrict__ attD, float* __restrict__ asrc,
    float* __restrict__ adst)
{
  const int n = blockIdx.x * 4 + (threadIdx.x >> 6);
  const int l = threadIdx.x & 63;
  const float x0 = xl[(size_t)n * HID + l];
  const float x1 = xl[(size_t)n * HID + 64 + l];
  float s = fmaf(x0, attS[l], x1 * attS[64 + l]);
  float d = fmaf(x0, attD[l], x1 * attD[64 + l]);
#pragma unroll
  for (int sh = 32; sh > 0; sh >>= 1) {
    s += __shfl_xor(s, sh, 64);
    d += __shfl_xor(d, sh, 64);
  }
  if (l == 0) { asrc[n] = s; adst[n] = d; }
}

// ---------------------------------------------------------------------------
// GAT attention (reference's degenerate neighbor pattern); emits single bf16
// in chunk-swizzled global layout.  __expf: native v_exp_f32 path.
// ---------------------------------------------------------------------------
__global__ __launch_bounds__(256) void attn_kernel(
    const float* __restrict__ xl, const float* __restrict__ asrc,
    const float* __restrict__ adst, const float* __restrict__ gatb,
    ushort* __restrict__ ghi)
{
  __shared__ int cs[2][17];
  __shared__ float al[2][17];
  const int t = threadIdx.x;
  const int nl = t >> 7, j = t & 127;
  const int n = blockIdx.x * 2 + nl;
  const int loc = n & (NPG - 1);
  const int gb = n & ~(NPG - 1);
  if (j < 17) {
    int c;
    if (j < 16) {
      const int nb = (loc < 16) ? ((j < loc) ? j : j + 1) : j;
      c = gb + nb;
    } else {
      c = n;  // self loop
    }
    cs[nl][j] = c;
    al[nl][j] = asrc[c];
  }
  __syncthreads();
  const float ad = adst[n];
  float m = -__builtin_inff();
#pragma unroll
  for (int k = 0; k < 17; k++) {
    float l = al[nl][k] + ad;
    l = (l > 0.f) ? l : NEG_SLOPE * l;
    m = fmaxf(m, l);
  }
  float w[17]; float den = 0.f;
#pragma unroll
  for (int k = 0; k < 17; k++) {
    float l = al[nl][k] + ad;
    l = (l > 0.f) ? l : NEG_SLOPE * l;
    w[k] = __expf(l - m);
    den += w[k];
  }
  const float inv = 1.f / den;
  float accv = 0.f;
#pragma unroll
  for (int k = 0; k < 17; k++)
    accv = fmaf(w[k], xl[(size_t)cs[nl][k] * HID + j], accv);
  const float v = accv * inv + gatb[j];
  ghi[(size_t)n * HID + swz_col(n, j)] = f2b(v);
}

// ---------------------------------------------------------------------------
// weight converts: W[K][N] fp32 -> Wt hi/lo [N][K] bf16 transposed;
// convw_kernel additionally chunk-swizzles (K multiple of 64 required).
// ---------------------------------------------------------------------------
__global__ __launch_bounds__(256) void convw_kernel(
    const float* __restrict__ W, int Kd, int Nd,
    ushort* __restrict__ Whi, ushort* __restrict__ Wlo)
{
  const int i = blockIdx.x * 256 + threadIdx.x;
  if (i < Kd * Nd) {
    const int k = i / Nd, n = i - k * Nd;
    const float v = W[i];
    const ushort hi = f2b(v);
    const int kc = swz_col(n, k);
    Whi[(size_t)n * Kd + kc] = hi;
    Wlo[(size_t)n * Kd + kc] = f2b(v - b2f(hi));
  }
}

__global__ __launch_bounds__(256) void convw_plain_kernel(
    const float* __restrict__ W, int Kd, int Nd,
    ushort* __restrict__ Whi, ushort* __restrict__ Wlo)
{
  const int i = blockIdx.x * 256 + threadIdx.x;
  if (i < Kd * Nd) {
    const int k = i / Nd, n = i - k * Nd;
    const float v = W[i];
    const ushort hi = f2b(v);
    Whi[(size_t)n * Kd + k] = hi;
    Wlo[(size_t)n * Kd + k] = f2b(v - b2f(hi));
  }
}

// ---------------------------------------------------------------------------
// MFMA GEMM, A single bf16 x W split hi/lo (2-term), 2-phase dbuf pipeline.
// BM=64, BK=64, 256 threads = 4 waves (2M x 2N); wave tile 32 x BN/2.
// ---------------------------------------------------------------------------
template <int K, int N, int BN, bool RELU, bool BF_OUT>
__global__ __launch_bounds__(256) void mgemm_kernel(
    const ushort* __restrict__ A,
    const ushort* __restrict__ Whi, const ushort* __restrict__ Wlo,
    const float* __restrict__ bias, float* __restrict__ C,
    ushort* __restrict__ Cb)
{
  constexpr int ASEG = 64 * 128;           // bytes: 64 rows x 64 bf16
  constexpr int BSEG = BN * 128;           // bytes per B half
  constexpr int BUF  = ASEG + 2 * BSEG;
  constexpr int NC   = BN / 32;            // 16-col frags per wave
  extern __shared__ __align__(16) char lds[];

  const int m0 = blockIdx.x * 64;
  const int n0 = blockIdx.y * BN;
  const int t = threadIdx.x;
  const int wv = t >> 6, lane = t & 63;
  const int frow = lane & 15, kq = lane >> 4;
  const int wr = (wv >> 1) * 32;
  const int wc = (wv & 1) * (BN / 2);

  f32x4 acc[2][NC];
#pragma unroll
  for (int fr = 0; fr < 2; fr++)
#pragma unroll
    for (int fc = 0; fc < NC; fc++) acc[fr][fc] = (f32x4){0.f, 0.f, 0.f, 0.f};

  auto stage = [&](int buf, int kt) {
    char* base = lds + buf * BUF;
#pragma unroll
    for (int i = 0; i < ASEG / 4096; ++i) {
      const int c = t + i * 256;
      const int row = c >> 3, ch = c & 7;
      const size_t g = (size_t)(m0 + row) * K + kt + ch * 8;
      __builtin_amdgcn_global_load_lds(
          (const __attribute__((address_space(1))) void*)(A + g),
          (__attribute__((address_space(3))) void*)(base + i * 4096 + wv * 1024), 16, 0, 0);
    }
#pragma unroll
    for (int i = 0; i < BSEG / 4096; ++i) {
      const int c = t + i * 256;
      const int row = c >> 3, ch = c & 7;
      const size_t g = (size_t)(n0 + row) * K + kt + ch * 8;
      __builtin_amdgcn_global_load_lds(
          (const __attribute__((address_space(1))) void*)(Whi + g),
          (__attribute__((address_space(3))) void*)(base + ASEG + i * 4096 + wv * 1024), 16, 0, 0);
      __builtin_amdgcn_global_load_lds(
          (const __attribute__((address_space(1))) void*)(Wlo + g),
          (__attribute__((address_space(3))) void*)(base + ASEG + BSEG + i * 4096 + wv * 1024), 16, 0, 0);
    }
  };

  auto compute = [&](int buf) {
    char* Ah = lds + buf * BUF;
    char* Bh = Ah + ASEG;
    char* Bl = Bh + BSEG;
#pragma unroll
    for (int ks = 0; ks < 2; ++ks) {
      const int cc = ks * 4 + kq;
      bf16x8 af[2], bfh[NC], bfl[NC];
#pragma unroll
      for (int fr = 0; fr < 2; ++fr) {
        const int r = wr + fr * 16 + frow;
        af[fr] = *(const bf16x8*)(Ah + r * 128 + (((cc ^ r) & 7) << 4));
      }
#pragma unroll
      for (int fc = 0; fc < NC; ++fc) {
        const int r = wc + fc * 16 + frow;
        const int off = r * 128 + (((cc ^ r) & 7) << 4);
        bfh[fc] = *(const bf16x8*)(Bh + off);
        bfl[fc] = *(const bf16x8*)(Bl + off);
      }
#pragma unroll
      for (int fr = 0; fr < 2; ++fr)
#pragma unroll
        for (int fc = 0; fc < NC; ++fc) {
          acc[fr][fc] = __builtin_amdgcn_mfma_f32_16x16x32_bf16(af[fr], bfh[fc], acc[fr][fc], 0, 0, 0);
          acc[fr][fc] = __builtin_amdgcn_mfma_f32_16x16x32_bf16(af[fr], bfl[fc], acc[fr][fc], 0, 0, 0);
        }
    }
  };

  stage(0, 0);
  __syncthreads();
  int cur = 0;
#pragma unroll 1
  for (int kt = 0; kt < K; kt += 64) {
    if (kt + 64 < K) stage(cur ^ 1, kt + 64);
    compute(cur);
    __syncthreads();
    cur ^= 1;
  }

  const int rq = kq * 4;
#pragma unroll
  for (int fr = 0; fr < 2; fr++)
#pragma unroll
    for (int fc = 0; fc < NC; fc++)
#pragma unroll
      for (int j = 0; j < 4; j++) {
        const int row = m0 + wr + fr * 16 + rq + j;
        const int col = n0 + wc + fc * 16 + frow;
        float v = acc[fr][fc][j] + bias[col];
        if (RELU) v = fmaxf(v, 0.f);
        if constexpr (BF_OUT) {
          Cb[(size_t)row * N + swz_col(row, col)] = f2b(v);
        } else {
          C[(size_t)row * N + col] = v;
        }
      }
}

// ---------------------------------------------------------------------------
// pairs layout detection (parallel) + init
// ---------------------------------------------------------------------------
__global__ void init_flag_kernel(int* __restrict__ flag) { *flag = 0; }

__global__ __launch_bounds__(256) void detect_kernel(
    const unsigned long long* __restrict__ p64, int* __restrict__ flag)
{
  __shared__ int s;
  if (threadIdx.x == 0) s = 0;
  __syncthreads();
  int loc = 0;
  for (int i = blockIdx.x * 256 + threadIdx.x; i < NPAIR; i += 256 * 256)
    loc |= ((p64[i] >> 32) != 0ull) ? 1 : 0;
  if (loc) atomicOr(&s, 1);
  __syncthreads();
  if (threadIdx.x == 0 && s) atomicOr(flag, 1);
}

// ---------------------------------------------------------------------------
// final pair gather (fp32 out): [emb[pairs[:,0]], emb[pairs[:,1]]] ++ labels
// ---------------------------------------------------------------------------
__global__ __launch_bounds__(256) void gather_kernel(
    const float* __restrict__ emb, const unsigned long long* __restrict__ p64,
    const float* __restrict__ labels, const int* __restrict__ flagp,
    float* __restrict__ out)
{
  const int i = blockIdx.x * 256 + threadIdx.x;
  const int tot = 2 * NPAIR * OUTD;
  if (i < tot) {
    const int fl = *flagp;
    const int which = i / (NPAIR * OUTD);
    const int rem = i - which * (NPAIR * OUTD);
    const int p = rem >> 6, j = rem & 63;
    const int fi = p * 2 + which;
    int node;
    if (fl) {
      const unsigned long long w = p64[fi >> 1];
      node = (int)((fi & 1) ? (w >> 32) : (w & 0xffffffffull));
    } else {
      node = (int)p64[fi];
    }
    node &= (NTOT - 1);
    out[i] = emb[(size_t)node * OUTD + j];
  } else if (i < tot + NPAIR) {
    out[i] = labels[i - tot];
  }
}

extern "C" void kernel_launch(void* const* d_in, const int* in_sizes, int n_in,
                              void* d_out, int out_size, void* d_ws, size_t ws_size,
                              hipStream_t stream)
{
  const float* x      = (const float*)d_in[0];
  const unsigned long long* pairs = (const unsigned long long*)d_in[2];
  const float* labels = (const float*)d_in[3];
  const float* linW   = (const float*)d_in[4];
  const float* linb   = (const float*)d_in[5];
  const float* gatW   = (const float*)d_in[6];
  const float* attS   = (const float*)d_in[7];
  const float* attD   = (const float*)d_in[8];
  const float* gatb   = (const float*)d_in[9];
  const float* W1     = (const float*)d_in[10];
  const float* b1     = (const float*)d_in[11];
  const float* W2     = (const float*)d_in[12];
  const float* b2     = (const float*)d_in[13];
  const float* W3     = (const float*)d_in[14];
  const float* b3     = (const float*)d_in[15];

  float* ws = (float*)d_ws;
  const size_t NT = NTOT;
  float*  xl   = ws;                         // [0,128)
  ushort* ghi  = (ushort*)(ws + NT * 128);   // [128,192)  N x 128 bf16 swz
  ushort* e1b  = (ushort*)(ws + NT * 192);   // [192,448)  N x 512 bf16 swz
  ushort* e2b  = (ushort*)(ws + NT * 448);   // [448,576)  N x 256 bf16 swz
  float*  emb  = ws + NT * 576;              // [576,640)
  float*  asrc = ws + NT * 640;
  float*  adst = ws + NT * 641;
  ushort* wt1hi = (ushort*)(ws + NT * 642);
  ushort* wt1lo = wt1hi + 512 * 128;
  ushort* wt2hi = wt1lo + 512 * 128;
  ushort* wt2lo = wt2hi + 512 * 256;
  ushort* wt3hi = wt2lo + 512 * 256;
  ushort* wt3lo = wt3hi + 256 * 64;
  ushort* lwThi = wt3lo + 256 * 64;          // [128][32] plain transpose
  ushort* lwTlo = lwThi + 128 * 32;
  ushort* gwShi = lwTlo + 128 * 32;          // [128][128] transposed + swz
  ushort* gwSlo = gwShi + 128 * 128;
  int*    flag  = (int*)(gwSlo + 128 * 128);

  constexpr int LDS1 = 2 * (64 * 128 + 2 * 128 * 128);  // 81920 (BN=128)
  constexpr int LDS3 = 2 * (64 * 128 + 2 * 64 * 128);   // 49152 (BN=64)
  (void)hipFuncSetAttribute(
      reinterpret_cast<const void*>(mgemm_kernel<128, 512, 128, true,  true >),
      hipFuncAttributeMaxDynamicSharedMemorySize, LDS1);
  (void)hipFuncSetAttribute(
      reinterpret_cast<const void*>(mgemm_kernel<512, 256, 128, true,  true >),
      hipFuncAttributeMaxDynamicSharedMemorySize, LDS1);
  (void)hipFuncSetAttribute(
      reinterpret_cast<const void*>(mgemm_kernel<256,  64,  64, false, false>),
      hipFuncAttributeMaxDynamicSharedMemorySize, LDS3);
  (void)hipFuncSetAttribute(
      reinterpret_cast<const void*>(prep_mfma_kernel),
      hipFuncAttributeMaxDynamicSharedMemorySize, PREP_LDS);

  init_flag_kernel<<<1, 1, 0, stream>>>(flag);
  detect_kernel<<<256, 256, 0, stream>>>(pairs, flag);
  convw_kernel<<<(128 * 512 + 255) / 256, 256, 0, stream>>>(W1, 128, 512, wt1hi, wt1lo);
  convw_kernel<<<(512 * 256 + 255) / 256, 256, 0, stream>>>(W2, 512, 256, wt2hi, wt2lo);
  convw_kernel<<<(256 * 64 + 255) / 256, 256, 0, stream>>>(W3, 256, 64, wt3hi, wt3lo);
  convw_plain_kernel<<<(32 * 128 + 255) / 256, 256, 0, stream>>>(linW, 32, 128, lwThi, lwTlo);
  convw_kernel<<<(128 * 128 + 255) / 256, 256, 0, stream>>>(gatW, 128, 128, gwShi, gwSlo);

  prep_mfma_kernel<<<NTOT / 128, 256, PREP_LDS, stream>>>(
      x, lwThi, lwTlo, linb, gwShi, gwSlo, xl);
  reduce_kernel<<<NTOT / 4, 256, 0, stream>>>(xl, attS, attD, asrc, adst);
  attn_kernel<<<NTOT / 2, 256, 0, stream>>>(xl, asrc, adst, gatb, ghi);

  mgemm_kernel<128, 512, 128, true,  true ><<<dim3(NTOT / 64, 4), 256, LDS1, stream>>>(
      ghi, wt1hi, wt1lo, b1, nullptr, e1b);
  mgemm_kernel<512, 256, 128, true,  true ><<<dim3(NTOT / 64, 2), 256, LDS1, stream>>>(
      e1b, wt2hi, wt2lo, b2, nullptr, e2b);
  mgemm_kernel<256,  64,  64, false, false><<<dim3(NTOT / 64, 1), 256, LDS3, stream>>>(
      e2b, wt3hi, wt3lo, b3, emb, nullptr);
  const int total = 2 * NPAIR * OUTD + NPAIR;
  gather_kernel<<<(total + 255) / 256, 256, 0, stream>>>(emb, pairs, labels, flag, (float*)d_out);
}

// Round 11
// 116.623 us; speedup vs baseline: 1.7024x; 1.2089x over previous
//
#include <hip/hip_runtime.h>
#include <math.h>

#define NTOT 32768
#define NPG  2048
#define INDIM 32
#define HID  128
#define OUTD 64
#define NPAIR 100000
#define NEG_SLOPE 0.2f

typedef short bf16x8 __attribute__((ext_vector_type(8)));
typedef float f32x4 __attribute__((ext_vector_type(4)));

static __device__ __forceinline__ float b2f(ushort u) {
  return __uint_as_float(((unsigned)u) << 16);
}
static __device__ __forceinline__ ushort f2b(float f) {
  unsigned u = __float_as_uint(f);
  unsigned r = (u + 0x7fffu + ((u >> 16) & 1u)) >> 16;   // RNE
  return (ushort)r;
}
// chunk-swizzle: permute 8-bf16 (16B) chunks within each aligned 64-col group
// by row&7.  Involution; producers write swizzled global layout, GEMM stages
// linearly via global_load_lds, readers XOR on the LDS offset.
static __device__ __forceinline__ int swz_col(int row, int col) {
  return (col & ~63) | ((((col >> 3) ^ row) & 7) << 3) | (col & 7);
}

// ---------------------------------------------------------------------------
// MFMA prep: h = x@linW + b ; xl = h@gatW   (both split-bf16 3-term)
// One block = 128 rows, 256 threads = 4 waves (2x2), full N=128 cols.
// ---------------------------------------------------------------------------
#define HSTR 136          // hs row stride in ushorts (272B = 17*16)
#define XSTR 40           // xs row stride in ushorts (80B = 5*16)
#define PREP_LDS (34816 * 2 + 65536)

__global__ __launch_bounds__(256) void prep_mfma_kernel(
    const float* __restrict__ x,
    const ushort* __restrict__ lwThi, const ushort* __restrict__ lwTlo,
    const float* __restrict__ linb,
    const ushort* __restrict__ gwShi, const ushort* __restrict__ gwSlo,
    float* __restrict__ xl)
{
  extern __shared__ __align__(16) char lds[];
  char* HS_HI = lds;                  // [128][136] u16 = 34816 B
  char* HS_LO = lds + 34816;
  char* GW_HI = lds + 69632;          // [128][128] u16 linear(swizzled content)
  char* GW_LO = lds + 102400;
  char* XS_HI = lds;                  // [128][40] u16 (overlays HS, dead early)
  char* XS_LO = lds + 10240;

  const int t = threadIdx.x;
  const int wv = t >> 6, lane = t & 63;
  const int frow = lane & 15, kq = lane >> 4;
  const int wr = (wv >> 1) * 64;
  const int wc = (wv & 1) * 64;
  const int m0 = blockIdx.x * 128;

  // ---- issue gatWt staging early (64 KB, drained at first barrier) ----
#pragma unroll
  for (int i = 0; i < 8; ++i) {
    const int c = t + i * 256;               // 2048 chunks per half
    const int row = c >> 4, ch = c & 15;
    const size_t g = (size_t)row * 128 + ch * 8;
    __builtin_amdgcn_global_load_lds(
        (const __attribute__((address_space(1))) void*)(gwShi + g),
        (__attribute__((address_space(3))) void*)(GW_HI + i * 4096 + wv * 1024), 16, 0, 0);
    __builtin_amdgcn_global_load_lds(
        (const __attribute__((address_space(1))) void*)(gwSlo + g),
        (__attribute__((address_space(3))) void*)(GW_LO + i * 4096 + wv * 1024), 16, 0, 0);
  }

  // ---- stage x tile: fp32 -> bf16 hi/lo in LDS ----
  {
    const int row = t >> 1, hf = t & 1;      // 16 floats per thread
#pragma unroll
    for (int q = 0; q < 4; ++q) {
      const float4 v = *(const float4*)&x[(size_t)(m0 + row) * INDIM + hf * 16 + q * 4];
      ushort4 hi, lo;
      hi.x = f2b(v.x); lo.x = f2b(v.x - b2f(hi.x));
      hi.y = f2b(v.y); lo.y = f2b(v.y - b2f(hi.y));
      hi.z = f2b(v.z); lo.z = f2b(v.z - b2f(hi.z));
      hi.w = f2b(v.w); lo.w = f2b(v.w - b2f(hi.w));
      const int off = row * (XSTR * 2) + (hf * 16 + q * 4) * 2;
      *(ushort4*)(XS_HI + off) = hi;
      *(ushort4*)(XS_LO + off) = lo;
    }
  }
  __syncthreads();

  // ---- GEMM1: h = x @ linW + b  (K=32, one k-step) ----
  f32x4 acc1[4][4];
  {
    bf16x8 ah[4], al[4], bh[4], bl[4];
#pragma unroll
    for (int fr = 0; fr < 4; ++fr) {
      const int r = wr + fr * 16 + frow;
      const int off = r * (XSTR * 2) + kq * 16;
      ah[fr] = *(const bf16x8*)(XS_HI + off);
      al[fr] = *(const bf16x8*)(XS_LO + off);
    }
#pragma unroll
    for (int fc = 0; fc < 4; ++fc) {
      const int col = wc + fc * 16 + frow;
      bh[fc] = *(const bf16x8*)(lwThi + (size_t)col * 32 + kq * 8);
      bl[fc] = *(const bf16x8*)(lwTlo + (size_t)col * 32 + kq * 8);
    }
#pragma unroll
    for (int fr = 0; fr < 4; ++fr)
#pragma unroll
      for (int fc = 0; fc < 4; ++fc) {
        f32x4 a = (f32x4){0.f, 0.f, 0.f, 0.f};
        a = __builtin_amdgcn_mfma_f32_16x16x32_bf16(ah[fr], bh[fc], a, 0, 0, 0);
        a = __builtin_amdgcn_mfma_f32_16x16x32_bf16(ah[fr], bl[fc], a, 0, 0, 0);
        a = __builtin_amdgcn_mfma_f32_16x16x32_bf16(al[fr], bh[fc], a, 0, 0, 0);
        acc1[fr][fc] = a;
      }
  }
  __syncthreads();   // xs reads done; safe to overwrite region with hs

  // ---- h += bias; split to hs hi/lo ----
#pragma unroll
  for (int fr = 0; fr < 4; ++fr)
#pragma unroll
    for (int fc = 0; fc < 4; ++fc) {
      const int col = wc + fc * 16 + frow;
      const float bj = linb[col];
#pragma unroll
      for (int j = 0; j < 4; ++j) {
        const int row = wr + fr * 16 + kq * 4 + j;
        const float v = acc1[fr][fc][j] + bj;
        const ushort hi = f2b(v);
        const int off = row * (HSTR * 2) + col * 2;
        *(ushort*)(HS_HI + off) = hi;
        *(ushort*)(HS_LO + off) = f2b(v - b2f(hi));
      }
    }
  __syncthreads();   // hs visible; gw staging long since drained

  // ---- GEMM2: xl = h @ gatW  (K=128, 4 k-steps) ----
  f32x4 acc2[4][4];
#pragma unroll
  for (int fr = 0; fr < 4; ++fr)
#pragma unroll
    for (int fc = 0; fc < 4; ++fc) acc2[fr][fc] = (f32x4){0.f, 0.f, 0.f, 0.f};
#pragma unroll
  for (int ks = 0; ks < 4; ++ks) {
    const int k = ks * 32 + kq * 8;
    bf16x8 ah[4], al[4], bh[4], bl[4];
#pragma unroll
    for (int fr = 0; fr < 4; ++fr) {
      const int r = wr + fr * 16 + frow;
      const int off = r * (HSTR * 2) + k * 2;
      ah[fr] = *(const bf16x8*)(HS_HI + off);
      al[fr] = *(const bf16x8*)(HS_LO + off);
    }
#pragma unroll
    for (int fc = 0; fc < 4; ++fc) {
      const int col = wc + fc * 16 + frow;
      const int off = col * 256 + (k & ~63) * 2 + ((((k >> 3) ^ col) & 7) << 4);
      bh[fc] = *(const bf16x8*)(GW_HI + off);
      bl[fc] = *(const bf16x8*)(GW_LO + off);
    }
#pragma unroll
    for (int fr = 0; fr < 4; ++fr)
#pragma unroll
      for (int fc = 0; fc < 4; ++fc) {
        acc2[fr][fc] = __builtin_amdgcn_mfma_f32_16x16x32_bf16(ah[fr], bh[fc], acc2[fr][fc], 0, 0, 0);
        acc2[fr][fc] = __builtin_amdgcn_mfma_f32_16x16x32_bf16(ah[fr], bl[fc], acc2[fr][fc], 0, 0, 0);
        acc2[fr][fc] = __builtin_amdgcn_mfma_f32_16x16x32_bf16(al[fr], bh[fc], acc2[fr][fc], 0, 0, 0);
      }
  }

  // ---- epilogue: xl fp32 to global ----
#pragma unroll
  for (int fr = 0; fr < 4; ++fr)
#pragma unroll
    for (int fc = 0; fc < 4; ++fc)
#pragma unroll
      for (int j = 0; j < 4; ++j) {
        const int row = m0 + wr + fr * 16 + kq * 4 + j;
        const int col = wc + fc * 16 + frow;
        xl[(size_t)row * HID + col] = acc2[fr][fc][j];
      }
}

// ---------------------------------------------------------------------------
// asrc/adst: one wave per node, shuffle reduce over 128 cols of xl (fp32)
// ---------------------------------------------------------------------------
__global__ __launch_bounds__(256) void reduce_kernel(
    const float* __restrict__ xl, const float* __restrict__ attS,
    const float* __restrict__ attD, float* __restrict__ asrc,
    float* __restrict__ adst)
{
  const int n = blockIdx.x * 4 + (threadIdx.x >> 6);
  const int l = threadIdx.x & 63;
  const float x0 = xl[(size_t)n * HID + l];
  const float x1 = xl[(size_t)n * HID + 64 + l];
  float s = fmaf(x0, attS[l], x1 * attS[64 + l]);
  float d = fmaf(x0, attD[l], x1 * attD[64 + l]);
#pragma unroll
  for (int sh = 32; sh > 0; sh >>= 1) {
    s += __shfl_xor(s, sh, 64);
    d += __shfl_xor(d, sh, 64);
  }
  if (l == 0) { asrc[n] = s; adst[n] = d; }
}

// ---------------------------------------------------------------------------
// GAT attention (reference's degenerate neighbor pattern); emits single bf16
// in chunk-swizzled global layout.  __expf: native v_exp_f32 path.
// ---------------------------------------------------------------------------
__global__ __launch_bounds__(256) void attn_kernel(
    const float* __restrict__ xl, const float* __restrict__ asrc,
    const float* __restrict__ adst, const float* __restrict__ gatb,
    ushort* __restrict__ ghi)
{
  __shared__ int cs[2][17];
  __shared__ float al[2][17];
  const int t = threadIdx.x;
  const int nl = t >> 7, j = t & 127;
  const int n = blockIdx.x * 2 + nl;
  const int loc = n & (NPG - 1);
  const int gb = n & ~(NPG - 1);
  if (j < 17) {
    int c;
    if (j < 16) {
      const int nb = (loc < 16) ? ((j < loc) ? j : j + 1) : j;
      c = gb + nb;
    } else {
      c = n;  // self loop
    }
    cs[nl][j] = c;
    al[nl][j] = asrc[c];
  }
  __syncthreads();
  const float ad = adst[n];
  float m = -__builtin_inff();
#pragma unroll
  for (int k = 0; k < 17; k++) {
    float l = al[nl][k] + ad;
    l = (l > 0.f) ? l : NEG_SLOPE * l;
    m = fmaxf(m, l);
  }
  float w[17]; float den = 0.f;
#pragma unroll
  for (int k = 0; k < 17; k++) {
    float l = al[nl][k] + ad;
    l = (l > 0.f) ? l : NEG_SLOPE * l;
    w[k] = __expf(l - m);
    den += w[k];
  }
  const float inv = 1.f / den;
  float accv = 0.f;
#pragma unroll
  for (int k = 0; k < 17; k++)
    accv = fmaf(w[k], xl[(size_t)cs[nl][k] * HID + j], accv);
  const float v = accv * inv + gatb[j];
  ghi[(size_t)n * HID + swz_col(n, j)] = f2b(v);
}

// ---------------------------------------------------------------------------
// fused weight conversion (one launch): MLP weights -> hi-only transposed+swz;
// linW -> hi/lo plain transpose; gatW -> hi/lo transposed+swz; flag init.
// ---------------------------------------------------------------------------
__global__ __launch_bounds__(256) void convert_all_kernel(
    const float* __restrict__ W1, const float* __restrict__ W2,
    const float* __restrict__ W3, const float* __restrict__ linW,
    const float* __restrict__ gatW,
    ushort* __restrict__ wt1hi, ushort* __restrict__ wt2hi,
    ushort* __restrict__ wt3hi,
    ushort* __restrict__ lwThi, ushort* __restrict__ lwTlo,
    ushort* __restrict__ gwShi, ushort* __restrict__ gwSlo,
    int* __restrict__ flag)
{
  const int i = blockIdx.x * 256 + threadIdx.x;
  if (i == 0) *flag = 0;
  if (i < 65536) {                            // W1 [128][512] -> [512][128]
    const int k = i >> 9, n = i & 511;
    wt1hi[(size_t)n * 128 + swz_col(n, k)] = f2b(W1[i]);
  } else if (i < 196608) {                    // W2 [512][256] -> [256][512]
    const int j = i - 65536;
    const int k = j >> 8, n = j & 255;
    wt2hi[(size_t)n * 512 + swz_col(n, k)] = f2b(W2[j]);
  } else if (i < 212992) {                    // W3 [256][64] -> [64][256]
    const int j = i - 196608;
    const int k = j >> 6, n = j & 63;
    wt3hi[(size_t)n * 256 + swz_col(n, k)] = f2b(W3[j]);
  } else if (i < 217088) {                    // linW [32][128] -> [128][32] plain
    const int j = i - 212992;
    const int k = j >> 7, n = j & 127;
    const float v = linW[j];
    const ushort hi = f2b(v);
    lwThi[(size_t)n * 32 + k] = hi;
    lwTlo[(size_t)n * 32 + k] = f2b(v - b2f(hi));
  } else if (i < 233472) {                    // gatW [128][128] -> swz hi/lo
    const int j = i - 217088;
    const int k = j >> 7, n = j & 127;
    const float v = gatW[j];
    const ushort hi = f2b(v);
    const int kc = swz_col(n, k);
    gwShi[(size_t)n * 128 + kc] = hi;
    gwSlo[(size_t)n * 128 + kc] = f2b(v - b2f(hi));
  }
}

// ---------------------------------------------------------------------------
// MFMA GEMM, A bf16 x W bf16 (hi only), 2-phase dbuf pipeline.
// BM=64, BK=64, 256 threads = 4 waves (2M x 2N); wave tile 32 x BN/2.
// LDS/buf = 8KB (A) + BN*128B (B); BN=128: 24KB*2=48KB -> 3 blocks/CU.
// OMODE: 0 = fp32 linear, 1 = bf16 swizzled, 2 = bf16 linear.
// ---------------------------------------------------------------------------
template <int K, int N, int BN, bool RELU, int OMODE>
__global__ __launch_bounds__(256) void mgemm_kernel(
    const ushort* __restrict__ A, const ushort* __restrict__ Whi,
    const float* __restrict__ bias, float* __restrict__ C,
    ushort* __restrict__ Cb)
{
  constexpr int ASEG = 64 * 128;           // bytes: 64 rows x 64 bf16
  constexpr int BSEG = BN * 128;           // bytes (hi only)
  constexpr int BUF  = ASEG + BSEG;
  constexpr int NC   = BN / 32;            // 16-col frags per wave
  extern __shared__ __align__(16) char lds[];

  const int m0 = blockIdx.x * 64;
  const int n0 = blockIdx.y * BN;
  const int t = threadIdx.x;
  const int wv = t >> 6, lane = t & 63;
  const int frow = lane & 15, kq = lane >> 4;
  const int wr = (wv >> 1) * 32;
  const int wc = (wv & 1) * (BN / 2);

  f32x4 acc[2][NC];
#pragma unroll
  for (int fr = 0; fr < 2; fr++)
#pragma unroll
    for (int fc = 0; fc < NC; fc++) acc[fr][fc] = (f32x4){0.f, 0.f, 0.f, 0.f};

  auto stage = [&](int buf, int kt) {
    char* base = lds + buf * BUF;
#pragma unroll
    for (int i = 0; i < ASEG / 4096; ++i) {
      const int c = t + i * 256;
      const int row = c >> 3, ch = c & 7;
      const size_t g = (size_t)(m0 + row) * K + kt + ch * 8;
      __builtin_amdgcn_global_load_lds(
          (const __attribute__((address_space(1))) void*)(A + g),
          (__attribute__((address_space(3))) void*)(base + i * 4096 + wv * 1024), 16, 0, 0);
    }
#pragma unroll
    for (int i = 0; i < BSEG / 4096; ++i) {
      const int c = t + i * 256;
      const int row = c >> 3, ch = c & 7;
      const size_t g = (size_t)(n0 + row) * K + kt + ch * 8;
      __builtin_amdgcn_global_load_lds(
          (const __attribute__((address_space(1))) void*)(Whi + g),
          (__attribute__((address_space(3))) void*)(base + ASEG + i * 4096 + wv * 1024), 16, 0, 0);
    }
  };

  auto compute = [&](int buf) {
    char* Ah = lds + buf * BUF;
    char* Bh = Ah + ASEG;
#pragma unroll
    for (int ks = 0; ks < 2; ++ks) {
      const int cc = ks * 4 + kq;
      bf16x8 af[2], bf[NC];
#pragma unroll
      for (int fr = 0; fr < 2; ++fr) {
        const int r = wr + fr * 16 + frow;
        af[fr] = *(const bf16x8*)(Ah + r * 128 + (((cc ^ r) & 7) << 4));
      }
#pragma unroll
      for (int fc = 0; fc < NC; ++fc) {
        const int r = wc + fc * 16 + frow;
        bf[fc] = *(const bf16x8*)(Bh + r * 128 + (((cc ^ r) & 7) << 4));
      }
#pragma unroll
      for (int fr = 0; fr < 2; ++fr)
#pragma unroll
        for (int fc = 0; fc < NC; ++fc)
          acc[fr][fc] = __builtin_amdgcn_mfma_f32_16x16x32_bf16(af[fr], bf[fc], acc[fr][fc], 0, 0, 0);
    }
  };

  stage(0, 0);
  __syncthreads();
  int cur = 0;
#pragma unroll 1
  for (int kt = 0; kt < K; kt += 64) {
    if (kt + 64 < K) stage(cur ^ 1, kt + 64);
    compute(cur);
    __syncthreads();
    cur ^= 1;
  }

  const int rq = kq * 4;
#pragma unroll
  for (int fr = 0; fr < 2; fr++)
#pragma unroll
    for (int fc = 0; fc < NC; fc++)
#pragma unroll
      for (int j = 0; j < 4; j++) {
        const int row = m0 + wr + fr * 16 + rq + j;
        const int col = n0 + wc + fc * 16 + frow;
        float v = acc[fr][fc][j] + bias[col];
        if (RELU) v = fmaxf(v, 0.f);
        if constexpr (OMODE == 0) {
          C[(size_t)row * N + col] = v;
        } else if constexpr (OMODE == 1) {
          Cb[(size_t)row * N + swz_col(row, col)] = f2b(v);
        } else {
          Cb[(size_t)row * N + col] = f2b(v);
        }
      }
}

// ---------------------------------------------------------------------------
// pairs layout detection (parallel; flag pre-zeroed by convert_all)
// ---------------------------------------------------------------------------
__global__ __launch_bounds__(256) void detect_kernel(
    const unsigned long long* __restrict__ p64, int* __restrict__ flag)
{
  __shared__ int s;
  if (threadIdx.x == 0) s = 0;
  __syncthreads();
  int loc = 0;
  for (int i = blockIdx.x * 256 + threadIdx.x; i < NPAIR; i += 256 * 256)
    loc |= ((p64[i] >> 32) != 0ull) ? 1 : 0;
  if (loc) atomicOr(&s, 1);
  __syncthreads();
  if (threadIdx.x == 0 && s) atomicOr(flag, 1);
}

// ---------------------------------------------------------------------------
// final pair gather (fp32 out): [emb[pairs[:,0]], emb[pairs[:,1]]] ++ labels
// emb is bf16 linear; pairs int64 (flag=0) or packed int32 (flag=1)
// ---------------------------------------------------------------------------
__global__ __launch_bounds__(256) void gather_kernel(
    const ushort* __restrict__ embb, const unsigned long long* __restrict__ p64,
    const float* __restrict__ labels, const int* __restrict__ flagp,
    float* __restrict__ out)
{
  const int i = blockIdx.x * 256 + threadIdx.x;
  const int tot = 2 * NPAIR * OUTD;
  if (i < tot) {
    const int fl = *flagp;
    const int which = i / (NPAIR * OUTD);
    const int rem = i - which * (NPAIR * OUTD);
    const int p = rem >> 6, j = rem & 63;
    const int fi = p * 2 + which;
    int node;
    if (fl) {
      const unsigned long long w = p64[fi >> 1];
      node = (int)((fi & 1) ? (w >> 32) : (w & 0xffffffffull));
    } else {
      node = (int)p64[fi];
    }
    node &= (NTOT - 1);
    out[i] = b2f(embb[(size_t)node * OUTD + j]);
  } else if (i < tot + NPAIR) {
    out[i] = labels[i - tot];
  }
}

extern "C" void kernel_launch(void* const* d_in, const int* in_sizes, int n_in,
                              void* d_out, int out_size, void* d_ws, size_t ws_size,
                              hipStream_t stream)
{
  const float* x      = (const float*)d_in[0];
  const unsigned long long* pairs = (const unsigned long long*)d_in[2];
  const float* labels = (const float*)d_in[3];
  const float* linW   = (const float*)d_in[4];
  const float* linb   = (const float*)d_in[5];
  const float* gatW   = (const float*)d_in[6];
  const float* attS   = (const float*)d_in[7];
  const float* attD   = (const float*)d_in[8];
  const float* gatb   = (const float*)d_in[9];
  const float* W1     = (const float*)d_in[10];
  const float* b1     = (const float*)d_in[11];
  const float* W2     = (const float*)d_in[12];
  const float* b2     = (const float*)d_in[13];
  const float* W3     = (const float*)d_in[14];
  const float* b3     = (const float*)d_in[15];

  float* ws = (float*)d_ws;
  const size_t NT = NTOT;
  float*  xl   = ws;                         // [0,128)
  ushort* ghi  = (ushort*)(ws + NT * 128);   // [128,192)  N x 128 bf16 swz
  ushort* e1b  = (ushort*)(ws + NT * 192);   // [192,448)  N x 512 bf16 swz
  ushort* e2b  = (ushort*)(ws + NT * 448);   // [448,576)  N x 256 bf16 swz
  ushort* embb = (ushort*)(ws + NT * 576);   // [576,608)  N x 64  bf16 linear
  float*  asrc = ws + NT * 608;
  float*  adst = ws + NT * 609;
  ushort* wt1hi = (ushort*)(ws + NT * 610);  // [512][128]
  ushort* wt2hi = wt1hi + 512 * 128;         // [256][512]
  ushort* wt3hi = wt2hi + 256 * 512;         // [64][256]
  ushort* lwThi = wt3hi + 64 * 256;          // [128][32] plain
  ushort* lwTlo = lwThi + 128 * 32;
  ushort* gwShi = lwTlo + 128 * 32;          // [128][128] swz
  ushort* gwSlo = gwShi + 128 * 128;
  int*    flag  = (int*)(gwSlo + 128 * 128);

  constexpr int LDS1 = 2 * (64 * 128 + 128 * 128);  // 49152 (BN=128)
  constexpr int LDS3 = 2 * (64 * 128 + 64 * 128);   // 32768 (BN=64)
  (void)hipFuncSetAttribute(
      reinterpret_cast<const void*>(prep_mfma_kernel),
      hipFuncAttributeMaxDynamicSharedMemorySize, PREP_LDS);

  convert_all_kernel<<<(233472 + 255) / 256, 256, 0, stream>>>(
      W1, W2, W3, linW, gatW, wt1hi, wt2hi, wt3hi,
      lwThi, lwTlo, gwShi, gwSlo, flag);
  detect_kernel<<<256, 256, 0, stream>>>(pairs, flag);

  prep_mfma_kernel<<<NTOT / 128, 256, PREP_LDS, stream>>>(
      x, lwThi, lwTlo, linb, gwShi, gwSlo, xl);
  reduce_kernel<<<NTOT / 4, 256, 0, stream>>>(xl, attS, attD, asrc, adst);
  attn_kernel<<<NTOT / 2, 256, 0, stream>>>(xl, asrc, adst, gatb, ghi);

  mgemm_kernel<128, 512, 128, true,  1><<<dim3(NTOT / 64, 4), 256, LDS1, stream>>>(
      ghi, wt1hi, b1, nullptr, e1b);
  mgemm_kernel<512, 256, 128, true,  1><<<dim3(NTOT / 64, 2), 256, LDS1, stream>>>(
      e1b, wt2hi, b2, nullptr, e2b);
  mgemm_kernel<256,  64,  64, false, 2><<<dim3(NTOT / 64, 1), 256, LDS3, stream>>>(
      e2b, wt3hi, b3, nullptr, embb);
  const int total = 2 * NPAIR * OUTD + NPAIR;
  gather_kernel<<<(total + 255) / 256, 256, 0, stream>>>(embb, pairs, labels, flag, (float*)d_out);
}

// Round 12
// 116.517 us; speedup vs baseline: 1.7040x; 1.0009x over previous
//
#include <hip/hip_runtime.h>
#include <math.h>

#define NTOT 32768
#define NPG  2048
#define INDIM 32
#define HID  128
#define OUTD 64
#define NPAIR 100000
#define NEG_SLOPE 0.2f

typedef short bf16x8 __attribute__((ext_vector_type(8)));
typedef float f32x4 __attribute__((ext_vector_type(4)));

static __device__ __forceinline__ float b2f(ushort u) {
  return __uint_as_float(((unsigned)u) << 16);
}
static __device__ __forceinline__ ushort f2b(float f) {
  unsigned u = __float_as_uint(f);
  unsigned r = (u + 0x7fffu + ((u >> 16) & 1u)) >> 16;   // RNE
  return (ushort)r;
}
// chunk-swizzle: permute 8-bf16 (16B) chunks within each aligned 64-col group
// by row&7.  Involution; producers write swizzled global layout, GEMM stages
// linearly via global_load_lds, readers XOR on the LDS offset.
static __device__ __forceinline__ int swz_col(int row, int col) {
  return (col & ~63) | ((((col >> 3) ^ row) & 7) << 3) | (col & 7);
}
static __device__ __forceinline__ void gll16(const void* g, char* l) {
  __builtin_amdgcn_global_load_lds(
      (const __attribute__((address_space(1))) void*)g,
      (__attribute__((address_space(3))) void*)l, 16, 0, 0);
}

// ---------------------------------------------------------------------------
// MFMA prep: h = x@linW + b ; xl = h@gatW   (both split-bf16 3-term)
// ---------------------------------------------------------------------------
#define HSTR 136
#define XSTR 40
#define PREP_LDS (34816 * 2 + 65536)

__global__ __launch_bounds__(256) void prep_mfma_kernel(
    const float* __restrict__ x,
    const ushort* __restrict__ lwThi, const ushort* __restrict__ lwTlo,
    const float* __restrict__ linb,
    const ushort* __restrict__ gwShi, const ushort* __restrict__ gwSlo,
    float* __restrict__ xl)
{
  extern __shared__ __align__(16) char lds[];
  char* HS_HI = lds;
  char* HS_LO = lds + 34816;
  char* GW_HI = lds + 69632;
  char* GW_LO = lds + 102400;
  char* XS_HI = lds;
  char* XS_LO = lds + 10240;

  const int t = threadIdx.x;
  const int wv = t >> 6, lane = t & 63;
  const int frow = lane & 15, kq = lane >> 4;
  const int wr = (wv >> 1) * 64;
  const int wc = (wv & 1) * 64;
  const int m0 = blockIdx.x * 128;

#pragma unroll
  for (int i = 0; i < 8; ++i) {
    const int c = t + i * 256;
    const int row = c >> 4, ch = c & 15;
    const size_t g = (size_t)row * 128 + ch * 8;
    gll16(gwShi + g, GW_HI + i * 4096 + wv * 1024);
    gll16(gwSlo + g, GW_LO + i * 4096 + wv * 1024);
  }

  {
    const int row = t >> 1, hf = t & 1;
#pragma unroll
    for (int q = 0; q < 4; ++q) {
      const float4 v = *(const float4*)&x[(size_t)(m0 + row) * INDIM + hf * 16 + q * 4];
      ushort4 hi, lo;
      hi.x = f2b(v.x); lo.x = f2b(v.x - b2f(hi.x));
      hi.y = f2b(v.y); lo.y = f2b(v.y - b2f(hi.y));
      hi.z = f2b(v.z); lo.z = f2b(v.z - b2f(hi.z));
      hi.w = f2b(v.w); lo.w = f2b(v.w - b2f(hi.w));
      const int off = row * (XSTR * 2) + (hf * 16 + q * 4) * 2;
      *(ushort4*)(XS_HI + off) = hi;
      *(ushort4*)(XS_LO + off) = lo;
    }
  }
  __syncthreads();

  f32x4 acc1[4][4];
  {
    bf16x8 ah[4], al[4], bh[4], bl[4];
#pragma unroll
    for (int fr = 0; fr < 4; ++fr) {
      const int r = wr + fr * 16 + frow;
      const int off = r * (XSTR * 2) + kq * 16;
      ah[fr] = *(const bf16x8*)(XS_HI + off);
      al[fr] = *(const bf16x8*)(XS_LO + off);
    }
#pragma unroll
    for (int fc = 0; fc < 4; ++fc) {
      const int col = wc + fc * 16 + frow;
      bh[fc] = *(const bf16x8*)(lwThi + (size_t)col * 32 + kq * 8);
      bl[fc] = *(const bf16x8*)(lwTlo + (size_t)col * 32 + kq * 8);
    }
#pragma unroll
    for (int fr = 0; fr < 4; ++fr)
#pragma unroll
      for (int fc = 0; fc < 4; ++fc) {
        f32x4 a = (f32x4){0.f, 0.f, 0.f, 0.f};
        a = __builtin_amdgcn_mfma_f32_16x16x32_bf16(ah[fr], bh[fc], a, 0, 0, 0);
        a = __builtin_amdgcn_mfma_f32_16x16x32_bf16(ah[fr], bl[fc], a, 0, 0, 0);
        a = __builtin_amdgcn_mfma_f32_16x16x32_bf16(al[fr], bh[fc], a, 0, 0, 0);
        acc1[fr][fc] = a;
      }
  }
  __syncthreads();

#pragma unroll
  for (int fr = 0; fr < 4; ++fr)
#pragma unroll
    for (int fc = 0; fc < 4; ++fc) {
      const int col = wc + fc * 16 + frow;
      const float bj = linb[col];
#pragma unroll
      for (int j = 0; j < 4; ++j) {
        const int row = wr + fr * 16 + kq * 4 + j;
        const float v = acc1[fr][fc][j] + bj;
        const ushort hi = f2b(v);
        const int off = row * (HSTR * 2) + col * 2;
        *(ushort*)(HS_HI + off) = hi;
        *(ushort*)(HS_LO + off) = f2b(v - b2f(hi));
      }
    }
  __syncthreads();

  f32x4 acc2[4][4];
#pragma unroll
  for (int fr = 0; fr < 4; ++fr)
#pragma unroll
    for (int fc = 0; fc < 4; ++fc) acc2[fr][fc] = (f32x4){0.f, 0.f, 0.f, 0.f};
#pragma unroll
  for (int ks = 0; ks < 4; ++ks) {
    const int k = ks * 32 + kq * 8;
    bf16x8 ah[4], al[4], bh[4], bl[4];
#pragma unroll
    for (int fr = 0; fr < 4; ++fr) {
      const int r = wr + fr * 16 + frow;
      const int off = r * (HSTR * 2) + k * 2;
      ah[fr] = *(const bf16x8*)(HS_HI + off);
      al[fr] = *(const bf16x8*)(HS_LO + off);
    }
#pragma unroll
    for (int fc = 0; fc < 4; ++fc) {
      const int col = wc + fc * 16 + frow;
      const int off = col * 256 + (k & ~63) * 2 + ((((k >> 3) ^ col) & 7) << 4);
      bh[fc] = *(const bf16x8*)(GW_HI + off);
      bl[fc] = *(const bf16x8*)(GW_LO + off);
    }
#pragma unroll
    for (int fr = 0; fr < 4; ++fr)
#pragma unroll
      for (int fc = 0; fc < 4; ++fc) {
        acc2[fr][fc] = __builtin_amdgcn_mfma_f32_16x16x32_bf16(ah[fr], bh[fc], acc2[fr][fc], 0, 0, 0);
        acc2[fr][fc] = __builtin_amdgcn_mfma_f32_16x16x32_bf16(ah[fr], bl[fc], acc2[fr][fc], 0, 0, 0);
        acc2[fr][fc] = __builtin_amdgcn_mfma_f32_16x16x32_bf16(al[fr], bh[fc], acc2[fr][fc], 0, 0, 0);
      }
  }

#pragma unroll
  for (int fr = 0; fr < 4; ++fr)
#pragma unroll
    for (int fc = 0; fc < 4; ++fc)
#pragma unroll
      for (int j = 0; j < 4; ++j) {
        const int row = m0 + wr + fr * 16 + kq * 4 + j;
        const int col = wc + fc * 16 + frow;
        xl[(size_t)row * HID + col] = acc2[fr][fc][j];
      }
}

// ---------------------------------------------------------------------------
// asrc/adst: one wave per node, shuffle reduce over 128 cols of xl (fp32)
// ---------------------------------------------------------------------------
__global__ __launch_bounds__(256) void reduce_kernel(
    const float* __restrict__ xl, const float* __restrict__ attS,
    const float* __restrict__ attD, float* __restrict__ asrc,
    float* __restrict__ adst)
{
  const int n = blockIdx.x * 4 + (threadIdx.x >> 6);
  const int l = threadIdx.x & 63;
  const float x0 = xl[(size_t)n * HID + l];
  const float x1 = xl[(size_t)n * HID + 64 + l];
  float s = fmaf(x0, attS[l], x1 * attS[64 + l]);
  float d = fmaf(x0, attD[l], x1 * attD[64 + l]);
#pragma unroll
  for (int sh = 32; sh > 0; sh >>= 1) {
    s += __shfl_xor(s, sh, 64);
    d += __shfl_xor(d, sh, 64);
  }
  if (l == 0) { asrc[n] = s; adst[n] = d; }
}

// ---------------------------------------------------------------------------
// MEGA kernel: attention + 3-layer MLP fused; all intermediates in LDS.
// Per block: 64 rows.  256 threads = 4 waves (2x2).
// LDS: R1 ghi 16K | R2 64K (xl+hub, then e1, then W3) | R3 64K (W dbuf, then e2)
//      RWR wrow [64][18] f32 | RGB gatb [128] f32
// ---------------------------------------------------------------------------
#define R1O 0
#define R2O 16384
#define R3O 81920
#define RWR 147456
#define RGB 152064
#define MEGA_LDS 152576

__global__ __launch_bounds__(256) void mega_kernel(
    const float* __restrict__ xl, const float* __restrict__ asrc,
    const float* __restrict__ adst, const float* __restrict__ gatb,
    const ushort* __restrict__ wt1hi, const ushort* __restrict__ wt2hi,
    const ushort* __restrict__ wt3hi,
    const float* __restrict__ b1, const float* __restrict__ b2,
    const float* __restrict__ b3, ushort* __restrict__ embb)
{
  extern __shared__ __align__(16) char lds[];
  const int t = threadIdx.x;
  const int wv = t >> 6, lane = t & 63;
  const int frow = lane & 15, kq = lane >> 4;
  const int wrow = (wv >> 1) * 32;
  const int wch = wv & 1;
  const int m0 = blockIdx.x * 64;
  const int gb = m0 & ~(NPG - 1);

  // ---- stage: xl tile (32KB), hub rows (12KB), W1 half0 (64KB) ----
#pragma unroll
  for (int i = 0; i < 8; ++i) {      // xl tile: 2048 chunks
    const int c = t + i * 256;
    gll16(xl + (size_t)(m0 + (c >> 5)) * HID + (c & 31) * 4,
          lds + R2O + i * 4096 + wv * 1024);
  }
#pragma unroll
  for (int i = 0; i < 3; ++i) {      // hub rows gb+0..23: 768 chunks
    const int c = t + i * 256;
    gll16(xl + (size_t)(gb + (c >> 5)) * HID + (c & 31) * 4,
          lds + R2O + 32768 + i * 4096 + wv * 1024);
  }
#pragma unroll
  for (int i = 0; i < 16; ++i) {     // W1t rows 0..255: 4096 chunks
    const int c = t + i * 256;
    gll16(wt1hi + (size_t)(c >> 4) * 128 + (c & 15) * 8,
          lds + R3O + i * 4096 + wv * 1024);
  }
  // gatb to LDS (threads 64..191)
  if (t >= 64 && t < 192) ((float*)(lds + RGB))[t - 64] = gatb[t - 64];

  // ---- softmax weights (threads 0..63, one row each) ----
  float* wr = (float*)(lds + RWR);
  if (t < 64) {
    const int n = m0 + t;
    const int loc = n & (NPG - 1);
    float a[17];
#pragma unroll
    for (int k = 0; k < 17; ++k) {
      int c;
      if (k < 16) { const int nb = (loc < 16) ? ((k < loc) ? k : k + 1) : k; c = gb + nb; }
      else c = n;
      a[k] = asrc[c];
    }
    const float ad = adst[n];
    float m = -__builtin_inff();
#pragma unroll
    for (int k = 0; k < 17; ++k) {
      float l = a[k] + ad;
      l = (l > 0.f) ? l : NEG_SLOPE * l;
      m = fmaxf(m, l);
    }
    float den = 0.f;
#pragma unroll
    for (int k = 0; k < 17; ++k) {
      float l = a[k] + ad;
      l = (l > 0.f) ? l : NEG_SLOPE * l;
      const float w = __expf(l - m);
      wr[t * 18 + k] = w;
      den += w;
    }
    wr[t * 18 + 17] = 1.f / den;
  }
  __syncthreads();   // staging drained + wr/gatb visible

  // ---- weighted sum -> ghi tile (R1, bf16 swizzled) ----
  {
    const float* xs = (const float*)(lds + R2O);
    const float* hs = (const float*)(lds + R2O + 32768);
    const float* gs = (const float*)(lds + RGB);
#pragma unroll 1
    for (int oi = 0; oi < 32; ++oi) {
      const int idx = t + oi * 256;
      const int r = idx >> 7, j = idx & 127;
      const int loc = (m0 + r) & (NPG - 1);
      float acc = 0.f;
#pragma unroll
      for (int k = 0; k < 16; ++k) {
        const int nb = (loc < 16) ? ((k < loc) ? k : k + 1) : k;
        acc = fmaf(wr[r * 18 + k], hs[nb * 128 + j], acc);
      }
      acc = fmaf(wr[r * 18 + 16], xs[r * 128 + j], acc);
      const float v = acc * wr[r * 18 + 17] + gs[j];
      const int off = r * 256 + ((j >> 6) << 7) + ((((j >> 3) & 7) ^ (r & 7)) << 4) + ((j & 7) << 1);
      *(ushort*)(lds + R1O + off) = f2b(v);
    }
  }
  __syncthreads();   // ghi ready; xl/hub regions dead

  // ---- phase 1: e1 = relu(ghi @ W1 + b1), two 256-col halves ----
#pragma unroll 1
  for (int h = 0; h < 2; ++h) {
    f32x4 acc[2][8];
#pragma unroll
    for (int fr = 0; fr < 2; ++fr)
#pragma unroll
      for (int fc = 0; fc < 8; ++fc) acc[fr][fc] = (f32x4){0.f, 0.f, 0.f, 0.f};
#pragma unroll
    for (int ks = 0; ks < 4; ++ks) {
      const int cc = ks * 4 + kq;                      // 0..15
      bf16x8 af[2], bf[8];
#pragma unroll
      for (int fr = 0; fr < 2; ++fr) {
        const int r = wrow + fr * 16 + frow;
        af[fr] = *(const bf16x8*)(lds + R1O + r * 256 + ((cc >> 3) << 7) + (((cc & 7) ^ (r & 7)) << 4));
      }
#pragma unroll
      for (int fc = 0; fc < 8; ++fc) {
        const int rb = wch * 128 + fc * 16 + frow;
        bf[fc] = *(const bf16x8*)(lds + R3O + rb * 256 + ((cc >> 3) << 7) + (((cc & 7) ^ (rb & 7)) << 4));
      }
#pragma unroll
      for (int fr = 0; fr < 2; ++fr)
#pragma unroll
        for (int fc = 0; fc < 8; ++fc)
          acc[fr][fc] = __builtin_amdgcn_mfma_f32_16x16x32_bf16(af[fr], bf[fc], acc[fr][fc], 0, 0, 0);
    }
    __syncthreads();   // R3 reads done
    // epilogue -> e1 (R2), and stage next B
#pragma unroll
    for (int fr = 0; fr < 2; ++fr)
#pragma unroll
      for (int fc = 0; fc < 8; ++fc)
#pragma unroll
        for (int j = 0; j < 4; ++j) {
          const int row = wrow + fr * 16 + kq * 4 + j;
          const int colg = h * 256 + wch * 128 + fc * 16 + frow;
          float v = acc[fr][fc][j] + b1[colg];
          v = fmaxf(v, 0.f);
          const int off = row * 1024 + ((colg >> 6) << 7) + ((((colg >> 3) & 7) ^ (row & 7)) << 4) + ((colg & 7) << 1);
          *(ushort*)(lds + R2O + off) = f2b(v);
        }
    if (h == 0) {
#pragma unroll
      for (int i = 0; i < 16; ++i) {   // W1t rows 256..511
        const int c = t + i * 256;
        gll16(wt1hi + (size_t)(256 + (c >> 4)) * 128 + (c & 15) * 8,
              lds + R3O + i * 4096 + wv * 1024);
      }
    } else {
#pragma unroll
      for (int i = 0; i < 8; ++i) {    // W2 chunk 0: [256][64]
        const int c = t + i * 256;
        gll16(wt2hi + (size_t)(c >> 3) * 512 + (c & 7) * 8,
              lds + R3O + i * 4096 + wv * 1024);
      }
    }
    __syncthreads();
  }

  // ---- phase 2: e2 = relu(e1 @ W2 + b2), K=512, 8 chunks dbuf ----
  f32x4 acc2[2][8];
#pragma unroll
  for (int fr = 0; fr < 2; ++fr)
#pragma unroll
    for (int fc = 0; fc < 8; ++fc) acc2[fr][fc] = (f32x4){0.f, 0.f, 0.f, 0.f};
#pragma unroll 1
  for (int kc = 0; kc < 8; ++kc) {
    if (kc < 7) {
      char* dst = lds + R3O + ((kc + 1) & 1) * 32768;
#pragma unroll
      for (int i = 0; i < 8; ++i) {
        const int c = t + i * 256;
        gll16(wt2hi + (size_t)(c >> 3) * 512 + (kc + 1) * 64 + (c & 7) * 8,
              dst + i * 4096 + wv * 1024);
      }
    }
    char* Bb = lds + R3O + (kc & 1) * 32768;
#pragma unroll
    for (int ks = 0; ks < 2; ++ks) {
      const int cl = ks * 4 + kq;                      // 0..7
      bf16x8 af[2], bf[8];
#pragma unroll
      for (int fr = 0; fr < 2; ++fr) {
        const int r = wrow + fr * 16 + frow;
        af[fr] = *(const bf16x8*)(lds + R2O + r * 1024 + (kc << 7) + ((cl ^ (r & 7)) << 4));
      }
#pragma unroll
      for (int fc = 0; fc < 8; ++fc) {
        const int rb = wch * 128 + fc * 16 + frow;
        bf[fc] = *(const bf16x8*)(Bb + rb * 128 + ((cl ^ (rb & 7)) << 4));
      }
#pragma unroll
      for (int fr = 0; fr < 2; ++fr)
#pragma unroll
        for (int fc = 0; fc < 8; ++fc)
          acc2[fr][fc] = __builtin_amdgcn_mfma_f32_16x16x32_bf16(af[fr], bf[fc], acc2[fr][fc], 0, 0, 0);
    }
    __syncthreads();
  }
  // epilogue -> e2 (R3 base), stage W3 -> R2 base
#pragma unroll
  for (int fr = 0; fr < 2; ++fr)
#pragma unroll
    for (int fc = 0; fc < 8; ++fc)
#pragma unroll
      for (int j = 0; j < 4; ++j) {
        const int row = wrow + fr * 16 + kq * 4 + j;
        const int col = wch * 128 + fc * 16 + frow;
        float v = acc2[fr][fc][j] + b2[col];
        v = fmaxf(v, 0.f);
        const int off = row * 512 + ((col >> 6) << 7) + ((((col >> 3) & 7) ^ (row & 7)) << 4) + ((col & 7) << 1);
        *(ushort*)(lds + R3O + off) = f2b(v);
      }
#pragma unroll
  for (int i = 0; i < 8; ++i) {   // W3t [64][256] = 32KB
    const int c = t + i * 256;
    gll16(wt3hi + (size_t)(c >> 5) * 256 + (c & 31) * 8,
          lds + R2O + i * 4096 + wv * 1024);
  }
  __syncthreads();

  // ---- phase 3: emb = e2 @ W3 + b3, K=256 ----
  f32x4 acc3[2][2];
#pragma unroll
  for (int fr = 0; fr < 2; ++fr)
#pragma unroll
    for (int fc = 0; fc < 2; ++fc) acc3[fr][fc] = (f32x4){0.f, 0.f, 0.f, 0.f};
#pragma unroll
  for (int ks = 0; ks < 8; ++ks) {
    const int cc = ks * 4 + kq;                        // 0..31
    bf16x8 af[2], bf[2];
#pragma unroll
    for (int fr = 0; fr < 2; ++fr) {
      const int r = wrow + fr * 16 + frow;
      af[fr] = *(const bf16x8*)(lds + R3O + r * 512 + ((cc >> 3) << 7) + (((cc & 7) ^ (r & 7)) << 4));
    }
#pragma unroll
    for (int fc = 0; fc < 2; ++fc) {
      const int rb = wch * 32 + fc * 16 + frow;
      bf[fc] = *(const bf16x8*)(lds + R2O + rb * 512 + ((cc >> 3) << 7) + (((cc & 7) ^ (rb & 7)) << 4));
    }
#pragma unroll
    for (int fr = 0; fr < 2; ++fr)
#pragma unroll
      for (int fc = 0; fc < 2; ++fc)
        acc3[fr][fc] = __builtin_amdgcn_mfma_f32_16x16x32_bf16(af[fr], bf[fc], acc3[fr][fc], 0, 0, 0);
  }
#pragma unroll
  for (int fr = 0; fr < 2; ++fr)
#pragma unroll
    for (int fc = 0; fc < 2; ++fc)
#pragma unroll
      for (int j = 0; j < 4; ++j) {
        const int row = m0 + wrow + fr * 16 + kq * 4 + j;
        const int col = wch * 32 + fc * 16 + frow;
        embb[(size_t)row * OUTD + col] = f2b(acc3[fr][fc][j] + b3[col]);
      }
}

// ---------------------------------------------------------------------------
// fused weight conversion (one launch) + flag init
// ---------------------------------------------------------------------------
__global__ __launch_bounds__(256) void convert_all_kernel(
    const float* __restrict__ W1, const float* __restrict__ W2,
    const float* __restrict__ W3, const float* __restrict__ linW,
    const float* __restrict__ gatW,
    ushort* __restrict__ wt1hi, ushort* __restrict__ wt2hi,
    ushort* __restrict__ wt3hi,
    ushort* __restrict__ lwThi, ushort* __restrict__ lwTlo,
    ushort* __restrict__ gwShi, ushort* __restrict__ gwSlo,
    int* __restrict__ flag)
{
  const int i = blockIdx.x * 256 + threadIdx.x;
  if (i == 0) *flag = 0;
  if (i < 65536) {                            // W1 [128][512] -> [512][128]
    const int k = i >> 9, n = i & 511;
    wt1hi[(size_t)n * 128 + swz_col(n, k)] = f2b(W1[i]);
  } else if (i < 196608) {                    // W2 [512][256] -> [256][512]
    const int j = i - 65536;
    const int k = j >> 8, n = j & 255;
    wt2hi[(size_t)n * 512 + swz_col(n, k)] = f2b(W2[j]);
  } else if (i < 212992) {                    // W3 [256][64] -> [64][256]
    const int j = i - 196608;
    const int k = j >> 6, n = j & 63;
    wt3hi[(size_t)n * 256 + swz_col(n, k)] = f2b(W3[j]);
  } else if (i < 217088) {                    // linW [32][128] -> [128][32]
    const int j = i - 212992;
    const int k = j >> 7, n = j & 127;
    const float v = linW[j];
    const ushort hi = f2b(v);
    lwThi[(size_t)n * 32 + k] = hi;
    lwTlo[(size_t)n * 32 + k] = f2b(v - b2f(hi));
  } else if (i < 233472) {                    // gatW [128][128] -> swz hi/lo
    const int j = i - 217088;
    const int k = j >> 7, n = j & 127;
    const float v = gatW[j];
    const ushort hi = f2b(v);
    const int kc = swz_col(n, k);
    gwShi[(size_t)n * 128 + kc] = hi;
    gwSlo[(size_t)n * 128 + kc] = f2b(v - b2f(hi));
  }
}

// ---------------------------------------------------------------------------
// pairs layout detection (parallel; flag pre-zeroed by convert_all)
// ---------------------------------------------------------------------------
__global__ __launch_bounds__(256) void detect_kernel(
    const unsigned long long* __restrict__ p64, int* __restrict__ flag)
{
  __shared__ int s;
  if (threadIdx.x == 0) s = 0;
  __syncthreads();
  int loc = 0;
  for (int i = blockIdx.x * 256 + threadIdx.x; i < NPAIR; i += 256 * 256)
    loc |= ((p64[i] >> 32) != 0ull) ? 1 : 0;
  if (loc) atomicOr(&s, 1);
  __syncthreads();
  if (threadIdx.x == 0 && s) atomicOr(flag, 1);
}

// ---------------------------------------------------------------------------
// final pair gather (fp32 out)
// ---------------------------------------------------------------------------
__global__ __launch_bounds__(256) void gather_kernel(
    const ushort* __restrict__ embb, const unsigned long long* __restrict__ p64,
    const float* __restrict__ labels, const int* __restrict__ flagp,
    float* __restrict__ out)
{
  const int i = blockIdx.x * 256 + threadIdx.x;
  const int tot = 2 * NPAIR * OUTD;
  if (i < tot) {
    const int fl = *flagp;
    const int which = i / (NPAIR * OUTD);
    const int rem = i - which * (NPAIR * OUTD);
    const int p = rem >> 6, j = rem & 63;
    const int fi = p * 2 + which;
    int node;
    if (fl) {
      const unsigned long long w = p64[fi >> 1];
      node = (int)((fi & 1) ? (w >> 32) : (w & 0xffffffffull));
    } else {
      node = (int)p64[fi];
    }
    node &= (NTOT - 1);
    out[i] = b2f(embb[(size_t)node * OUTD + j]);
  } else if (i < tot + NPAIR) {
    out[i] = labels[i - tot];
  }
}

extern "C" void kernel_launch(void* const* d_in, const int* in_sizes, int n_in,
                              void* d_out, int out_size, void* d_ws, size_t ws_size,
                              hipStream_t stream)
{
  const float* x      = (const float*)d_in[0];
  const unsigned long long* pairs = (const unsigned long long*)d_in[2];
  const float* labels = (const float*)d_in[3];
  const float* linW   = (const float*)d_in[4];
  const float* linb   = (const float*)d_in[5];
  const float* gatW   = (const float*)d_in[6];
  const float* attS   = (const float*)d_in[7];
  const float* attD   = (const float*)d_in[8];
  const float* gatb   = (const float*)d_in[9];
  const float* W1     = (const float*)d_in[10];
  const float* b1     = (const float*)d_in[11];
  const float* W2     = (const float*)d_in[12];
  const float* b2     = (const float*)d_in[13];
  const float* W3     = (const float*)d_in[14];
  const float* b3     = (const float*)d_in[15];

  float* ws = (float*)d_ws;
  const size_t NT = NTOT;
  float*  xl    = ws;                        // [0,128)
  ushort* embb  = (ushort*)(ws + NT * 128);  // [128,160)
  float*  asrc  = ws + NT * 160;
  float*  adst  = ws + NT * 161;
  ushort* wt1hi = (ushort*)(ws + NT * 162);  // [512][128]
  ushort* wt2hi = wt1hi + 512 * 128;         // [256][512]
  ushort* wt3hi = wt2hi + 256 * 512;         // [64][256]
  ushort* lwThi = wt3hi + 64 * 256;          // [128][32]
  ushort* lwTlo = lwThi + 128 * 32;
  ushort* gwShi = lwTlo + 128 * 32;          // [128][128]
  ushort* gwSlo = gwShi + 128 * 128;
  int*    flag  = (int*)(gwSlo + 128 * 128);

  (void)hipFuncSetAttribute(
      reinterpret_cast<const void*>(prep_mfma_kernel),
      hipFuncAttributeMaxDynamicSharedMemorySize, PREP_LDS);
  (void)hipFuncSetAttribute(
      reinterpret_cast<const void*>(mega_kernel),
      hipFuncAttributeMaxDynamicSharedMemorySize, MEGA_LDS);

  convert_all_kernel<<<(233472 + 255) / 256, 256, 0, stream>>>(
      W1, W2, W3, linW, gatW, wt1hi, wt2hi, wt3hi,
      lwThi, lwTlo, gwShi, gwSlo, flag);
  detect_kernel<<<256, 256, 0, stream>>>(pairs, flag);

  prep_mfma_kernel<<<NTOT / 128, 256, PREP_LDS, stream>>>(
      x, lwThi, lwTlo, linb, gwShi, gwSlo, xl);
  reduce_kernel<<<NTOT / 4, 256, 0, stream>>>(xl, attS, attD, asrc, adst);

  mega_kernel<<<NTOT / 64, 256, MEGA_LDS, stream>>>(
      xl, asrc, adst, gatb, wt1hi, wt2hi, wt3hi, b1, b2, b3, embb);

  const int total = 2 * NPAIR * OUTD + NPAIR;
  gather_kernel<<<(total + 255) / 256, 256, 0, stream>>>(embb, pairs, labels, flag, (float*)d_out);
}

// Round 13
// 101.700 us; speedup vs baseline: 1.9522x; 1.1457x over previous
//
#include <hip/hip_runtime.h>
#include <math.h>

#define NTOT 32768
#define NPG  2048
#define INDIM 32
#define HID  128
#define OUTD 64
#define NPAIR 100000
#define NEG_SLOPE 0.2f

typedef short bf16x8 __attribute__((ext_vector_type(8)));
typedef float f32x4 __attribute__((ext_vector_type(4)));

static __device__ __forceinline__ float b2f(ushort u) {
  return __uint_as_float(((unsigned)u) << 16);
}
static __device__ __forceinline__ ushort f2b(float f) {
  unsigned u = __float_as_uint(f);
  unsigned r = (u + 0x7fffu + ((u >> 16) & 1u)) >> 16;   // RNE
  return (ushort)r;
}
// chunk-swizzle: permute 8-bf16 (16B) chunks within each aligned 64-col group
// by row&7.  Involution; producers write swizzled global layout, GEMM stages
// linearly via global_load_lds, readers XOR on the LDS offset.
static __device__ __forceinline__ int swz_col(int row, int col) {
  return (col & ~63) | ((((col >> 3) ^ row) & 7) << 3) | (col & 7);
}
static __device__ __forceinline__ void gll16(const void* g, char* l) {
  __builtin_amdgcn_global_load_lds(
      (const __attribute__((address_space(1))) void*)g,
      (__attribute__((address_space(3))) void*)l, 16, 0, 0);
}

// ---------------------------------------------------------------------------
// MFMA prep: h = x@linW + b ; xl = h@gatW   (both split-bf16 3-term)
// ---------------------------------------------------------------------------
#define HSTR 136
#define XSTR 40
#define PREP_LDS (34816 * 2 + 65536)

__global__ __launch_bounds__(256) void prep_mfma_kernel(
    const float* __restrict__ x,
    const ushort* __restrict__ lwThi, const ushort* __restrict__ lwTlo,
    const float* __restrict__ linb,
    const ushort* __restrict__ gwShi, const ushort* __restrict__ gwSlo,
    float* __restrict__ xl)
{
  extern __shared__ __align__(16) char lds[];
  char* HS_HI = lds;
  char* HS_LO = lds + 34816;
  char* GW_HI = lds + 69632;
  char* GW_LO = lds + 102400;
  char* XS_HI = lds;
  char* XS_LO = lds + 10240;

  const int t = threadIdx.x;
  const int wv = t >> 6, lane = t & 63;
  const int frow = lane & 15, kq = lane >> 4;
  const int wr = (wv >> 1) * 64;
  const int wc = (wv & 1) * 64;
  const int m0 = blockIdx.x * 128;

#pragma unroll
  for (int i = 0; i < 8; ++i) {
    const int c = t + i * 256;
    const int row = c >> 4, ch = c & 15;
    const size_t g = (size_t)row * 128 + ch * 8;
    gll16(gwShi + g, GW_HI + i * 4096 + wv * 1024);
    gll16(gwSlo + g, GW_LO + i * 4096 + wv * 1024);
  }

  {
    const int row = t >> 1, hf = t & 1;
#pragma unroll
    for (int q = 0; q < 4; ++q) {
      const float4 v = *(const float4*)&x[(size_t)(m0 + row) * INDIM + hf * 16 + q * 4];
      ushort4 hi, lo;
      hi.x = f2b(v.x); lo.x = f2b(v.x - b2f(hi.x));
      hi.y = f2b(v.y); lo.y = f2b(v.y - b2f(hi.y));
      hi.z = f2b(v.z); lo.z = f2b(v.z - b2f(hi.z));
      hi.w = f2b(v.w); lo.w = f2b(v.w - b2f(hi.w));
      const int off = row * (XSTR * 2) + (hf * 16 + q * 4) * 2;
      *(ushort4*)(XS_HI + off) = hi;
      *(ushort4*)(XS_LO + off) = lo;
    }
  }
  __syncthreads();

  f32x4 acc1[4][4];
  {
    bf16x8 ah[4], al[4], bh[4], bl[4];
#pragma unroll
    for (int fr = 0; fr < 4; ++fr) {
      const int r = wr + fr * 16 + frow;
      const int off = r * (XSTR * 2) + kq * 16;
      ah[fr] = *(const bf16x8*)(XS_HI + off);
      al[fr] = *(const bf16x8*)(XS_LO + off);
    }
#pragma unroll
    for (int fc = 0; fc < 4; ++fc) {
      const int col = wc + fc * 16 + frow;
      bh[fc] = *(const bf16x8*)(lwThi + (size_t)col * 32 + kq * 8);
      bl[fc] = *(const bf16x8*)(lwTlo + (size_t)col * 32 + kq * 8);
    }
#pragma unroll
    for (int fr = 0; fr < 4; ++fr)
#pragma unroll
      for (int fc = 0; fc < 4; ++fc) {
        f32x4 a = (f32x4){0.f, 0.f, 0.f, 0.f};
        a = __builtin_amdgcn_mfma_f32_16x16x32_bf16(ah[fr], bh[fc], a, 0, 0, 0);
        a = __builtin_amdgcn_mfma_f32_16x16x32_bf16(ah[fr], bl[fc], a, 0, 0, 0);
        a = __builtin_amdgcn_mfma_f32_16x16x32_bf16(al[fr], bh[fc], a, 0, 0, 0);
        acc1[fr][fc] = a;
      }
  }
  __syncthreads();

#pragma unroll
  for (int fr = 0; fr < 4; ++fr)
#pragma unroll
    for (int fc = 0; fc < 4; ++fc) {
      const int col = wc + fc * 16 + frow;
      const float bj = linb[col];
#pragma unroll
      for (int j = 0; j < 4; ++j) {
        const int row = wr + fr * 16 + kq * 4 + j;
        const float v = acc1[fr][fc][j] + bj;
        const ushort hi = f2b(v);
        const int off = row * (HSTR * 2) + col * 2;
        *(ushort*)(HS_HI + off) = hi;
        *(ushort*)(HS_LO + off) = f2b(v - b2f(hi));
      }
    }
  __syncthreads();

  f32x4 acc2[4][4];
#pragma unroll
  for (int fr = 0; fr < 4; ++fr)
#pragma unroll
    for (int fc = 0; fc < 4; ++fc) acc2[fr][fc] = (f32x4){0.f, 0.f, 0.f, 0.f};
#pragma unroll
  for (int ks = 0; ks < 4; ++ks) {
    const int k = ks * 32 + kq * 8;
    bf16x8 ah[4], al[4], bh[4], bl[4];
#pragma unroll
    for (int fr = 0; fr < 4; ++fr) {
      const int r = wr + fr * 16 + frow;
      const int off = r * (HSTR * 2) + k * 2;
      ah[fr] = *(const bf16x8*)(HS_HI + off);
      al[fr] = *(const bf16x8*)(HS_LO + off);
    }
#pragma unroll
    for (int fc = 0; fc < 4; ++fc) {
      const int col = wc + fc * 16 + frow;
      const int off = col * 256 + (k & ~63) * 2 + ((((k >> 3) ^ col) & 7) << 4);
      bh[fc] = *(const bf16x8*)(GW_HI + off);
      bl[fc] = *(const bf16x8*)(GW_LO + off);
    }
#pragma unroll
    for (int fr = 0; fr < 4; ++fr)
#pragma unroll
      for (int fc = 0; fc < 4; ++fc) {
        acc2[fr][fc] = __builtin_amdgcn_mfma_f32_16x16x32_bf16(ah[fr], bh[fc], acc2[fr][fc], 0, 0, 0);
        acc2[fr][fc] = __builtin_amdgcn_mfma_f32_16x16x32_bf16(ah[fr], bl[fc], acc2[fr][fc], 0, 0, 0);
        acc2[fr][fc] = __builtin_amdgcn_mfma_f32_16x16x32_bf16(al[fr], bh[fc], acc2[fr][fc], 0, 0, 0);
      }
  }

#pragma unroll
  for (int fr = 0; fr < 4; ++fr)
#pragma unroll
    for (int fc = 0; fc < 4; ++fc)
#pragma unroll
      for (int j = 0; j < 4; ++j) {
        const int row = m0 + wr + fr * 16 + kq * 4 + j;
        const int col = wc + fc * 16 + frow;
        xl[(size_t)row * HID + col] = acc2[fr][fc][j];
      }
}

// ---------------------------------------------------------------------------
// asrc/adst: one wave per node, shuffle reduce over 128 cols of xl (fp32)
// ---------------------------------------------------------------------------
__global__ __launch_bounds__(256) void reduce_kernel(
    const float* __restrict__ xl, const float* __restrict__ attS,
    const float* __restrict__ attD, float* __restrict__ asrc,
    float* __restrict__ adst)
{
  const int n = blockIdx.x * 4 + (threadIdx.x >> 6);
  const int l = threadIdx.x & 63;
  const float x0 = xl[(size_t)n * HID + l];
  const float x1 = xl[(size_t)n * HID + 64 + l];
  float s = fmaf(x0, attS[l], x1 * attS[64 + l]);
  float d = fmaf(x0, attD[l], x1 * attD[64 + l]);
#pragma unroll
  for (int sh = 32; sh > 0; sh >>= 1) {
    s += __shfl_xor(s, sh, 64);
    d += __shfl_xor(d, sh, 64);
  }
  if (l == 0) { asrc[n] = s; adst[n] = d; }
}

// ---------------------------------------------------------------------------
// MEGA v2: attention + 3-layer MLP fused, 512 threads = 8 waves (2/SIMD).
// Per block: 64 rows.  Phase1 in 4 pipelined 128-col quarters (W1 32KB dbuf),
// phase2 8 pipelined W2 K-chunks, phase3 from LDS.  All intermediates in LDS.
// LDS: R1 ghi 16K | R2 64K (xl+hub -> e1 -> W3) | R3 64K (W dbuf -> e2)
// ---------------------------------------------------------------------------
#define R1O 0
#define R2O 16384
#define R3O 81920
#define RWR 147456
#define RGB 152064
#define MEGA_LDS 152576

__global__ __launch_bounds__(512) void mega_kernel(
    const float* __restrict__ xl, const float* __restrict__ asrc,
    const float* __restrict__ adst, const float* __restrict__ gatb,
    const ushort* __restrict__ wt1hi, const ushort* __restrict__ wt2hi,
    const ushort* __restrict__ wt3hi,
    const float* __restrict__ b1, const float* __restrict__ b2,
    const float* __restrict__ b3, ushort* __restrict__ embb)
{
  extern __shared__ __align__(16) char lds[];
  const int t = threadIdx.x;
  const int wv = t >> 6, lane = t & 63;
  const int frow = lane & 15, kq = lane >> 4;
  const int wrow = (wv >> 2) * 32;       // M-half of the 64-row tile
  const int wq = wv & 3;                 // N-quarter within phase tiles
  const int m0 = blockIdx.x * 64;
  const int gb = m0 & ~(NPG - 1);

  // ---- stage: xl tile (32KB), hub rows (12KB), W1 quarter0 (32KB) ----
#pragma unroll
  for (int i = 0; i < 4; ++i) {          // xl: 2048 chunks
    const int c = t + i * 512;
    gll16(xl + (size_t)(m0 + (c >> 5)) * HID + (c & 31) * 4,
          lds + R2O + i * 8192 + wv * 1024);
  }
#pragma unroll
  for (int i = 0; i < 2; ++i) {          // hub rows gb+0..23: 768 chunks
    const int c = t + i * 512;
    if (c < 768)
      gll16(xl + (size_t)(gb + (c >> 5)) * HID + (c & 31) * 4,
            lds + R2O + 32768 + i * 8192 + wv * 1024);
  }
#pragma unroll
  for (int i = 0; i < 4; ++i) {          // W1t rows 0..127 -> R3 half0
    const int c = t + i * 512;
    gll16(wt1hi + (size_t)(c >> 4) * 128 + (c & 15) * 8,
          lds + R3O + i * 8192 + wv * 1024);
  }
  if (t >= 64 && t < 192) ((float*)(lds + RGB))[t - 64] = gatb[t - 64];

  // ---- softmax weights (wave 0, one row per lane) ----
  float* wr = (float*)(lds + RWR);
  if (t < 64) {
    const int n = m0 + t;
    const int loc = n & (NPG - 1);
    float a[17];
#pragma unroll
    for (int k = 0; k < 17; ++k) {
      int c;
      if (k < 16) { const int nb = (loc < 16) ? ((k < loc) ? k : k + 1) : k; c = gb + nb; }
      else c = n;
      a[k] = asrc[c];
    }
    const float ad = adst[n];
    float m = -__builtin_inff();
#pragma unroll
    for (int k = 0; k < 17; ++k) {
      float l = a[k] + ad;
      l = (l > 0.f) ? l : NEG_SLOPE * l;
      m = fmaxf(m, l);
    }
    float den = 0.f;
#pragma unroll
    for (int k = 0; k < 17; ++k) {
      float l = a[k] + ad;
      l = (l > 0.f) ? l : NEG_SLOPE * l;
      const float w = __expf(l - m);
      wr[t * 18 + k] = w;
      den += w;
    }
    wr[t * 18 + 17] = 1.f / den;
  }
  __syncthreads();   // staging drained + wr/gatb visible

  // ---- weighted sum -> ghi tile (R1, bf16 swizzled), 512 threads ----
  {
    const float* xs = (const float*)(lds + R2O);
    const float* hs = (const float*)(lds + R2O + 32768);
    const float* gs = (const float*)(lds + RGB);
#pragma unroll 1
    for (int oi = 0; oi < 16; ++oi) {
      const int idx = t + oi * 512;
      const int r = idx >> 7, j = idx & 127;
      const int loc = (m0 + r) & (NPG - 1);
      float acc = 0.f;
#pragma unroll
      for (int k = 0; k < 16; ++k) {
        const int nb = (loc < 16) ? ((k < loc) ? k : k + 1) : k;
        acc = fmaf(wr[r * 18 + k], hs[nb * 128 + j], acc);
      }
      acc = fmaf(wr[r * 18 + 16], xs[r * 128 + j], acc);
      const float v = acc * wr[r * 18 + 17] + gs[j];
      const int off = r * 256 + ((j >> 6) << 7) + ((((j >> 3) & 7) ^ (r & 7)) << 4) + ((j & 7) << 1);
      *(ushort*)(lds + R1O + off) = f2b(v);
    }
  }
  __syncthreads();   // ghi ready; xl/hub dead

  // ---- phase 1: e1 = relu(ghi @ W1 + b1), 4 pipelined 128-col quarters ----
#pragma unroll 1
  for (int q = 0; q < 4; ++q) {
    if (q < 3) {                         // stage next W1 quarter
      char* dst = lds + R3O + ((q + 1) & 1) * 32768;
#pragma unroll
      for (int i = 0; i < 4; ++i) {
        const int c = t + i * 512;
        gll16(wt1hi + (size_t)((q + 1) * 128 + (c >> 4)) * 128 + (c & 15) * 8,
              dst + i * 8192 + wv * 1024);
      }
    } else {                             // stage W2 chunk0 -> half0
#pragma unroll
      for (int i = 0; i < 4; ++i) {
        const int c = t + i * 512;
        gll16(wt2hi + (size_t)(c >> 3) * 512 + (c & 7) * 8,
              lds + R3O + i * 8192 + wv * 1024);
      }
    }
    char* Bq = lds + R3O + (q & 1) * 32768;
    f32x4 acc[2][2];
#pragma unroll
    for (int fr = 0; fr < 2; ++fr)
#pragma unroll
      for (int fc = 0; fc < 2; ++fc) acc[fr][fc] = (f32x4){0.f, 0.f, 0.f, 0.f};
#pragma unroll
    for (int ks = 0; ks < 4; ++ks) {
      const int cc = ks * 4 + kq;        // 0..15
      bf16x8 af[2], bf[2];
#pragma unroll
      for (int fr = 0; fr < 2; ++fr) {
        const int r = wrow + fr * 16 + frow;
        af[fr] = *(const bf16x8*)(lds + R1O + r * 256 + ((cc >> 3) << 7) + (((cc & 7) ^ (r & 7)) << 4));
      }
#pragma unroll
      for (int fc = 0; fc < 2; ++fc) {
        const int rb = wq * 32 + fc * 16 + frow;
        bf[fc] = *(const bf16x8*)(Bq + rb * 256 + ((cc >> 3) << 7) + (((cc & 7) ^ (rb & 7)) << 4));
      }
#pragma unroll
      for (int fr = 0; fr < 2; ++fr)
#pragma unroll
        for (int fc = 0; fc < 2; ++fc)
          acc[fr][fc] = __builtin_amdgcn_mfma_f32_16x16x32_bf16(af[fr], bf[fc], acc[fr][fc], 0, 0, 0);
    }
    // epilogue -> e1 (R2)
#pragma unroll
    for (int fr = 0; fr < 2; ++fr)
#pragma unroll
      for (int fc = 0; fc < 2; ++fc)
#pragma unroll
        for (int j = 0; j < 4; ++j) {
          const int row = wrow + fr * 16 + kq * 4 + j;
          const int colg = q * 128 + wq * 32 + fc * 16 + frow;
          float v = acc[fr][fc][j] + b1[colg];
          v = fmaxf(v, 0.f);
          const int off = row * 1024 + ((colg >> 6) << 7) + ((((colg >> 3) & 7) ^ (row & 7)) << 4) + ((colg & 7) << 1);
          *(ushort*)(lds + R2O + off) = f2b(v);
        }
    __syncthreads();
  }

  // ---- phase 2: e2 = relu(e1 @ W2 + b2), K=512, 8 pipelined chunks ----
  f32x4 acc2[2][4];
#pragma unroll
  for (int fr = 0; fr < 2; ++fr)
#pragma unroll
    for (int fc = 0; fc < 4; ++fc) acc2[fr][fc] = (f32x4){0.f, 0.f, 0.f, 0.f};
#pragma unroll 1
  for (int kc = 0; kc < 8; ++kc) {
    if (kc < 7) {
      char* dst = lds + R3O + ((kc + 1) & 1) * 32768;
#pragma unroll
      for (int i = 0; i < 4; ++i) {
        const int c = t + i * 512;
        gll16(wt2hi + (size_t)(c >> 3) * 512 + (kc + 1) * 64 + (c & 7) * 8,
              dst + i * 8192 + wv * 1024);
      }
    }
    char* Bb = lds + R3O + (kc & 1) * 32768;
#pragma unroll
    for (int ks = 0; ks < 2; ++ks) {
      const int cl = ks * 4 + kq;        // 0..7
      bf16x8 af[2], bf[4];
#pragma unroll
      for (int fr = 0; fr < 2; ++fr) {
        const int r = wrow + fr * 16 + frow;
        af[fr] = *(const bf16x8*)(lds + R2O + r * 1024 + (kc << 7) + ((cl ^ (r & 7)) << 4));
      }
#pragma unroll
      for (int fc = 0; fc < 4; ++fc) {
        const int rb = wq * 64 + fc * 16 + frow;
        bf[fc] = *(const bf16x8*)(Bb + rb * 128 + ((cl ^ (rb & 7)) << 4));
      }
#pragma unroll
      for (int fr = 0; fr < 2; ++fr)
#pragma unroll
        for (int fc = 0; fc < 4; ++fc)
          acc2[fr][fc] = __builtin_amdgcn_mfma_f32_16x16x32_bf16(af[fr], bf[fc], acc2[fr][fc], 0, 0, 0);
    }
    __syncthreads();
  }
  // epilogue -> e2 (R3 half0; chunk6 dead, chunk7 lives in half1)
#pragma unroll
  for (int fr = 0; fr < 2; ++fr)
#pragma unroll
    for (int fc = 0; fc < 4; ++fc)
#pragma unroll
      for (int j = 0; j < 4; ++j) {
        const int row = wrow + fr * 16 + kq * 4 + j;
        const int col = wq * 64 + fc * 16 + frow;
        float v = acc2[fr][fc][j] + b2[col];
        v = fmaxf(v, 0.f);
        const int off = row * 512 + ((col >> 6) << 7) + ((((col >> 3) & 7) ^ (row & 7)) << 4) + ((col & 7) << 1);
        *(ushort*)(lds + R3O + off) = f2b(v);
      }
  // stage W3 -> R2 base (e1 dead)
#pragma unroll
  for (int i = 0; i < 4; ++i) {
    const int c = t + i * 512;
    gll16(wt3hi + (size_t)(c >> 5) * 256 + (c & 31) * 8,
          lds + R2O + i * 8192 + wv * 1024);
  }
  __syncthreads();

  // ---- phase 3: emb = e2 @ W3 + b3, K=256 ----
  f32x4 acc3[2];
#pragma unroll
  for (int fr = 0; fr < 2; ++fr) acc3[fr] = (f32x4){0.f, 0.f, 0.f, 0.f};
#pragma unroll
  for (int ks = 0; ks < 8; ++ks) {
    const int cc = ks * 4 + kq;          // 0..31
    bf16x8 af[2], bf;
#pragma unroll
    for (int fr = 0; fr < 2; ++fr) {
      const int r = wrow + fr * 16 + frow;
      af[fr] = *(const bf16x8*)(lds + R3O + r * 512 + ((cc >> 3) << 7) + (((cc & 7) ^ (r & 7)) << 4));
    }
    {
      const int rb = wq * 16 + frow;
      bf = *(const bf16x8*)(lds + R2O + rb * 512 + ((cc >> 3) << 7) + (((cc & 7) ^ (rb & 7)) << 4));
    }
#pragma unroll
    for (int fr = 0; fr < 2; ++fr)
      acc3[fr] = __builtin_amdgcn_mfma_f32_16x16x32_bf16(af[fr], bf, acc3[fr], 0, 0, 0);
  }
#pragma unroll
  for (int fr = 0; fr < 2; ++fr)
#pragma unroll
    for (int j = 0; j < 4; ++j) {
      const int row = m0 + wrow + fr * 16 + kq * 4 + j;
      const int col = wq * 16 + frow;
      embb[(size_t)row * OUTD + col] = f2b(acc3[fr][j] + b3[col]);
    }
}

// ---------------------------------------------------------------------------
// fused weight conversion (one launch) + flag init
// ---------------------------------------------------------------------------
__global__ __launch_bounds__(256) void convert_all_kernel(
    const float* __restrict__ W1, const float* __restrict__ W2,
    const float* __restrict__ W3, const float* __restrict__ linW,
    const float* __restrict__ gatW,
    ushort* __restrict__ wt1hi, ushort* __restrict__ wt2hi,
    ushort* __restrict__ wt3hi,
    ushort* __restrict__ lwThi, ushort* __restrict__ lwTlo,
    ushort* __restrict__ gwShi, ushort* __restrict__ gwSlo,
    int* __restrict__ flag)
{
  const int i = blockIdx.x * 256 + threadIdx.x;
  if (i == 0) *flag = 0;
  if (i < 65536) {                            // W1 [128][512] -> [512][128]
    const int k = i >> 9, n = i & 511;
    wt1hi[(size_t)n * 128 + swz_col(n, k)] = f2b(W1[i]);
  } else if (i < 196608) {                    // W2 [512][256] -> [256][512]
    const int j = i - 65536;
    const int k = j >> 8, n = j & 255;
    wt2hi[(size_t)n * 512 + swz_col(n, k)] = f2b(W2[j]);
  } else if (i < 212992) {                    // W3 [256][64] -> [64][256]
    const int j = i - 196608;
    const int k = j >> 6, n = j & 63;
    wt3hi[(size_t)n * 256 + swz_col(n, k)] = f2b(W3[j]);
  } else if (i < 217088) {                    // linW [32][128] -> [128][32]
    const int j = i - 212992;
    const int k = j >> 7, n = j & 127;
    const float v = linW[j];
    const ushort hi = f2b(v);
    lwThi[(size_t)n * 32 + k] = hi;
    lwTlo[(size_t)n * 32 + k] = f2b(v - b2f(hi));
  } else if (i < 233472) {                    // gatW [128][128] -> swz hi/lo
    const int j = i - 217088;
    const int k = j >> 7, n = j & 127;
    const float v = gatW[j];
    const ushort hi = f2b(v);
    const int kc = swz_col(n, k);
    gwShi[(size_t)n * 128 + kc] = hi;
    gwSlo[(size_t)n * 128 + kc] = f2b(v - b2f(hi));
  }
}

// ---------------------------------------------------------------------------
// pairs layout detection (parallel; flag pre-zeroed by convert_all)
// ---------------------------------------------------------------------------
__global__ __launch_bounds__(256) void detect_kernel(
    const unsigned long long* __restrict__ p64, int* __restrict__ flag)
{
  __shared__ int s;
  if (threadIdx.x == 0) s = 0;
  __syncthreads();
  int loc = 0;
  for (int i = blockIdx.x * 256 + threadIdx.x; i < NPAIR; i += 256 * 256)
    loc |= ((p64[i] >> 32) != 0ull) ? 1 : 0;
  if (loc) atomicOr(&s, 1);
  __syncthreads();
  if (threadIdx.x == 0 && s) atomicOr(flag, 1);
}

// ---------------------------------------------------------------------------
// final pair gather (fp32 out)
// ---------------------------------------------------------------------------
__global__ __launch_bounds__(256) void gather_kernel(
    const ushort* __restrict__ embb, const unsigned long long* __restrict__ p64,
    const float* __restrict__ labels, const int* __restrict__ flagp,
    float* __restrict__ out)
{
  const int i = blockIdx.x * 256 + threadIdx.x;
  const int tot = 2 * NPAIR * OUTD;
  if (i < tot) {
    const int fl = *flagp;
    const int which = i / (NPAIR * OUTD);
    const int rem = i - which * (NPAIR * OUTD);
    const int p = rem >> 6, j = rem & 63;
    const int fi = p * 2 + which;
    int node;
    if (fl) {
      const unsigned long long w = p64[fi >> 1];
      node = (int)((fi & 1) ? (w >> 32) : (w & 0xffffffffull));
    } else {
      node = (int)p64[fi];
    }
    node &= (NTOT - 1);
    out[i] = b2f(embb[(size_t)node * OUTD + j]);
  } else if (i < tot + NPAIR) {
    out[i] = labels[i - tot];
  }
}

extern "C" void kernel_launch(void* const* d_in, const int* in_sizes, int n_in,
                              void* d_out, int out_size, void* d_ws, size_t ws_size,
                              hipStream_t stream)
{
  const float* x      = (const float*)d_in[0];
  const unsigned long long* pairs = (const unsigned long long*)d_in[2];
  const float* labels = (const float*)d_in[3];
  const float* linW   = (const float*)d_in[4];
  const float* linb   = (const float*)d_in[5];
  const float* gatW   = (const float*)d_in[6];
  const float* attS   = (const float*)d_in[7];
  const float* attD   = (const float*)d_in[8];
  const float* gatb   = (const float*)d_in[9];
  const float* W1     = (const float*)d_in[10];
  const float* b1     = (const float*)d_in[11];
  const float* W2     = (const float*)d_in[12];
  const float* b2     = (const float*)d_in[13];
  const float* W3     = (const float*)d_in[14];
  const float* b3     = (const float*)d_in[15];

  float* ws = (float*)d_ws;
  const size_t NT = NTOT;
  float*  xl    = ws;                        // [0,128)
  ushort* embb  = (ushort*)(ws + NT * 128);  // [128,160)
  float*  asrc  = ws + NT * 160;
  float*  adst  = ws + NT * 161;
  ushort* wt1hi = (ushort*)(ws + NT * 162);  // [512][128]
  ushort* wt2hi = wt1hi + 512 * 128;         // [256][512]
  ushort* wt3hi = wt2hi + 256 * 512;         // [64][256]
  ushort* lwThi = wt3hi + 64 * 256;          // [128][32]
  ushort* lwTlo = lwThi + 128 * 32;
  ushort* gwShi = lwTlo + 128 * 32;          // [128][128]
  ushort* gwSlo = gwShi + 128 * 128;
  int*    flag  = (int*)(gwSlo + 128 * 128);

  (void)hipFuncSetAttribute(
      reinterpret_cast<const void*>(prep_mfma_kernel),
      hipFuncAttributeMaxDynamicSharedMemorySize, PREP_LDS);
  (void)hipFuncSetAttribute(
      reinterpret_cast<const void*>(mega_kernel),
      hipFuncAttributeMaxDynamicSharedMemorySize, MEGA_LDS);

  convert_all_kernel<<<(233472 + 255) / 256, 256, 0, stream>>>(
      W1, W2, W3, linW, gatW, wt1hi, wt2hi, wt3hi,
      lwThi, lwTlo, gwShi, gwSlo, flag);
  detect_kernel<<<256, 256, 0, stream>>>(pairs, flag);

  prep_mfma_kernel<<<NTOT / 128, 256, PREP_LDS, stream>>>(
      x, lwThi, lwTlo, linb, gwShi, gwSlo, xl);
  reduce_kernel<<<NTOT / 4, 256, 0, stream>>>(xl, attS, attD, asrc, adst);

  mega_kernel<<<NTOT / 64, 512, MEGA_LDS, stream>>>(
      xl, asrc, adst, gatb, wt1hi, wt2hi, wt3hi, b1, b2, b3, embb);

  const int total = 2 * NPAIR * OUTD + NPAIR;
  gather_kernel<<<(total + 255) / 256, 256, 0, stream>>>(embb, pairs, labels, flag, (float*)d_out);
}

// Round 16
// 98.822 us; speedup vs baseline: 2.0091x; 1.0291x over previous
//
#include <hip/hip_runtime.h>
#include <math.h>

#define NTOT 32768
#define NPG  2048
#define INDIM 32
#define HID  128
#define OUTD 64
#define NPAIR 100000
#define NEG_SLOPE 0.2f

typedef short bf16x8 __attribute__((ext_vector_type(8)));
typedef float f32x4 __attribute__((ext_vector_type(4)));

static __device__ __forceinline__ float b2f(ushort u) {
  return __uint_as_float(((unsigned)u) << 16);
}
static __device__ __forceinline__ ushort f2b(float f) {
  unsigned u = __float_as_uint(f);
  unsigned r = (u + 0x7fffu + ((u >> 16) & 1u)) >> 16;   // RNE
  return (ushort)r;
}
// chunk-swizzle: permute 8-bf16 (16B) chunks within each aligned 64-col group
// by row&7.  Involution; producers write swizzled global layout, GEMM stages
// linearly via global_load_lds, readers XOR on the LDS offset.
static __device__ __forceinline__ int swz_col(int row, int col) {
  return (col & ~63) | ((((col >> 3) ^ row) & 7) << 3) | (col & 7);
}
static __device__ __forceinline__ void gll16(const void* g, char* l) {
  __builtin_amdgcn_global_load_lds(
      (const __attribute__((address_space(1))) void*)g,
      (__attribute__((address_space(3))) void*)l, 16, 0, 0);
}

// ---------------------------------------------------------------------------
// MFMA prep: h = x@linW + b ; xl = h@gatW   (both split-bf16 3-term)
// (verbatim from round 13, passing)
// ---------------------------------------------------------------------------
#define HSTR 136
#define XSTR 40
#define PREP_LDS (34816 * 2 + 65536)

__global__ __launch_bounds__(256) void prep_mfma_kernel(
    const float* __restrict__ x,
    const ushort* __restrict__ lwThi, const ushort* __restrict__ lwTlo,
    const float* __restrict__ linb,
    const ushort* __restrict__ gwShi, const ushort* __restrict__ gwSlo,
    float* __restrict__ xl)
{
  extern __shared__ __align__(16) char lds[];
  char* HS_HI = lds;
  char* HS_LO = lds + 34816;
  char* GW_HI = lds + 69632;
  char* GW_LO = lds + 102400;
  char* XS_HI = lds;
  char* XS_LO = lds + 10240;

  const int t = threadIdx.x;
  const int wv = t >> 6, lane = t & 63;
  const int frow = lane & 15, kq = lane >> 4;
  const int wr = (wv >> 1) * 64;
  const int wc = (wv & 1) * 64;
  const int m0 = blockIdx.x * 128;

#pragma unroll
  for (int i = 0; i < 8; ++i) {
    const int c = t + i * 256;
    const int row = c >> 4, ch = c & 15;
    const size_t g = (size_t)row * 128 + ch * 8;
    gll16(gwShi + g, GW_HI + i * 4096 + wv * 1024);
    gll16(gwSlo + g, GW_LO + i * 4096 + wv * 1024);
  }

  {
    const int row = t >> 1, hf = t & 1;
#pragma unroll
    for (int q = 0; q < 4; ++q) {
      const float4 v = *(const float4*)&x[(size_t)(m0 + row) * INDIM + hf * 16 + q * 4];
      ushort4 hi, lo;
      hi.x = f2b(v.x); lo.x = f2b(v.x - b2f(hi.x));
      hi.y = f2b(v.y); lo.y = f2b(v.y - b2f(hi.y));
      hi.z = f2b(v.z); lo.z = f2b(v.z - b2f(hi.z));
      hi.w = f2b(v.w); lo.w = f2b(v.w - b2f(hi.w));
      const int off = row * (XSTR * 2) + (hf * 16 + q * 4) * 2;
      *(ushort4*)(XS_HI + off) = hi;
      *(ushort4*)(XS_LO + off) = lo;
    }
  }
  __syncthreads();

  f32x4 acc1[4][4];
  {
    bf16x8 ah[4], al[4], bh[4], bl[4];
#pragma unroll
    for (int fr = 0; fr < 4; ++fr) {
      const int r = wr + fr * 16 + frow;
      const int off = r * (XSTR * 2) + kq * 16;
      ah[fr] = *(const bf16x8*)(XS_HI + off);
      al[fr] = *(const bf16x8*)(XS_LO + off);
    }
#pragma unroll
    for (int fc = 0; fc < 4; ++fc) {
      const int col = wc + fc * 16 + frow;
      bh[fc] = *(const bf16x8*)(lwThi + (size_t)col * 32 + kq * 8);
      bl[fc] = *(const bf16x8*)(lwTlo + (size_t)col * 32 + kq * 8);
    }
#pragma unroll
    for (int fr = 0; fr < 4; ++fr)
#pragma unroll
      for (int fc = 0; fc < 4; ++fc) {
        f32x4 a = (f32x4){0.f, 0.f, 0.f, 0.f};
        a = __builtin_amdgcn_mfma_f32_16x16x32_bf16(ah[fr], bh[fc], a, 0, 0, 0);
        a = __builtin_amdgcn_mfma_f32_16x16x32_bf16(ah[fr], bl[fc], a, 0, 0, 0);
        a = __builtin_amdgcn_mfma_f32_16x16x32_bf16(al[fr], bh[fc], a, 0, 0, 0);
        acc1[fr][fc] = a;
      }
  }
  __syncthreads();

#pragma unroll
  for (int fr = 0; fr < 4; ++fr)
#pragma unroll
    for (int fc = 0; fc < 4; ++fc) {
      const int col = wc + fc * 16 + frow;
      const float bj = linb[col];
#pragma unroll
      for (int j = 0; j < 4; ++j) {
        const int row = wr + fr * 16 + kq * 4 + j;
        const float v = acc1[fr][fc][j] + bj;
        const ushort hi = f2b(v);
        const int off = row * (HSTR * 2) + col * 2;
        *(ushort*)(HS_HI + off) = hi;
        *(ushort*)(HS_LO + off) = f2b(v - b2f(hi));
      }
    }
  __syncthreads();

  f32x4 acc2[4][4];
#pragma unroll
  for (int fr = 0; fr < 4; ++fr)
#pragma unroll
    for (int fc = 0; fc < 4; ++fc) acc2[fr][fc] = (f32x4){0.f, 0.f, 0.f, 0.f};
#pragma unroll
  for (int ks = 0; ks < 4; ++ks) {
    const int k = ks * 32 + kq * 8;
    bf16x8 ah[4], al[4], bh[4], bl[4];
#pragma unroll
    for (int fr = 0; fr < 4; ++fr) {
      const int r = wr + fr * 16 + frow;
      const int off = r * (HSTR * 2) + k * 2;
      ah[fr] = *(const bf16x8*)(HS_HI + off);
      al[fr] = *(const bf16x8*)(HS_LO + off);
    }
#pragma unroll
    for (int fc = 0; fc < 4; ++fc) {
      const int col = wc + fc * 16 + frow;
      const int off = col * 256 + (k & ~63) * 2 + ((((k >> 3) ^ col) & 7) << 4);
      bh[fc] = *(const bf16x8*)(GW_HI + off);
      bl[fc] = *(const bf16x8*)(GW_LO + off);
    }
#pragma unroll
    for (int fr = 0; fr < 4; ++fr)
#pragma unroll
      for (int fc = 0; fc < 4; ++fc) {
        acc2[fr][fc] = __builtin_amdgcn_mfma_f32_16x16x32_bf16(ah[fr], bh[fc], acc2[fr][fc], 0, 0, 0);
        acc2[fr][fc] = __builtin_amdgcn_mfma_f32_16x16x32_bf16(ah[fr], bl[fc], acc2[fr][fc], 0, 0, 0);
        acc2[fr][fc] = __builtin_amdgcn_mfma_f32_16x16x32_bf16(al[fr], bh[fc], acc2[fr][fc], 0, 0, 0);
      }
  }

#pragma unroll
  for (int fr = 0; fr < 4; ++fr)
#pragma unroll
    for (int fc = 0; fc < 4; ++fc)
#pragma unroll
      for (int j = 0; j < 4; ++j) {
        const int row = m0 + wr + fr * 16 + kq * 4 + j;
        const int col = wc + fc * 16 + frow;
        xl[(size_t)row * HID + col] = acc2[fr][fc][j];
      }
}

// ---------------------------------------------------------------------------
// asrc/adst: one wave per node, shuffle reduce over 128 cols of xl (fp32)
// ---------------------------------------------------------------------------
__global__ __launch_bounds__(256) void reduce_kernel(
    const float* __restrict__ xl, const float* __restrict__ attS,
    const float* __restrict__ attD, float* __restrict__ asrc,
    float* __restrict__ adst)
{
  const int n = blockIdx.x * 4 + (threadIdx.x >> 6);
  const int l = threadIdx.x & 63;
  const float x0 = xl[(size_t)n * HID + l];
  const float x1 = xl[(size_t)n * HID + 64 + l];
  float s = fmaf(x0, attS[l], x1 * attS[64 + l]);
  float d = fmaf(x0, attD[l], x1 * attD[64 + l]);
#pragma unroll
  for (int sh = 32; sh > 0; sh >>= 1) {
    s += __shfl_xor(s, sh, 64);
    d += __shfl_xor(d, sh, 64);
  }
  if (l == 0) { asrc[n] = s; adst[n] = d; }
}

// ---------------------------------------------------------------------------
// MEGA v5: r13's passing 64-row fused kernel, rescaled to 1024 thr = 16 waves
// (4 waves/SIMD).  Identical data flow, LDS map, swizzles, barrier schedule;
// only the wave->tile decomposition and staging iteration counts change.
// LDS: R1 ghi 16K | R2 64K (xl+hub -> e1 -> W3) | R3 64K (W dbuf -> e2)
// ---------------------------------------------------------------------------
#define R1O 0
#define R2O 16384
#define R3O 81920
#define RWR 147456
#define RGB 152064
#define MEGA_LDS 152576

__global__ __launch_bounds__(1024) void mega_kernel(
    const float* __restrict__ xl, const float* __restrict__ asrc,
    const float* __restrict__ adst, const float* __restrict__ gatb,
    const ushort* __restrict__ wt1hi, const ushort* __restrict__ wt2hi,
    const ushort* __restrict__ wt3hi,
    const float* __restrict__ b1, const float* __restrict__ b2,
    const float* __restrict__ b3, ushort* __restrict__ embb)
{
  extern __shared__ __align__(16) char lds[];
  const int t = threadIdx.x;
  const int wv = t >> 6, lane = t & 63;
  const int frow = lane & 15, kq = lane >> 4;
  const int wrow = (wv >> 3) * 32;       // phases 1-2: 2 row-halves of 32
  const int wq = wv & 7;                 // phases 1-2: 8 col-waves
  const int m0 = blockIdx.x * 64;
  const int gb = m0 & ~(NPG - 1);

  // ---- stage: xl tile (32KB, 2048 chunks), hub rows (12KB, 768),
  //      W1 quarter0 (32KB, 2048) -> R3 half0 ----
#pragma unroll
  for (int i = 0; i < 2; ++i) {
    const int c = t + i * 1024;
    gll16(xl + (size_t)(m0 + (c >> 5)) * HID + (c & 31) * 4,
          lds + R2O + i * 16384 + wv * 1024);
  }
  if (t < 768)       // 12 full waves: wave-uniform guard
    gll16(xl + (size_t)(gb + (t >> 5)) * HID + (t & 31) * 4,
          lds + R2O + 32768 + wv * 1024);
#pragma unroll
  for (int i = 0; i < 2; ++i) {
    const int c = t + i * 1024;
    gll16(wt1hi + (size_t)(c >> 4) * 128 + (c & 15) * 8,
          lds + R3O + i * 16384 + wv * 1024);
  }
  if (t >= 64 && t < 192) ((float*)(lds + RGB))[t - 64] = gatb[t - 64];

  // ---- softmax weights (wave 0, one row per lane, 64 rows) ----
  float* wr = (float*)(lds + RWR);
  if (t < 64) {
    const int n = m0 + t;
    const int loc = n & (NPG - 1);
    float a[17];
#pragma unroll
    for (int k = 0; k < 17; ++k) {
      int c;
      if (k < 16) { const int nb = (loc < 16) ? ((k < loc) ? k : k + 1) : k; c = gb + nb; }
      else c = n;
      a[k] = asrc[c];
    }
    const float ad = adst[n];
    float m = -__builtin_inff();
#pragma unroll
    for (int k = 0; k < 17; ++k) {
      float l = a[k] + ad;
      l = (l > 0.f) ? l : NEG_SLOPE * l;
      m = fmaxf(m, l);
    }
    float den = 0.f;
#pragma unroll
    for (int k = 0; k < 17; ++k) {
      float l = a[k] + ad;
      l = (l > 0.f) ? l : NEG_SLOPE * l;
      const float w = __expf(l - m);
      wr[t * 18 + k] = w;
      den += w;
    }
    wr[t * 18 + 17] = 1.f / den;
  }
  __syncthreads();   // staging drained + wr/gatb visible

  // ---- weighted sum -> ghi tile (R1, bf16 swizzled), 8192 scalars ----
  {
    const float* xs = (const float*)(lds + R2O);
    const float* hs = (const float*)(lds + R2O + 32768);
    const float* gs = (const float*)(lds + RGB);
#pragma unroll 1
    for (int oi = 0; oi < 8; ++oi) {
      const int idx = t + oi * 1024;
      const int r = idx >> 7, j = idx & 127;
      const int loc = (m0 + r) & (NPG - 1);
      float acc = 0.f;
#pragma unroll
      for (int k = 0; k < 16; ++k) {
        const int nb = (loc < 16) ? ((k < loc) ? k : k + 1) : k;
        acc = fmaf(wr[r * 18 + k], hs[nb * 128 + j], acc);
      }
      acc = fmaf(wr[r * 18 + 16], xs[r * 128 + j], acc);
      const float v = acc * wr[r * 18 + 17] + gs[j];
      const int off = r * 256 + ((j >> 6) << 7) + ((((j >> 3) & 7) ^ (r & 7)) << 4) + ((j & 7) << 1);
      *(ushort*)(lds + R1O + off) = f2b(v);
    }
  }
  __syncthreads();   // ghi ready; xl/hub dead

  // ---- phase 1: e1 = relu(ghi @ W1 + b1), 4 pipelined 128-col quarters ----
#pragma unroll 1
  for (int q = 0; q < 4; ++q) {
    if (q < 3) {                         // stage next W1 quarter
      char* dst = lds + R3O + ((q + 1) & 1) * 32768;
#pragma unroll
      for (int i = 0; i < 2; ++i) {
        const int c = t + i * 1024;
        gll16(wt1hi + (size_t)((q + 1) * 128 + (c >> 4)) * 128 + (c & 15) * 8,
              dst + i * 16384 + wv * 1024);
      }
    } else {                             // stage W2 chunk0 -> half0
#pragma unroll
      for (int i = 0; i < 2; ++i) {
        const int c = t + i * 1024;
        gll16(wt2hi + (size_t)(c >> 3) * 512 + (c & 7) * 8,
              lds + R3O + i * 16384 + wv * 1024);
      }
    }
    char* Bq = lds + R3O + (q & 1) * 32768;
    f32x4 acc[2];
#pragma unroll
    for (int fr = 0; fr < 2; ++fr) acc[fr] = (f32x4){0.f, 0.f, 0.f, 0.f};
#pragma unroll
    for (int ks = 0; ks < 4; ++ks) {
      const int cc = ks * 4 + kq;        // 0..15
      bf16x8 af[2], bf;
#pragma unroll
      for (int fr = 0; fr < 2; ++fr) {
        const int r = wrow + fr * 16 + frow;
        af[fr] = *(const bf16x8*)(lds + R1O + r * 256 + ((cc >> 3) << 7) + (((cc & 7) ^ (r & 7)) << 4));
      }
      {
        const int rb = wq * 16 + frow;   // 0..127 within quarter
        bf = *(const bf16x8*)(Bq + rb * 256 + ((cc >> 3) << 7) + (((cc & 7) ^ (rb & 7)) << 4));
      }
#pragma unroll
      for (int fr = 0; fr < 2; ++fr)
        acc[fr] = __builtin_amdgcn_mfma_f32_16x16x32_bf16(af[fr], bf, acc[fr], 0, 0, 0);
    }
    // epilogue -> e1 (R2)
#pragma unroll
    for (int fr = 0; fr < 2; ++fr)
#pragma unroll
      for (int j = 0; j < 4; ++j) {
        const int row = wrow + fr * 16 + kq * 4 + j;
        const int colg = q * 128 + wq * 16 + frow;
        float v = acc[fr][j] + b1[colg];
        v = fmaxf(v, 0.f);
        const int off = row * 1024 + ((colg >> 6) << 7) + ((((colg >> 3) & 7) ^ (row & 7)) << 4) + ((colg & 7) << 1);
        *(ushort*)(lds + R2O + off) = f2b(v);
      }
    __syncthreads();
  }

  // ---- phase 2: e2 = relu(e1 @ W2 + b2), K=512, 8 pipelined chunks ----
  f32x4 acc2[2][2];
#pragma unroll
  for (int fr = 0; fr < 2; ++fr)
#pragma unroll
    for (int fc = 0; fc < 2; ++fc) acc2[fr][fc] = (f32x4){0.f, 0.f, 0.f, 0.f};
#pragma unroll 1
  for (int kc = 0; kc < 8; ++kc) {
    if (kc < 7) {
      char* dst = lds + R3O + ((kc + 1) & 1) * 32768;
#pragma unroll
      for (int i = 0; i < 2; ++i) {
        const int c = t + i * 1024;
        gll16(wt2hi + (size_t)(c >> 3) * 512 + (kc + 1) * 64 + (c & 7) * 8,
              dst + i * 16384 + wv * 1024);
      }
    }
    char* Bb = lds + R3O + (kc & 1) * 32768;
#pragma unroll
    for (int ks = 0; ks < 2; ++ks) {
      const int cl = ks * 4 + kq;        // 0..7
      bf16x8 af[2], bf[2];
#pragma unroll
      for (int fr = 0; fr < 2; ++fr) {
        const int r = wrow + fr * 16 + frow;
        af[fr] = *(const bf16x8*)(lds + R2O + r * 1024 + (kc << 7) + ((cl ^ (r & 7)) << 4));
      }
#pragma unroll
      for (int fc = 0; fc < 2; ++fc) {
        const int rb = wq * 32 + fc * 16 + frow;   // 0..255
        bf[fc] = *(const bf16x8*)(Bb + rb * 128 + ((cl ^ (rb & 7)) << 4));
      }
#pragma unroll
      for (int fr = 0; fr < 2; ++fr)
#pragma unroll
        for (int fc = 0; fc < 2; ++fc)
          acc2[fr][fc] = __builtin_amdgcn_mfma_f32_16x16x32_bf16(af[fr], bf[fc], acc2[fr][fc], 0, 0, 0);
    }
    __syncthreads();
  }
  // epilogue -> e2 (R3 half0), stage W3 -> R2 base (e1 dead)
#pragma unroll
  for (int fr = 0; fr < 2; ++fr)
#pragma unroll
    for (int fc = 0; fc < 2; ++fc)
#pragma unroll
      for (int j = 0; j < 4; ++j) {
        const int row = wrow + fr * 16 + kq * 4 + j;
        const int col = wq * 32 + fc * 16 + frow;
        float v = acc2[fr][fc][j] + b2[col];
        v = fmaxf(v, 0.f);
        const int off = row * 512 + ((col >> 6) << 7) + ((((col >> 3) & 7) ^ (row & 7)) << 4) + ((col & 7) << 1);
        *(ushort*)(lds + R3O + off) = f2b(v);
      }
#pragma unroll
  for (int i = 0; i < 2; ++i) {   // W3t [64][256] = 32KB, 2048 chunks
    const int c = t + i * 1024;
    gll16(wt3hi + (size_t)(c >> 5) * 256 + (c & 31) * 8,
          lds + R2O + i * 16384 + wv * 1024);
  }
  __syncthreads();

  // ---- phase 3: emb = e2 @ W3 + b3; 4 row-quarters x 4 col-quarters ----
  {
    const int wr3 = (wv >> 2) * 16;      // 0,16,32,48
    const int wq3 = wv & 3;
    f32x4 acc3 = (f32x4){0.f, 0.f, 0.f, 0.f};
#pragma unroll
    for (int ks = 0; ks < 8; ++ks) {
      const int cc = ks * 4 + kq;        // 0..31
      const int r = wr3 + frow;
      const bf16x8 af = *(const bf16x8*)(lds + R3O + r * 512 + ((cc >> 3) << 7) + (((cc & 7) ^ (r & 7)) << 4));
      const int rb = wq3 * 16 + frow;
      const bf16x8 bf = *(const bf16x8*)(lds + R2O + rb * 512 + ((cc >> 3) << 7) + (((cc & 7) ^ (rb & 7)) << 4));
      acc3 = __builtin_amdgcn_mfma_f32_16x16x32_bf16(af, bf, acc3, 0, 0, 0);
    }
#pragma unroll
    for (int j = 0; j < 4; ++j) {
      const int row = m0 + wr3 + kq * 4 + j;
      const int col = wq3 * 16 + frow;
      embb[(size_t)row * OUTD + col] = f2b(acc3[j] + b3[col]);
    }
  }
}

// ---------------------------------------------------------------------------
// fused weight conversion (one launch) + flag init (r13 version: swizzled)
// ---------------------------------------------------------------------------
__global__ __launch_bounds__(256) void convert_all_kernel(
    const float* __restrict__ W1, const float* __restrict__ W2,
    const float* __restrict__ W3, const float* __restrict__ linW,
    const float* __restrict__ gatW,
    ushort* __restrict__ wt1hi, ushort* __restrict__ wt2hi,
    ushort* __restrict__ wt3hi,
    ushort* __restrict__ lwThi, ushort* __restrict__ lwTlo,
    ushort* __restrict__ gwShi, ushort* __restrict__ gwSlo,
    int* __restrict__ flag)
{
  const int i = blockIdx.x * 256 + threadIdx.x;
  if (i == 0) *flag = 0;
  if (i < 65536) {                            // W1 [128][512] -> [512][128]
    const int k = i >> 9, n = i & 511;
    wt1hi[(size_t)n * 128 + swz_col(n, k)] = f2b(W1[i]);
  } else if (i < 196608) {                    // W2 [512][256] -> [256][512]
    const int j = i - 65536;
    const int k = j >> 8, n = j & 255;
    wt2hi[(size_t)n * 512 + swz_col(n, k)] = f2b(W2[j]);
  } else if (i < 212992) {                    // W3 [256][64] -> [64][256]
    const int j = i - 196608;
    const int k = j >> 6, n = j & 63;
    wt3hi[(size_t)n * 256 + swz_col(n, k)] = f2b(W3[j]);
  } else if (i < 217088) {                    // linW [32][128] -> [128][32]
    const int j = i - 212992;
    const int k = j >> 7, n = j & 127;
    const float v = linW[j];
    const ushort hi = f2b(v);
    lwThi[(size_t)n * 32 + k] = hi;
    lwTlo[(size_t)n * 32 + k] = f2b(v - b2f(hi));
  } else if (i < 233472) {                    // gatW [128][128] -> swz hi/lo
    const int j = i - 217088;
    const int k = j >> 7, n = j & 127;
    const float v = gatW[j];
    const ushort hi = f2b(v);
    const int kc = swz_col(n, k);
    gwShi[(size_t)n * 128 + kc] = hi;
    gwSlo[(size_t)n * 128 + kc] = f2b(v - b2f(hi));
  }
}

// ---------------------------------------------------------------------------
// pairs layout detection (parallel; flag pre-zeroed by convert_all)
// ---------------------------------------------------------------------------
__global__ __launch_bounds__(256) void detect_kernel(
    const unsigned long long* __restrict__ p64, int* __restrict__ flag)
{
  __shared__ int s;
  if (threadIdx.x == 0) s = 0;
  __syncthreads();
  int loc = 0;
  for (int i = blockIdx.x * 256 + threadIdx.x; i < NPAIR; i += 256 * 256)
    loc |= ((p64[i] >> 32) != 0ull) ? 1 : 0;
  if (loc) atomicOr(&s, 1);
  __syncthreads();
  if (threadIdx.x == 0 && s) atomicOr(flag, 1);
}

// ---------------------------------------------------------------------------
// final pair gather (fp32 out)
// ---------------------------------------------------------------------------
__global__ __launch_bounds__(256) void gather_kernel(
    const ushort* __restrict__ embb, const unsigned long long* __restrict__ p64,
    const float* __restrict__ labels, const int* __restrict__ flagp,
    float* __restrict__ out)
{
  const int i = blockIdx.x * 256 + threadIdx.x;
  const int tot = 2 * NPAIR * OUTD;
  if (i < tot) {
    const int fl = *flagp;
    const int which = i / (NPAIR * OUTD);
    const int rem = i - which * (NPAIR * OUTD);
    const int p = rem >> 6, j = rem & 63;
    const int fi = p * 2 + which;
    int node;
    if (fl) {
      const unsigned long long w = p64[fi >> 1];
      node = (int)((fi & 1) ? (w >> 32) : (w & 0xffffffffull));
    } else {
      node = (int)p64[fi];
    }
    node &= (NTOT - 1);
    out[i] = b2f(embb[(size_t)node * OUTD + j]);
  } else if (i < tot + NPAIR) {
    out[i] = labels[i - tot];
  }
}

extern "C" void kernel_launch(void* const* d_in, const int* in_sizes, int n_in,
                              void* d_out, int out_size, void* d_ws, size_t ws_size,
                              hipStream_t stream)
{
  const float* x      = (const float*)d_in[0];
  const unsigned long long* pairs = (const unsigned long long*)d_in[2];
  const float* labels = (const float*)d_in[3];
  const float* linW   = (const float*)d_in[4];
  const float* linb   = (const float*)d_in[5];
  const float* gatW   = (const float*)d_in[6];
  const float* attS   = (const float*)d_in[7];
  const float* attD   = (const float*)d_in[8];
  const float* gatb   = (const float*)d_in[9];
  const float* W1     = (const float*)d_in[10];
  const float* b1     = (const float*)d_in[11];
  const float* W2     = (const float*)d_in[12];
  const float* b2     = (const float*)d_in[13];
  const float* W3     = (const float*)d_in[14];
  const float* b3     = (const float*)d_in[15];

  float* ws = (float*)d_ws;
  const size_t NT = NTOT;
  float*  xl    = ws;                        // [0,128)
  ushort* embb  = (ushort*)(ws + NT * 128);  // [128,160)
  float*  asrc  = ws + NT * 160;
  float*  adst  = ws + NT * 161;
  ushort* wt1hi = (ushort*)(ws + NT * 162);  // [512][128] swz
  ushort* wt2hi = wt1hi + 512 * 128;         // [256][512] swz
  ushort* wt3hi = wt2hi + 256 * 512;         // [64][256]  swz
  ushort* lwThi = wt3hi + 64 * 256;          // [128][32]
  ushort* lwTlo = lwThi + 128 * 32;
  ushort* gwShi = lwTlo + 128 * 32;          // [128][128] swz
  ushort* gwSlo = gwShi + 128 * 128;
  int*    flag  = (int*)(gwSlo + 128 * 128);

  (void)hipFuncSetAttribute(
      reinterpret_cast<const void*>(prep_mfma_kernel),
      hipFuncAttributeMaxDynamicSharedMemorySize, PREP_LDS);
  (void)hipFuncSetAttribute(
      reinterpret_cast<const void*>(mega_kernel),
      hipFuncAttributeMaxDynamicSharedMemorySize, MEGA_LDS);

  convert_all_kernel<<<(233472 + 255) / 256, 256, 0, stream>>>(
      W1, W2, W3, linW, gatW, wt1hi, wt2hi, wt3hi,
      lwThi, lwTlo, gwShi, gwSlo, flag);
  detect_kernel<<<256, 256, 0, stream>>>(pairs, flag);

  prep_mfma_kernel<<<NTOT / 128, 256, PREP_LDS, stream>>>(
      x, lwThi, lwTlo, linb, gwShi, gwSlo, xl);
  reduce_kernel<<<NTOT / 4, 256, 0, stream>>>(xl, attS, attD, asrc, adst);

  mega_kernel<<<NTOT / 64, 1024, MEGA_LDS, stream>>>(
      xl, asrc, adst, gatb, wt1hi, wt2hi, wt3hi, b1, b2, b3, embb);

  const int total = 2 * NPAIR * OUTD + NPAIR;
  gather_kernel<<<(total + 255) / 256, 256, 0, stream>>>(embb, pairs, labels, flag, (float*)d_out);
}

// Round 17
// 80.260 us; speedup vs baseline: 2.4737x; 1.2313x over previous
//
#include <hip/hip_runtime.h>
#include <math.h>

#define NTOT 32768
#define NPG  2048
#define INDIM 32
#define HID  128
#define OUTD 64
#define NPAIR 100000
#define NEG_SLOPE 0.2f

typedef short bf16x8 __attribute__((ext_vector_type(8)));
typedef float f32x4 __attribute__((ext_vector_type(4)));

static __device__ __forceinline__ float b2f(ushort u) {
  return __uint_as_float(((unsigned)u) << 16);
}
static __device__ __forceinline__ ushort f2b(float f) {
  unsigned u = __float_as_uint(f);
  unsigned r = (u + 0x7fffu + ((u >> 16) & 1u)) >> 16;   // RNE
  return (ushort)r;
}
// chunk-swizzle: permute 8-bf16 (16B) chunks within each aligned 64-col group
// by row&7.  Involution; producers write swizzled global layout, GEMM stages
// linearly via global_load_lds, readers XOR on the LDS offset.
static __device__ __forceinline__ int swz_col(int row, int col) {
  return (col & ~63) | ((((col >> 3) ^ row) & 7) << 3) | (col & 7);
}
static __device__ __forceinline__ void gll16(const void* g, char* l) {
  __builtin_amdgcn_global_load_lds(
      (const __attribute__((address_space(1))) void*)g,
      (__attribute__((address_space(3))) void*)l, 16, 0, 0);
}

// ---------------------------------------------------------------------------
// MFMA prep: h = x@linW + b ; xl = h@gatW   (both split-bf16 3-term)
// GEMM2's gatW fragments now read DIRECTLY from global (plain transposed,
// L2-resident, same pattern as GEMM1's linW reads) — no LDS staging.
// LDS 68KB -> 2 blocks/CU.
// ---------------------------------------------------------------------------
#define HSTR 136
#define XSTR 40
#define PREP_LDS (34816 * 2)

__global__ __launch_bounds__(256) void prep_mfma_kernel(
    const float* __restrict__ x,
    const ushort* __restrict__ lwThi, const ushort* __restrict__ lwTlo,
    const float* __restrict__ linb,
    const ushort* __restrict__ gwThi, const ushort* __restrict__ gwTlo,
    float* __restrict__ xl)
{
  extern __shared__ __align__(16) char lds[];
  char* HS_HI = lds;
  char* HS_LO = lds + 34816;
  char* XS_HI = lds;
  char* XS_LO = lds + 10240;

  const int t = threadIdx.x;
  const int wv = t >> 6, lane = t & 63;
  const int frow = lane & 15, kq = lane >> 4;
  const int wr = (wv >> 1) * 64;
  const int wc = (wv & 1) * 64;
  const int m0 = blockIdx.x * 128;

  {
    const int row = t >> 1, hf = t & 1;
#pragma unroll
    for (int q = 0; q < 4; ++q) {
      const float4 v = *(const float4*)&x[(size_t)(m0 + row) * INDIM + hf * 16 + q * 4];
      ushort4 hi, lo;
      hi.x = f2b(v.x); lo.x = f2b(v.x - b2f(hi.x));
      hi.y = f2b(v.y); lo.y = f2b(v.y - b2f(hi.y));
      hi.z = f2b(v.z); lo.z = f2b(v.z - b2f(hi.z));
      hi.w = f2b(v.w); lo.w = f2b(v.w - b2f(hi.w));
      const int off = row * (XSTR * 2) + (hf * 16 + q * 4) * 2;
      *(ushort4*)(XS_HI + off) = hi;
      *(ushort4*)(XS_LO + off) = lo;
    }
  }
  __syncthreads();

  f32x4 acc1[4][4];
  {
    bf16x8 ah[4], al[4], bh[4], bl[4];
#pragma unroll
    for (int fr = 0; fr < 4; ++fr) {
      const int r = wr + fr * 16 + frow;
      const int off = r * (XSTR * 2) + kq * 16;
      ah[fr] = *(const bf16x8*)(XS_HI + off);
      al[fr] = *(const bf16x8*)(XS_LO + off);
    }
#pragma unroll
    for (int fc = 0; fc < 4; ++fc) {
      const int col = wc + fc * 16 + frow;
      bh[fc] = *(const bf16x8*)(lwThi + (size_t)col * 32 + kq * 8);
      bl[fc] = *(const bf16x8*)(lwTlo + (size_t)col * 32 + kq * 8);
    }
#pragma unroll
    for (int fr = 0; fr < 4; ++fr)
#pragma unroll
      for (int fc = 0; fc < 4; ++fc) {
        f32x4 a = (f32x4){0.f, 0.f, 0.f, 0.f};
        a = __builtin_amdgcn_mfma_f32_16x16x32_bf16(ah[fr], bh[fc], a, 0, 0, 0);
        a = __builtin_amdgcn_mfma_f32_16x16x32_bf16(ah[fr], bl[fc], a, 0, 0, 0);
        a = __builtin_amdgcn_mfma_f32_16x16x32_bf16(al[fr], bh[fc], a, 0, 0, 0);
        acc1[fr][fc] = a;
      }
  }
  __syncthreads();

#pragma unroll
  for (int fr = 0; fr < 4; ++fr)
#pragma unroll
    for (int fc = 0; fc < 4; ++fc) {
      const int col = wc + fc * 16 + frow;
      const float bj = linb[col];
#pragma unroll
      for (int j = 0; j < 4; ++j) {
        const int row = wr + fr * 16 + kq * 4 + j;
        const float v = acc1[fr][fc][j] + bj;
        const ushort hi = f2b(v);
        const int off = row * (HSTR * 2) + col * 2;
        *(ushort*)(HS_HI + off) = hi;
        *(ushort*)(HS_LO + off) = f2b(v - b2f(hi));
      }
    }
  __syncthreads();

  f32x4 acc2[4][4];
#pragma unroll
  for (int fr = 0; fr < 4; ++fr)
#pragma unroll
    for (int fc = 0; fc < 4; ++fc) acc2[fr][fc] = (f32x4){0.f, 0.f, 0.f, 0.f};
#pragma unroll
  for (int ks = 0; ks < 4; ++ks) {
    const int k = ks * 32 + kq * 8;
    bf16x8 ah[4], al[4], bh[4], bl[4];
#pragma unroll
    for (int fr = 0; fr < 4; ++fr) {
      const int r = wr + fr * 16 + frow;
      const int off = r * (HSTR * 2) + k * 2;
      ah[fr] = *(const bf16x8*)(HS_HI + off);
      al[fr] = *(const bf16x8*)(HS_LO + off);
    }
#pragma unroll
    for (int fc = 0; fc < 4; ++fc) {
      const int col = wc + fc * 16 + frow;
      bh[fc] = *(const bf16x8*)(gwThi + (size_t)col * 128 + k);
      bl[fc] = *(const bf16x8*)(gwTlo + (size_t)col * 128 + k);
    }
#pragma unroll
    for (int fr = 0; fr < 4; ++fr)
#pragma unroll
      for (int fc = 0; fc < 4; ++fc) {
        acc2[fr][fc] = __builtin_amdgcn_mfma_f32_16x16x32_bf16(ah[fr], bh[fc], acc2[fr][fc], 0, 0, 0);
        acc2[fr][fc] = __builtin_amdgcn_mfma_f32_16x16x32_bf16(ah[fr], bl[fc], acc2[fr][fc], 0, 0, 0);
        acc2[fr][fc] = __builtin_amdgcn_mfma_f32_16x16x32_bf16(al[fr], bh[fc], acc2[fr][fc], 0, 0, 0);
      }
  }

#pragma unroll
  for (int fr = 0; fr < 4; ++fr)
#pragma unroll
    for (int fc = 0; fc < 4; ++fc)
#pragma unroll
      for (int j = 0; j < 4; ++j) {
        const int row = m0 + wr + fr * 16 + kq * 4 + j;
        const int col = wc + fc * 16 + frow;
        xl[(size_t)row * HID + col] = acc2[fr][fc][j];
      }
}

// ---------------------------------------------------------------------------
// asrc/adst: one wave per node, shuffle reduce over 128 cols of xl (fp32)
// ---------------------------------------------------------------------------
__global__ __launch_bounds__(256) void reduce_kernel(
    const float* __restrict__ xl, const float* __restrict__ attS,
    const float* __restrict__ attD, float* __restrict__ asrc,
    float* __restrict__ adst)
{
  const int n = blockIdx.x * 4 + (threadIdx.x >> 6);
  const int l = threadIdx.x & 63;
  const float x0 = xl[(size_t)n * HID + l];
  const float x1 = xl[(size_t)n * HID + 64 + l];
  float s = fmaf(x0, attS[l], x1 * attS[64 + l]);
  float d = fmaf(x0, attD[l], x1 * attD[64 + l]);
#pragma unroll
  for (int sh = 32; sh > 0; sh >>= 1) {
    s += __shfl_xor(s, sh, 64);
    d += __shfl_xor(d, sh, 64);
  }
  if (l == 0) { asrc[n] = s; adst[n] = d; }
}

// ---------------------------------------------------------------------------
// MEGA v6: r16's passing v5 (64 rows, 1024 thr = 16 waves) with two surgical
// edits: (a) weighted-sum hoists the 17 hub values into registers (LDS reads
// 136->17 per thread; same swizzled write); (b) s_setprio around MFMA
// clusters (T5).  Data flow / LDS map / barriers otherwise identical.
// LDS: R1 ghi 16K | R2 64K (xl+hub -> e1 -> W3) | R3 64K (W dbuf -> e2)
// ---------------------------------------------------------------------------
#define R1O 0
#define R2O 16384
#define R3O 81920
#define RWR 147456
#define RGB 152064
#define MEGA_LDS 152576

__global__ __launch_bounds__(1024) void mega_kernel(
    const float* __restrict__ xl, const float* __restrict__ asrc,
    const float* __restrict__ adst, const float* __restrict__ gatb,
    const ushort* __restrict__ wt1hi, const ushort* __restrict__ wt2hi,
    const ushort* __restrict__ wt3hi,
    const float* __restrict__ b1, const float* __restrict__ b2,
    const float* __restrict__ b3, ushort* __restrict__ embb)
{
  extern __shared__ __align__(16) char lds[];
  const int t = threadIdx.x;
  const int wv = t >> 6, lane = t & 63;
  const int frow = lane & 15, kq = lane >> 4;
  const int wrow = (wv >> 3) * 32;       // phases 1-2: 2 row-halves of 32
  const int wq = wv & 7;                 // phases 1-2: 8 col-waves
  const int m0 = blockIdx.x * 64;
  const int gb = m0 & ~(NPG - 1);

  // ---- stage: xl tile (32KB, 2048 chunks), hub rows (12KB, 768),
  //      W1 quarter0 (32KB, 2048) -> R3 half0 ----
#pragma unroll
  for (int i = 0; i < 2; ++i) {
    const int c = t + i * 1024;
    gll16(xl + (size_t)(m0 + (c >> 5)) * HID + (c & 31) * 4,
          lds + R2O + i * 16384 + wv * 1024);
  }
  if (t < 768)       // 12 full waves: wave-uniform guard
    gll16(xl + (size_t)(gb + (t >> 5)) * HID + (t & 31) * 4,
          lds + R2O + 32768 + wv * 1024);
#pragma unroll
  for (int i = 0; i < 2; ++i) {
    const int c = t + i * 1024;
    gll16(wt1hi + (size_t)(c >> 4) * 128 + (c & 15) * 8,
          lds + R3O + i * 16384 + wv * 1024);
  }
  if (t >= 64 && t < 192) ((float*)(lds + RGB))[t - 64] = gatb[t - 64];

  // ---- softmax weights (wave 0, one row per lane, 64 rows) ----
  float* wr = (float*)(lds + RWR);
  if (t < 64) {
    const int n = m0 + t;
    const int loc = n & (NPG - 1);
    float a[17];
#pragma unroll
    for (int k = 0; k < 17; ++k) {
      int c;
      if (k < 16) { const int nb = (loc < 16) ? ((k < loc) ? k : k + 1) : k; c = gb + nb; }
      else c = n;
      a[k] = asrc[c];
    }
    const float ad = adst[n];
    float m = -__builtin_inff();
#pragma unroll
    for (int k = 0; k < 17; ++k) {
      float l = a[k] + ad;
      l = (l > 0.f) ? l : NEG_SLOPE * l;
      m = fmaxf(m, l);
    }
    float den = 0.f;
#pragma unroll
    for (int k = 0; k < 17; ++k) {
      float l = a[k] + ad;
      l = (l > 0.f) ? l : NEG_SLOPE * l;
      const float w = __expf(l - m);
      wr[t * 18 + k] = w;
      den += w;
    }
    wr[t * 18 + 17] = 1.f / den;
  }
  __syncthreads();   // staging drained + wr/gatb visible

  // ---- weighted sum -> ghi tile (R1, bf16 swizzled).
  //      Hub values for a thread's fixed column j are loop-invariant:
  //      hoist hs[k*128+j] into 17 registers, iterate 8 rows. ----
  {
    const float* xs = (const float*)(lds + R2O);
    const float* hs = (const float*)(lds + R2O + 32768);
    const int j = t & 127;
    const int r0 = t >> 7;                 // 0..7
    const float gj = ((const float*)(lds + RGB))[j];
    float hb[17];
#pragma unroll
    for (int k = 0; k < 17; ++k) hb[k] = hs[k * 128 + j];
    const bool basel = (m0 & (NPG - 1)) == 0;
#pragma unroll
    for (int oi = 0; oi < 8; ++oi) {
      const int r = r0 + oi * 8;
      float acc = 0.f;
      if (basel && r < 16) {
#pragma unroll
        for (int k = 0; k < 16; ++k)
          acc = fmaf(wr[r * 18 + k], (k < r) ? hb[k] : hb[k + 1], acc);
      } else {
#pragma unroll
        for (int k = 0; k < 16; ++k)
          acc = fmaf(wr[r * 18 + k], hb[k], acc);
      }
      acc = fmaf(wr[r * 18 + 16], xs[r * 128 + j], acc);
      const float v = acc * wr[r * 18 + 17] + gj;
      const int off = r * 256 + ((j >> 6) << 7) + ((((j >> 3) & 7) ^ (r & 7)) << 4) + ((j & 7) << 1);
      *(ushort*)(lds + R1O + off) = f2b(v);
    }
  }
  __syncthreads();   // ghi ready; xl/hub dead

  // ---- phase 1: e1 = relu(ghi @ W1 + b1), 4 pipelined 128-col quarters ----
#pragma unroll 1
  for (int q = 0; q < 4; ++q) {
    if (q < 3) {                         // stage next W1 quarter
      char* dst = lds + R3O + ((q + 1) & 1) * 32768;
#pragma unroll
      for (int i = 0; i < 2; ++i) {
        const int c = t + i * 1024;
        gll16(wt1hi + (size_t)((q + 1) * 128 + (c >> 4)) * 128 + (c & 15) * 8,
              dst + i * 16384 + wv * 1024);
      }
    } else {                             // stage W2 chunk0 -> half0
#pragma unroll
      for (int i = 0; i < 2; ++i) {
        const int c = t + i * 1024;
        gll16(wt2hi + (size_t)(c >> 3) * 512 + (c & 7) * 8,
              lds + R3O + i * 16384 + wv * 1024);
      }
    }
    char* Bq = lds + R3O + (q & 1) * 32768;
    f32x4 acc[2];
#pragma unroll
    for (int fr = 0; fr < 2; ++fr) acc[fr] = (f32x4){0.f, 0.f, 0.f, 0.f};
    __builtin_amdgcn_s_setprio(1);
#pragma unroll
    for (int ks = 0; ks < 4; ++ks) {
      const int cc = ks * 4 + kq;        // 0..15
      bf16x8 af[2], bf;
#pragma unroll
      for (int fr = 0; fr < 2; ++fr) {
        const int r = wrow + fr * 16 + frow;
        af[fr] = *(const bf16x8*)(lds + R1O + r * 256 + ((cc >> 3) << 7) + (((cc & 7) ^ (r & 7)) << 4));
      }
      {
        const int rb = wq * 16 + frow;   // 0..127 within quarter
        bf = *(const bf16x8*)(Bq + rb * 256 + ((cc >> 3) << 7) + (((cc & 7) ^ (rb & 7)) << 4));
      }
#pragma unroll
      for (int fr = 0; fr < 2; ++fr)
        acc[fr] = __builtin_amdgcn_mfma_f32_16x16x32_bf16(af[fr], bf, acc[fr], 0, 0, 0);
    }
    __builtin_amdgcn_s_setprio(0);
    // epilogue -> e1 (R2)
#pragma unroll
    for (int fr = 0; fr < 2; ++fr)
#pragma unroll
      for (int j = 0; j < 4; ++j) {
        const int row = wrow + fr * 16 + kq * 4 + j;
        const int colg = q * 128 + wq * 16 + frow;
        float v = acc[fr][j] + b1[colg];
        v = fmaxf(v, 0.f);
        const int off = row * 1024 + ((colg >> 6) << 7) + ((((colg >> 3) & 7) ^ (row & 7)) << 4) + ((colg & 7) << 1);
        *(ushort*)(lds + R2O + off) = f2b(v);
      }
    __syncthreads();
  }

  // ---- phase 2: e2 = relu(e1 @ W2 + b2), K=512, 8 pipelined chunks ----
  f32x4 acc2[2][2];
#pragma unroll
  for (int fr = 0; fr < 2; ++fr)
#pragma unroll
    for (int fc = 0; fc < 2; ++fc) acc2[fr][fc] = (f32x4){0.f, 0.f, 0.f, 0.f};
#pragma unroll 1
  for (int kc = 0; kc < 8; ++kc) {
    if (kc < 7) {
      char* dst = lds + R3O + ((kc + 1) & 1) * 32768;
#pragma unroll
      for (int i = 0; i < 2; ++i) {
        const int c = t + i * 1024;
        gll16(wt2hi + (size_t)(c >> 3) * 512 + (kc + 1) * 64 + (c & 7) * 8,
              dst + i * 16384 + wv * 1024);
      }
    }
    char* Bb = lds + R3O + (kc & 1) * 32768;
    __builtin_amdgcn_s_setprio(1);
#pragma unroll
    for (int ks = 0; ks < 2; ++ks) {
      const int cl = ks * 4 + kq;        // 0..7
      bf16x8 af[2], bf[2];
#pragma unroll
      for (int fr = 0; fr < 2; ++fr) {
        const int r = wrow + fr * 16 + frow;
        af[fr] = *(const bf16x8*)(lds + R2O + r * 1024 + (kc << 7) + ((cl ^ (r & 7)) << 4));
      }
#pragma unroll
      for (int fc = 0; fc < 2; ++fc) {
        const int rb = wq * 32 + fc * 16 + frow;   // 0..255
        bf[fc] = *(const bf16x8*)(Bb + rb * 128 + ((cl ^ (rb & 7)) << 4));
      }
#pragma unroll
      for (int fr = 0; fr < 2; ++fr)
#pragma unroll
        for (int fc = 0; fc < 2; ++fc)
          acc2[fr][fc] = __builtin_amdgcn_mfma_f32_16x16x32_bf16(af[fr], bf[fc], acc2[fr][fc], 0, 0, 0);
    }
    __builtin_amdgcn_s_setprio(0);
    __syncthreads();
  }
  // epilogue -> e2 (R3 half0), stage W3 -> R2 base (e1 dead)
#pragma unroll
  for (int fr = 0; fr < 2; ++fr)
#pragma unroll
    for (int fc = 0; fc < 2; ++fc)
#pragma unroll
      for (int j = 0; j < 4; ++j) {
        const int row = wrow + fr * 16 + kq * 4 + j;
        const int col = wq * 32 + fc * 16 + frow;
        float v = acc2[fr][fc][j] + b2[col];
        v = fmaxf(v, 0.f);
        const int off = row * 512 + ((col >> 6) << 7) + ((((col >> 3) & 7) ^ (row & 7)) << 4) + ((col & 7) << 1);
        *(ushort*)(lds + R3O + off) = f2b(v);
      }
#pragma unroll
  for (int i = 0; i < 2; ++i) {   // W3t [64][256] = 32KB, 2048 chunks
    const int c = t + i * 1024;
    gll16(wt3hi + (size_t)(c >> 5) * 256 + (c & 31) * 8,
          lds + R2O + i * 16384 + wv * 1024);
  }
  __syncthreads();

  // ---- phase 3: emb = e2 @ W3 + b3; 4 row-quarters x 4 col-quarters ----
  {
    const int wr3 = (wv >> 2) * 16;      // 0,16,32,48
    const int wq3 = wv & 3;
    f32x4 acc3 = (f32x4){0.f, 0.f, 0.f, 0.f};
    __builtin_amdgcn_s_setprio(1);
#pragma unroll
    for (int ks = 0; ks < 8; ++ks) {
      const int cc = ks * 4 + kq;        // 0..31
      const int r = wr3 + frow;
      const bf16x8 af = *(const bf16x8*)(lds + R3O + r * 512 + ((cc >> 3) << 7) + (((cc & 7) ^ (r & 7)) << 4));
      const int rb = wq3 * 16 + frow;
      const bf16x8 bf = *(const bf16x8*)(lds + R2O + rb * 512 + ((cc >> 3) << 7) + (((cc & 7) ^ (rb & 7)) << 4));
      acc3 = __builtin_amdgcn_mfma_f32_16x16x32_bf16(af, bf, acc3, 0, 0, 0);
    }
    __builtin_amdgcn_s_setprio(0);
#pragma unroll
    for (int j = 0; j < 4; ++j) {
      const int row = m0 + wr3 + kq * 4 + j;
      const int col = wq3 * 16 + frow;
      embb[(size_t)row * OUTD + col] = f2b(acc3[j] + b3[col]);
    }
  }
}

// ---------------------------------------------------------------------------
// fused weight conversion (one launch) + flag init.  MLP weights swizzled
// (mega's LDS path); linW hi/lo plain; gatW hi/lo PLAIN transposed (prep's
// register path).
// ---------------------------------------------------------------------------
__global__ __launch_bounds__(256) void convert_all_kernel(
    const float* __restrict__ W1, const float* __restrict__ W2,
    const float* __restrict__ W3, const float* __restrict__ linW,
    const float* __restrict__ gatW,
    ushort* __restrict__ wt1hi, ushort* __restrict__ wt2hi,
    ushort* __restrict__ wt3hi,
    ushort* __restrict__ lwThi, ushort* __restrict__ lwTlo,
    ushort* __restrict__ gwThi, ushort* __restrict__ gwTlo,
    int* __restrict__ flag)
{
  const int i = blockIdx.x * 256 + threadIdx.x;
  if (i == 0) *flag = 0;
  if (i < 65536) {                            // W1 [128][512] -> [512][128]
    const int k = i >> 9, n = i & 511;
    wt1hi[(size_t)n * 128 + swz_col(n, k)] = f2b(W1[i]);
  } else if (i < 196608) {                    // W2 [512][256] -> [256][512]
    const int j = i - 65536;
    const int k = j >> 8, n = j & 255;
    wt2hi[(size_t)n * 512 + swz_col(n, k)] = f2b(W2[j]);
  } else if (i < 212992) {                    // W3 [256][64] -> [64][256]
    const int j = i - 196608;
    const int k = j >> 6, n = j & 63;
    wt3hi[(size_t)n * 256 + swz_col(n, k)] = f2b(W3[j]);
  } else if (i < 217088) {                    // linW [32][128] -> [128][32]
    const int j = i - 212992;
    const int k = j >> 7, n = j & 127;
    const float v = linW[j];
    const ushort hi = f2b(v);
    lwThi[(size_t)n * 32 + k] = hi;
    lwTlo[(size_t)n * 32 + k] = f2b(v - b2f(hi));
  } else if (i < 233472) {                    // gatW [128][128] -> plain T
    const int j = i - 217088;
    const int k = j >> 7, n = j & 127;
    const float v = gatW[j];
    const ushort hi = f2b(v);
    gwThi[(size_t)n * 128 + k] = hi;
    gwTlo[(size_t)n * 128 + k] = f2b(v - b2f(hi));
  }
}

// ---------------------------------------------------------------------------
// pairs layout detection (parallel; flag pre-zeroed by convert_all)
// ---------------------------------------------------------------------------
__global__ __launch_bounds__(256) void detect_kernel(
    const unsigned long long* __restrict__ p64, int* __restrict__ flag)
{
  __shared__ int s;
  if (threadIdx.x == 0) s = 0;
  __syncthreads();
  int loc = 0;
  for (int i = blockIdx.x * 256 + threadIdx.x; i < NPAIR; i += 256 * 256)
    loc |= ((p64[i] >> 32) != 0ull) ? 1 : 0;
  if (loc) atomicOr(&s, 1);
  __syncthreads();
  if (threadIdx.x == 0 && s) atomicOr(flag, 1);
}

// ---------------------------------------------------------------------------
// final pair gather (fp32 out), 4-wide vectorized: thread handles 4 cols of
// one pair row (ushort4 read -> float4 write); labels in the grid tail.
// ---------------------------------------------------------------------------
__global__ __launch_bounds__(256) void gather_kernel(
    const ushort* __restrict__ embb, const unsigned long long* __restrict__ p64,
    const float* __restrict__ labels, const int* __restrict__ flagp,
    float* __restrict__ out)
{
  const int i4 = blockIdx.x * 256 + threadIdx.x;
  const int tot4 = 2 * NPAIR * OUTD / 4;
  if (i4 < tot4) {
    const int fl = *flagp;
    const int i = i4 * 4;
    const int which = i / (NPAIR * OUTD);
    const int rem = i - which * (NPAIR * OUTD);
    const int p = rem >> 6, j = rem & 63;      // j multiple of 4
    const int fi = p * 2 + which;
    int node;
    if (fl) {
      const unsigned long long w = p64[fi >> 1];
      node = (int)((fi & 1) ? (w >> 32) : (w & 0xffffffffull));
    } else {
      node = (int)p64[fi];
    }
    node &= (NTOT - 1);
    const ushort4 e = *(const ushort4*)&embb[(size_t)node * OUTD + j];
    float4 o;
    o.x = b2f(e.x); o.y = b2f(e.y); o.z = b2f(e.z); o.w = b2f(e.w);
    *(float4*)&out[i] = o;
  } else {
    const int li = i4 - tot4;
    if (li < NPAIR) out[2 * NPAIR * OUTD + li] = labels[li];
  }
}

extern "C" void kernel_launch(void* const* d_in, const int* in_sizes, int n_in,
                              void* d_out, int out_size, void* d_ws, size_t ws_size,
                              hipStream_t stream)
{
  const float* x      = (const float*)d_in[0];
  const unsigned long long* pairs = (const unsigned long long*)d_in[2];
  const float* labels = (const float*)d_in[3];
  const float* linW   = (const float*)d_in[4];
  const float* linb   = (const float*)d_in[5];
  const float* gatW   = (const float*)d_in[6];
  const float* attS   = (const float*)d_in[7];
  const float* attD   = (const float*)d_in[8];
  const float* gatb   = (const float*)d_in[9];
  const float* W1     = (const float*)d_in[10];
  const float* b1     = (const float*)d_in[11];
  const float* W2     = (const float*)d_in[12];
  const float* b2     = (const float*)d_in[13];
  const float* W3     = (const float*)d_in[14];
  const float* b3     = (const float*)d_in[15];

  float* ws = (float*)d_ws;
  const size_t NT = NTOT;
  float*  xl    = ws;                        // [0,128)
  ushort* embb  = (ushort*)(ws + NT * 128);  // [128,160)
  float*  asrc  = ws + NT * 160;
  float*  adst  = ws + NT * 161;
  ushort* wt1hi = (ushort*)(ws + NT * 162);  // [512][128] swz
  ushort* wt2hi = wt1hi + 512 * 128;         // [256][512] swz
  ushort* wt3hi = wt2hi + 256 * 512;         // [64][256]  swz
  ushort* lwThi = wt3hi + 64 * 256;          // [128][32] plain
  ushort* lwTlo = lwThi + 128 * 32;
  ushort* gwThi = lwTlo + 128 * 32;          // [128][128] plain
  ushort* gwTlo = gwThi + 128 * 128;
  int*    flag  = (int*)(gwTlo + 128 * 128);

  (void)hipFuncSetAttribute(
      reinterpret_cast<const void*>(prep_mfma_kernel),
      hipFuncAttributeMaxDynamicSharedMemorySize, PREP_LDS);
  (void)hipFuncSetAttribute(
      reinterpret_cast<const void*>(mega_kernel),
      hipFuncAttributeMaxDynamicSharedMemorySize, MEGA_LDS);

  convert_all_kernel<<<(233472 + 255) / 256, 256, 0, stream>>>(
      W1, W2, W3, linW, gatW, wt1hi, wt2hi, wt3hi,
      lwThi, lwTlo, gwThi, gwTlo, flag);
  detect_kernel<<<256, 256, 0, stream>>>(pairs, flag);

  prep_mfma_kernel<<<NTOT / 128, 256, PREP_LDS, stream>>>(
      x, lwThi, lwTlo, linb, gwThi, gwTlo, xl);
  reduce_kernel<<<NTOT / 4, 256, 0, stream>>>(xl, attS, attD, asrc, adst);

  mega_kernel<<<NTOT / 64, 1024, MEGA_LDS, stream>>>(
      xl, asrc, adst, gatb, wt1hi, wt2hi, wt3hi, b1, b2, b3, embb);

  const int total4 = 2 * NPAIR * OUTD / 4 + NPAIR;
  gather_kernel<<<(total4 + 255) / 256, 256, 0, stream>>>(embb, pairs, labels, flag, (float*)d_out);
}

// Round 18
// 78.010 us; speedup vs baseline: 2.5451x; 1.0288x over previous
//
#include <hip/hip_runtime.h>
#include <math.h>

#define NTOT 32768
#define NPG  2048
#define INDIM 32
#define HID  128
#define OUTD 64
#define NPAIR 100000
#define NEG_SLOPE 0.2f

typedef short bf16x8 __attribute__((ext_vector_type(8)));
typedef float f32x4 __attribute__((ext_vector_type(4)));

static __device__ __forceinline__ float b2f(ushort u) {
  return __uint_as_float(((unsigned)u) << 16);
}
static __device__ __forceinline__ ushort f2b(float f) {
  unsigned u = __float_as_uint(f);
  unsigned r = (u + 0x7fffu + ((u >> 16) & 1u)) >> 16;   // RNE
  return (ushort)r;
}
// chunk-swizzle: permute 8-bf16 (16B) chunks within each aligned 64-col group
// by row&7.  Involution; producers write swizzled global layout, GEMM stages
// linearly via global_load_lds, readers XOR on the LDS offset.
static __device__ __forceinline__ int swz_col(int row, int col) {
  return (col & ~63) | ((((col >> 3) ^ row) & 7) << 3) | (col & 7);
}
static __device__ __forceinline__ void gll16(const void* g, char* l) {
  __builtin_amdgcn_global_load_lds(
      (const __attribute__((address_space(1))) void*)g,
      (__attribute__((address_space(3))) void*)l, 16, 0, 0);
}

// ---------------------------------------------------------------------------
// MFMA prep: h = x@linW + b ; xl = h@gatW   (both split-bf16 3-term)
// gatW fragments read directly from global (plain transposed, L2-resident).
// (verbatim from round 17, passing)
// ---------------------------------------------------------------------------
#define HSTR 136
#define XSTR 40
#define PREP_LDS (34816 * 2)

__global__ __launch_bounds__(256) void prep_mfma_kernel(
    const float* __restrict__ x,
    const ushort* __restrict__ lwThi, const ushort* __restrict__ lwTlo,
    const float* __restrict__ linb,
    const ushort* __restrict__ gwThi, const ushort* __restrict__ gwTlo,
    float* __restrict__ xl)
{
  extern __shared__ __align__(16) char lds[];
  char* HS_HI = lds;
  char* HS_LO = lds + 34816;
  char* XS_HI = lds;
  char* XS_LO = lds + 10240;

  const int t = threadIdx.x;
  const int wv = t >> 6, lane = t & 63;
  const int frow = lane & 15, kq = lane >> 4;
  const int wr = (wv >> 1) * 64;
  const int wc = (wv & 1) * 64;
  const int m0 = blockIdx.x * 128;

  {
    const int row = t >> 1, hf = t & 1;
#pragma unroll
    for (int q = 0; q < 4; ++q) {
      const float4 v = *(const float4*)&x[(size_t)(m0 + row) * INDIM + hf * 16 + q * 4];
      ushort4 hi, lo;
      hi.x = f2b(v.x); lo.x = f2b(v.x - b2f(hi.x));
      hi.y = f2b(v.y); lo.y = f2b(v.y - b2f(hi.y));
      hi.z = f2b(v.z); lo.z = f2b(v.z - b2f(hi.z));
      hi.w = f2b(v.w); lo.w = f2b(v.w - b2f(hi.w));
      const int off = row * (XSTR * 2) + (hf * 16 + q * 4) * 2;
      *(ushort4*)(XS_HI + off) = hi;
      *(ushort4*)(XS_LO + off) = lo;
    }
  }
  __syncthreads();

  f32x4 acc1[4][4];
  {
    bf16x8 ah[4], al[4], bh[4], bl[4];
#pragma unroll
    for (int fr = 0; fr < 4; ++fr) {
      const int r = wr + fr * 16 + frow;
      const int off = r * (XSTR * 2) + kq * 16;
      ah[fr] = *(const bf16x8*)(XS_HI + off);
      al[fr] = *(const bf16x8*)(XS_LO + off);
    }
#pragma unroll
    for (int fc = 0; fc < 4; ++fc) {
      const int col = wc + fc * 16 + frow;
      bh[fc] = *(const bf16x8*)(lwThi + (size_t)col * 32 + kq * 8);
      bl[fc] = *(const bf16x8*)(lwTlo + (size_t)col * 32 + kq * 8);
    }
#pragma unroll
    for (int fr = 0; fr < 4; ++fr)
#pragma unroll
      for (int fc = 0; fc < 4; ++fc) {
        f32x4 a = (f32x4){0.f, 0.f, 0.f, 0.f};
        a = __builtin_amdgcn_mfma_f32_16x16x32_bf16(ah[fr], bh[fc], a, 0, 0, 0);
        a = __builtin_amdgcn_mfma_f32_16x16x32_bf16(ah[fr], bl[fc], a, 0, 0, 0);
        a = __builtin_amdgcn_mfma_f32_16x16x32_bf16(al[fr], bh[fc], a, 0, 0, 0);
        acc1[fr][fc] = a;
      }
  }
  __syncthreads();

#pragma unroll
  for (int fr = 0; fr < 4; ++fr)
#pragma unroll
    for (int fc = 0; fc < 4; ++fc) {
      const int col = wc + fc * 16 + frow;
      const float bj = linb[col];
#pragma unroll
      for (int j = 0; j < 4; ++j) {
        const int row = wr + fr * 16 + kq * 4 + j;
        const float v = acc1[fr][fc][j] + bj;
        const ushort hi = f2b(v);
        const int off = row * (HSTR * 2) + col * 2;
        *(ushort*)(HS_HI + off) = hi;
        *(ushort*)(HS_LO + off) = f2b(v - b2f(hi));
      }
    }
  __syncthreads();

  f32x4 acc2[4][4];
#pragma unroll
  for (int fr = 0; fr < 4; ++fr)
#pragma unroll
    for (int fc = 0; fc < 4; ++fc) acc2[fr][fc] = (f32x4){0.f, 0.f, 0.f, 0.f};
#pragma unroll
  for (int ks = 0; ks < 4; ++ks) {
    const int k = ks * 32 + kq * 8;
    bf16x8 ah[4], al[4], bh[4], bl[4];
#pragma unroll
    for (int fr = 0; fr < 4; ++fr) {
      const int r = wr + fr * 16 + frow;
      const int off = r * (HSTR * 2) + k * 2;
      ah[fr] = *(const bf16x8*)(HS_HI + off);
      al[fr] = *(const bf16x8*)(HS_LO + off);
    }
#pragma unroll
    for (int fc = 0; fc < 4; ++fc) {
      const int col = wc + fc * 16 + frow;
      bh[fc] = *(const bf16x8*)(gwThi + (size_t)col * 128 + k);
      bl[fc] = *(const bf16x8*)(gwTlo + (size_t)col * 128 + k);
    }
#pragma unroll
    for (int fr = 0; fr < 4; ++fr)
#pragma unroll
      for (int fc = 0; fc < 4; ++fc) {
        acc2[fr][fc] = __builtin_amdgcn_mfma_f32_16x16x32_bf16(ah[fr], bh[fc], acc2[fr][fc], 0, 0, 0);
        acc2[fr][fc] = __builtin_amdgcn_mfma_f32_16x16x32_bf16(ah[fr], bl[fc], acc2[fr][fc], 0, 0, 0);
        acc2[fr][fc] = __builtin_amdgcn_mfma_f32_16x16x32_bf16(al[fr], bh[fc], acc2[fr][fc], 0, 0, 0);
      }
  }

#pragma unroll
  for (int fr = 0; fr < 4; ++fr)
#pragma unroll
    for (int fc = 0; fc < 4; ++fc)
#pragma unroll
      for (int j = 0; j < 4; ++j) {
        const int row = m0 + wr + fr * 16 + kq * 4 + j;
        const int col = wc + fc * 16 + frow;
        xl[(size_t)row * HID + col] = acc2[fr][fc][j];
      }
}

// ---------------------------------------------------------------------------
// asrc/adst: one wave per node, shuffle reduce over 128 cols of xl (fp32)
// ---------------------------------------------------------------------------
__global__ __launch_bounds__(256) void reduce_kernel(
    const float* __restrict__ xl, const float* __restrict__ attS,
    const float* __restrict__ attD, float* __restrict__ asrc,
    float* __restrict__ adst)
{
  const int n = blockIdx.x * 4 + (threadIdx.x >> 6);
  const int l = threadIdx.x & 63;
  const float x0 = xl[(size_t)n * HID + l];
  const float x1 = xl[(size_t)n * HID + 64 + l];
  float s = fmaf(x0, attS[l], x1 * attS[64 + l]);
  float d = fmaf(x0, attD[l], x1 * attD[64 + l]);
#pragma unroll
  for (int sh = 32; sh > 0; sh >>= 1) {
    s += __shfl_xor(s, sh, 64);
    d += __shfl_xor(d, sh, 64);
  }
  if (l == 0) { asrc[n] = s; adst[n] = d; }
}

// ---------------------------------------------------------------------------
// MEGA v7: r17's passing v6 with operand-SWAPPED MFMAs (compute D^T so each
// lane owns 1 row x 4 consecutive cols -> ushort4 epilogue writes, bank-
// conflict-free; phase-3 global store 8B-coalesced) + phase-1 ghi A-fragment
// hoist (q-invariant).  Staging / barriers / wave maps identical to r17.
// LDS: R1 ghi 16K | R2 64K (xl+hub -> e1 -> W3) | R3 64K (W dbuf -> e2)
// ---------------------------------------------------------------------------
#define R1O 0
#define R2O 16384
#define R3O 81920
#define RWR 147456
#define RGB 152064
#define MEGA_LDS 152576

__global__ __launch_bounds__(1024) void mega_kernel(
    const float* __restrict__ xl, const float* __restrict__ asrc,
    const float* __restrict__ adst, const float* __restrict__ gatb,
    const ushort* __restrict__ wt1hi, const ushort* __restrict__ wt2hi,
    const ushort* __restrict__ wt3hi,
    const float* __restrict__ b1, const float* __restrict__ b2,
    const float* __restrict__ b3, ushort* __restrict__ embb)
{
  extern __shared__ __align__(16) char lds[];
  const int t = threadIdx.x;
  const int wv = t >> 6, lane = t & 63;
  const int frow = lane & 15, kq = lane >> 4;
  const int wrow = (wv >> 3) * 32;       // phases 1-2: 2 row-halves of 32
  const int wq = wv & 7;                 // phases 1-2: 8 col-waves
  const int m0 = blockIdx.x * 64;
  const int gb = m0 & ~(NPG - 1);

  // ---- stage: xl tile (32KB), hub rows (12KB), W1 quarter0 -> R3 half0 ----
#pragma unroll
  for (int i = 0; i < 2; ++i) {
    const int c = t + i * 1024;
    gll16(xl + (size_t)(m0 + (c >> 5)) * HID + (c & 31) * 4,
          lds + R2O + i * 16384 + wv * 1024);
  }
  if (t < 768)
    gll16(xl + (size_t)(gb + (t >> 5)) * HID + (t & 31) * 4,
          lds + R2O + 32768 + wv * 1024);
#pragma unroll
  for (int i = 0; i < 2; ++i) {
    const int c = t + i * 1024;
    gll16(wt1hi + (size_t)(c >> 4) * 128 + (c & 15) * 8,
          lds + R3O + i * 16384 + wv * 1024);
  }
  if (t >= 64 && t < 192) ((float*)(lds + RGB))[t - 64] = gatb[t - 64];

  // ---- softmax weights (wave 0, one row per lane, 64 rows) ----
  float* wr = (float*)(lds + RWR);
  if (t < 64) {
    const int n = m0 + t;
    const int loc = n & (NPG - 1);
    float a[17];
#pragma unroll
    for (int k = 0; k < 17; ++k) {
      int c;
      if (k < 16) { const int nb = (loc < 16) ? ((k < loc) ? k : k + 1) : k; c = gb + nb; }
      else c = n;
      a[k] = asrc[c];
    }
    const float ad = adst[n];
    float m = -__builtin_inff();
#pragma unroll
    for (int k = 0; k < 17; ++k) {
      float l = a[k] + ad;
      l = (l > 0.f) ? l : NEG_SLOPE * l;
      m = fmaxf(m, l);
    }
    float den = 0.f;
#pragma unroll
    for (int k = 0; k < 17; ++k) {
      float l = a[k] + ad;
      l = (l > 0.f) ? l : NEG_SLOPE * l;
      const float w = __expf(l - m);
      wr[t * 18 + k] = w;
      den += w;
    }
    wr[t * 18 + 17] = 1.f / den;
  }
  __syncthreads();   // staging drained + wr/gatb visible

  // ---- weighted sum -> ghi tile (R1, bf16 swizzled); hub values hoisted ----
  {
    const float* xs = (const float*)(lds + R2O);
    const float* hs = (const float*)(lds + R2O + 32768);
    const int j = t & 127;
    const int r0 = t >> 7;                 // 0..7
    const float gj = ((const float*)(lds + RGB))[j];
    float hb[17];
#pragma unroll
    for (int k = 0; k < 17; ++k) hb[k] = hs[k * 128 + j];
    const bool basel = (m0 & (NPG - 1)) == 0;
#pragma unroll
    for (int oi = 0; oi < 8; ++oi) {
      const int r = r0 + oi * 8;
      float acc = 0.f;
      if (basel && r < 16) {
#pragma unroll
        for (int k = 0; k < 16; ++k)
          acc = fmaf(wr[r * 18 + k], (k < r) ? hb[k] : hb[k + 1], acc);
      } else {
#pragma unroll
        for (int k = 0; k < 16; ++k)
          acc = fmaf(wr[r * 18 + k], hb[k], acc);
      }
      acc = fmaf(wr[r * 18 + 16], xs[r * 128 + j], acc);
      const float v = acc * wr[r * 18 + 17] + gj;
      const int off = r * 256 + ((j >> 6) << 7) + ((((j >> 3) & 7) ^ (r & 7)) << 4) + ((j & 7) << 1);
      *(ushort*)(lds + R1O + off) = f2b(v);
    }
  }
  __syncthreads();   // ghi ready; xl/hub dead

  // ---- hoist ghi A-fragments (invariant across phase-1 quarters) ----
  bf16x8 af_all[2][4];
#pragma unroll
  for (int fr = 0; fr < 2; ++fr)
#pragma unroll
    for (int ks = 0; ks < 4; ++ks) {
      const int cc = ks * 4 + kq;
      const int r = wrow + fr * 16 + frow;
      af_all[fr][ks] = *(const bf16x8*)(lds + R1O + r * 256 + ((cc >> 3) << 7) + (((cc & 7) ^ (r & 7)) << 4));
    }

  // ---- phase 1: e1 = relu(ghi @ W1 + b1), 4 pipelined 128-col quarters,
  //      SWAPPED mfma(bf, af) -> lane owns 1 row x 4 cols ----
#pragma unroll 1
  for (int q = 0; q < 4; ++q) {
    if (q < 3) {                         // stage next W1 quarter
      char* dst = lds + R3O + ((q + 1) & 1) * 32768;
#pragma unroll
      for (int i = 0; i < 2; ++i) {
        const int c = t + i * 1024;
        gll16(wt1hi + (size_t)((q + 1) * 128 + (c >> 4)) * 128 + (c & 15) * 8,
              dst + i * 16384 + wv * 1024);
      }
    } else {                             // stage W2 chunk0 -> half0
#pragma unroll
      for (int i = 0; i < 2; ++i) {
        const int c = t + i * 1024;
        gll16(wt2hi + (size_t)(c >> 3) * 512 + (c & 7) * 8,
              lds + R3O + i * 16384 + wv * 1024);
      }
    }
    char* Bq = lds + R3O + (q & 1) * 32768;
    f32x4 acc[2];
#pragma unroll
    for (int fr = 0; fr < 2; ++fr) acc[fr] = (f32x4){0.f, 0.f, 0.f, 0.f};
    __builtin_amdgcn_s_setprio(1);
#pragma unroll
    for (int ks = 0; ks < 4; ++ks) {
      const int cc = ks * 4 + kq;        // 0..15
      const int rb = wq * 16 + frow;     // 0..127 within quarter
      const bf16x8 bf = *(const bf16x8*)(Bq + rb * 256 + ((cc >> 3) << 7) + (((cc & 7) ^ (rb & 7)) << 4));
#pragma unroll
      for (int fr = 0; fr < 2; ++fr)
        acc[fr] = __builtin_amdgcn_mfma_f32_16x16x32_bf16(bf, af_all[fr][ks], acc[fr], 0, 0, 0);
    }
    __builtin_amdgcn_s_setprio(0);
    // epilogue (transposed frag): row = wrow+fr*16+frow, cols colb..colb+3
#pragma unroll
    for (int fr = 0; fr < 2; ++fr) {
      const int row = wrow + fr * 16 + frow;
      const int colb = q * 128 + wq * 16 + kq * 4;
      const float4 bb = *(const float4*)&b1[colb];
      ushort4 o;
      o.x = f2b(fmaxf(acc[fr][0] + bb.x, 0.f));
      o.y = f2b(fmaxf(acc[fr][1] + bb.y, 0.f));
      o.z = f2b(fmaxf(acc[fr][2] + bb.z, 0.f));
      o.w = f2b(fmaxf(acc[fr][3] + bb.w, 0.f));
      const int off = row * 1024 + ((colb >> 6) << 7) + ((((colb >> 3) & 7) ^ (row & 7)) << 4) + ((colb & 7) << 1);
      *(ushort4*)(lds + R2O + off) = o;
    }
    __syncthreads();
  }

  // ---- phase 2: e2 = relu(e1 @ W2 + b2), K=512, 8 pipelined chunks,
  //      SWAPPED mfma ----
  f32x4 acc2[2][2];
#pragma unroll
  for (int fr = 0; fr < 2; ++fr)
#pragma unroll
    for (int fc = 0; fc < 2; ++fc) acc2[fr][fc] = (f32x4){0.f, 0.f, 0.f, 0.f};
#pragma unroll 1
  for (int kc = 0; kc < 8; ++kc) {
    if (kc < 7) {
      char* dst = lds + R3O + ((kc + 1) & 1) * 32768;
#pragma unroll
      for (int i = 0; i < 2; ++i) {
        const int c = t + i * 1024;
        gll16(wt2hi + (size_t)(c >> 3) * 512 + (kc + 1) * 64 + (c & 7) * 8,
              dst + i * 16384 + wv * 1024);
      }
    }
    char* Bb = lds + R3O + (kc & 1) * 32768;
    __builtin_amdgcn_s_setprio(1);
#pragma unroll
    for (int ks = 0; ks < 2; ++ks) {
      const int cl = ks * 4 + kq;        // 0..7
      bf16x8 af[2], bf[2];
#pragma unroll
      for (int fr = 0; fr < 2; ++fr) {
        const int r = wrow + fr * 16 + frow;
        af[fr] = *(const bf16x8*)(lds + R2O + r * 1024 + (kc << 7) + ((cl ^ (r & 7)) << 4));
      }
#pragma unroll
      for (int fc = 0; fc < 2; ++fc) {
        const int rb = wq * 32 + fc * 16 + frow;   // 0..255
        bf[fc] = *(const bf16x8*)(Bb + rb * 128 + ((cl ^ (rb & 7)) << 4));
      }
#pragma unroll
      for (int fr = 0; fr < 2; ++fr)
#pragma unroll
        for (int fc = 0; fc < 2; ++fc)
          acc2[fr][fc] = __builtin_amdgcn_mfma_f32_16x16x32_bf16(bf[fc], af[fr], acc2[fr][fc], 0, 0, 0);
    }
    __builtin_amdgcn_s_setprio(0);
    __syncthreads();
  }
  // epilogue (transposed frag) -> e2 (R3 half0), stage W3 -> R2 base
#pragma unroll
  for (int fr = 0; fr < 2; ++fr)
#pragma unroll
    for (int fc = 0; fc < 2; ++fc) {
      const int row = wrow + fr * 16 + frow;
      const int colb = wq * 32 + fc * 16 + kq * 4;
      const float4 bb = *(const float4*)&b2[colb];
      ushort4 o;
      o.x = f2b(fmaxf(acc2[fr][fc][0] + bb.x, 0.f));
      o.y = f2b(fmaxf(acc2[fr][fc][1] + bb.y, 0.f));
      o.z = f2b(fmaxf(acc2[fr][fc][2] + bb.z, 0.f));
      o.w = f2b(fmaxf(acc2[fr][fc][3] + bb.w, 0.f));
      const int off = row * 512 + ((colb >> 6) << 7) + ((((colb >> 3) & 7) ^ (row & 7)) << 4) + ((colb & 7) << 1);
      *(ushort4*)(lds + R3O + off) = o;
    }
#pragma unroll
  for (int i = 0; i < 2; ++i) {   // W3t [64][256] = 32KB
    const int c = t + i * 1024;
    gll16(wt3hi + (size_t)(c >> 5) * 256 + (c & 31) * 8,
          lds + R2O + i * 16384 + wv * 1024);
  }
  __syncthreads();

  // ---- phase 3: emb = e2 @ W3 + b3; SWAPPED mfma, coalesced ushort4 out ----
  {
    const int wr3 = (wv >> 2) * 16;      // 0,16,32,48
    const int wq3 = wv & 3;
    f32x4 acc3 = (f32x4){0.f, 0.f, 0.f, 0.f};
    __builtin_amdgcn_s_setprio(1);
#pragma unroll
    for (int ks = 0; ks < 8; ++ks) {
      const int cc = ks * 4 + kq;        // 0..31
      const int r = wr3 + frow;
      const bf16x8 af = *(const bf16x8*)(lds + R3O + r * 512 + ((cc >> 3) << 7) + (((cc & 7) ^ (r & 7)) << 4));
      const int rb = wq3 * 16 + frow;
      const bf16x8 bf = *(const bf16x8*)(lds + R2O + rb * 512 + ((cc >> 3) << 7) + (((cc & 7) ^ (rb & 7)) << 4));
      acc3 = __builtin_amdgcn_mfma_f32_16x16x32_bf16(bf, af, acc3, 0, 0, 0);
    }
    __builtin_amdgcn_s_setprio(0);
    const int row = m0 + wr3 + frow;
    const int colb = wq3 * 16 + kq * 4;
    ushort4 o;
    o.x = f2b(acc3[0] + b3[colb + 0]);
    o.y = f2b(acc3[1] + b3[colb + 1]);
    o.z = f2b(acc3[2] + b3[colb + 2]);
    o.w = f2b(acc3[3] + b3[colb + 3]);
    *(ushort4*)&embb[(size_t)row * OUTD + colb] = o;
  }
}

// ---------------------------------------------------------------------------
// fused weight conversion (one launch) + flag init.  MLP weights swizzled
// (mega's LDS path); linW hi/lo plain; gatW hi/lo plain transposed.
// ---------------------------------------------------------------------------
__global__ __launch_bounds__(256) void convert_all_kernel(
    const float* __restrict__ W1, const float* __restrict__ W2,
    const float* __restrict__ W3, const float* __restrict__ linW,
    const float* __restrict__ gatW,
    ushort* __restrict__ wt1hi, ushort* __restrict__ wt2hi,
    ushort* __restrict__ wt3hi,
    ushort* __restrict__ lwThi, ushort* __restrict__ lwTlo,
    ushort* __restrict__ gwThi, ushort* __restrict__ gwTlo,
    int* __restrict__ flag)
{
  const int i = blockIdx.x * 256 + threadIdx.x;
  if (i == 0) *flag = 0;
  if (i < 65536) {                            // W1 [128][512] -> [512][128]
    const int k = i >> 9, n = i & 511;
    wt1hi[(size_t)n * 128 + swz_col(n, k)] = f2b(W1[i]);
  } else if (i < 196608) {                    // W2 [512][256] -> [256][512]
    const int j = i - 65536;
    const int k = j >> 8, n = j & 255;
    wt2hi[(size_t)n * 512 + swz_col(n, k)] = f2b(W2[j]);
  } else if (i < 212992) {                    // W3 [256][64] -> [64][256]
    const int j = i - 196608;
    const int k = j >> 6, n = j & 63;
    wt3hi[(size_t)n * 256 + swz_col(n, k)] = f2b(W3[j]);
  } else if (i < 217088) {                    // linW [32][128] -> [128][32]
    const int j = i - 212992;
    const int k = j >> 7, n = j & 127;
    const float v = linW[j];
    const ushort hi = f2b(v);
    lwThi[(size_t)n * 32 + k] = hi;
    lwTlo[(size_t)n * 32 + k] = f2b(v - b2f(hi));
  } else if (i < 233472) {                    // gatW [128][128] -> plain T
    const int j = i - 217088;
    const int k = j >> 7, n = j & 127;
    const float v = gatW[j];
    const ushort hi = f2b(v);
    gwThi[(size_t)n * 128 + k] = hi;
    gwTlo[(size_t)n * 128 + k] = f2b(v - b2f(hi));
  }
}

// ---------------------------------------------------------------------------
// pairs layout detection (parallel; flag pre-zeroed by convert_all)
// ---------------------------------------------------------------------------
__global__ __launch_bounds__(256) void detect_kernel(
    const unsigned long long* __restrict__ p64, int* __restrict__ flag)
{
  __shared__ int s;
  if (threadIdx.x == 0) s = 0;
  __syncthreads();
  int loc = 0;
  for (int i = blockIdx.x * 256 + threadIdx.x; i < NPAIR; i += 256 * 256)
    loc |= ((p64[i] >> 32) != 0ull) ? 1 : 0;
  if (loc) atomicOr(&s, 1);
  __syncthreads();
  if (threadIdx.x == 0 && s) atomicOr(flag, 1);
}

// ---------------------------------------------------------------------------
// final pair gather (fp32 out), 4-wide vectorized
// ---------------------------------------------------------------------------
__global__ __launch_bounds__(256) void gather_kernel(
    const ushort* __restrict__ embb, const unsigned long long* __restrict__ p64,
    const float* __restrict__ labels, const int* __restrict__ flagp,
    float* __restrict__ out)
{
  const int i4 = blockIdx.x * 256 + threadIdx.x;
  const int tot4 = 2 * NPAIR * OUTD / 4;
  if (i4 < tot4) {
    const int fl = *flagp;
    const int i = i4 * 4;
    const int which = i / (NPAIR * OUTD);
    const int rem = i - which * (NPAIR * OUTD);
    const int p = rem >> 6, j = rem & 63;      // j multiple of 4
    const int fi = p * 2 + which;
    int node;
    if (fl) {
      const unsigned long long w = p64[fi >> 1];
      node = (int)((fi & 1) ? (w >> 32) : (w & 0xffffffffull));
    } else {
      node = (int)p64[fi];
    }
    node &= (NTOT - 1);
    const ushort4 e = *(const ushort4*)&embb[(size_t)node * OUTD + j];
    float4 o;
    o.x = b2f(e.x); o.y = b2f(e.y); o.z = b2f(e.z); o.w = b2f(e.w);
    *(float4*)&out[i] = o;
  } else {
    const int li = i4 - tot4;
    if (li < NPAIR) out[2 * NPAIR * OUTD + li] = labels[li];
  }
}

extern "C" void kernel_launch(void* const* d_in, const int* in_sizes, int n_in,
                              void* d_out, int out_size, void* d_ws, size_t ws_size,
                              hipStream_t stream)
{
  const float* x      = (const float*)d_in[0];
  const unsigned long long* pairs = (const unsigned long long*)d_in[2];
  const float* labels = (const float*)d_in[3];
  const float* linW   = (const float*)d_in[4];
  const float* linb   = (const float*)d_in[5];
  const float* gatW   = (const float*)d_in[6];
  const float* attS   = (const float*)d_in[7];
  const float* attD   = (const float*)d_in[8];
  const float* gatb   = (const float*)d_in[9];
  const float* W1     = (const float*)d_in[10];
  const float* b1     = (const float*)d_in[11];
  const float* W2     = (const float*)d_in[12];
  const float* b2     = (const float*)d_in[13];
  const float* W3     = (const float*)d_in[14];
  const float* b3     = (const float*)d_in[15];

  float* ws = (float*)d_ws;
  const size_t NT = NTOT;
  float*  xl    = ws;                        // [0,128)
  ushort* embb  = (ushort*)(ws + NT * 128);  // [128,160)
  float*  asrc  = ws + NT * 160;
  float*  adst  = ws + NT * 161;
  ushort* wt1hi = (ushort*)(ws + NT * 162);  // [512][128] swz
  ushort* wt2hi = wt1hi + 512 * 128;         // [256][512] swz
  ushort* wt3hi = wt2hi + 256 * 512;         // [64][256]  swz
  ushort* lwThi = wt3hi + 64 * 256;          // [128][32] plain
  ushort* lwTlo = lwThi + 128 * 32;
  ushort* gwThi = lwTlo + 128 * 32;          // [128][128] plain
  ushort* gwTlo = gwThi + 128 * 128;
  int*    flag  = (int*)(gwTlo + 128 * 128);

  (void)hipFuncSetAttribute(
      reinterpret_cast<const void*>(prep_mfma_kernel),
      hipFuncAttributeMaxDynamicSharedMemorySize, PREP_LDS);
  (void)hipFuncSetAttribute(
      reinterpret_cast<const void*>(mega_kernel),
      hipFuncAttributeMaxDynamicSharedMemorySize, MEGA_LDS);

  convert_all_kernel<<<(233472 + 255) / 256, 256, 0, stream>>>(
      W1, W2, W3, linW, gatW, wt1hi, wt2hi, wt3hi,
      lwThi, lwTlo, gwThi, gwTlo, flag);
  detect_kernel<<<256, 256, 0, stream>>>(pairs, flag);

  prep_mfma_kernel<<<NTOT / 128, 256, PREP_LDS, stream>>>(
      x, lwThi, lwTlo, linb, gwThi, gwTlo, xl);
  reduce_kernel<<<NTOT / 4, 256, 0, stream>>>(xl, attS, attD, asrc, adst);

  mega_kernel<<<NTOT / 64, 1024, MEGA_LDS, stream>>>(
      xl, asrc, adst, gatb, wt1hi, wt2hi, wt3hi, b1, b2, b3, embb);

  const int total4 = 2 * NPAIR * OUTD / 4 + NPAIR;
  gather_kernel<<<(total4 + 255) / 256, 256, 0, stream>>>(embb, pairs, labels, flag, (float*)d_out);
}